// Round 14
// baseline (164.254 us; speedup 1.0000x reference)
//
#include <hip/hip_runtime.h>
#include <math.h>

// Problem dims
#define BSZ   256
#define LDIM  128
#define PDIM  3
#define HDIM  512
#define DDIM  32
#define NDIM  50
#define NEDGE 1225   // N*(N-1)/2
#define EOUT  5      // EDIM+1
#define NRH   3      // r-splits: cols {192,192,128}

// out layout (floats)
//   node_logits  [256,50,32]   @ 0        (409600)
//   edge_logits  [256,1225,5]  @ 409600   (1568000)
//   size_probs   [256,50]      @ 1977600  (12800)
//   edge_indices [1225,2]      @ 1990400  (2450, float values)
// ws layout (floats): u0 @0, u1 @131072, n1a @262144, n1b @393216 (each 131072),
//                     pW1 @524288 (25600), P @549888 (3 x 1568000)

// ============ k_pre: K-split n1/u partials + size head + pW1 ==============
// grid 1178 x 256:
//   [0,512)    n1 partial: bg=bx>>2 (2 batches), jh=(bx>>1)&1, kh=bx&1
//   [512,1024) u  partial: same decomposition
//   [1024,1152) size head: 2 batches
//   [1152,1178) pW1: 4 rows x 256-col half
__global__ __launch_bounds__(256) void k_pre(
        const float* __restrict__ z, const float* __restrict__ tp,
        const float* __restrict__ W_in, const float* __restrict__ b_in,
        const float* __restrict__ W_s1, const float* __restrict__ b_s1,
        const float* __restrict__ W_s2, const float* __restrict__ b_s2,
        const float* __restrict__ W_n1, const float* __restrict__ W_e1,
        const float* __restrict__ pe,
        float* __restrict__ n1a, float* __restrict__ n1b,
        float* __restrict__ u0, float* __restrict__ u1,
        float* __restrict__ pW1, float* __restrict__ out_sp) {
    int bx = blockIdx.x, t = threadIdx.x;
    __shared__ float smem[2368];

    if (bx < 1024) {
        // ---- role n1 (bx<512) or u: 2 batches, j-half, K-half -------------
        int role = bx >> 9;              // 0: n1, 1: u
        int idx = bx & 511;
        int bg = idx >> 2, jh = (idx >> 1) & 1, kh = idx & 1;
        int b0 = bg * 2;
        float* sin_ = smem;              // [2][132]
        float* sh   = smem + 264;        // [2][256] : h cols kh*256..+256
        for (int q = t; q < 2 * 131; q += 256) {
            int bi = q / 131, k = q % 131;
            sin_[bi * 132 + k] = (k < LDIM) ? z[(size_t)(b0 + bi) * LDIM + k]
                                            : tp[(size_t)(b0 + bi) * PDIM + (k - LDIM)];
        }
        __syncthreads();
        {
            int g = kh * 256 + t;        // h column this thread owns
            float bin = b_in[g];
            float a0 = bin, a1 = bin;
            for (int k = 0; k < LDIM + PDIM; ++k) {
                float w = W_in[(size_t)k * HDIM + g];
                a0 += sin_[k] * w;
                a1 += sin_[132 + k] * w;
            }
            sh[t] = fmaxf(a0, 0.f);
            sh[256 + t] = fmaxf(a1, 0.f);
        }
        __syncthreads();
        int j = jh * 256 + t;
        const float* W = role ? W_e1 : W_n1;   // W1h = rows 0..511 of W_e1
        float s0a = 0.f, s0b = 0.f, s1a = 0.f, s1b = 0.f;
        for (int k4 = 0; k4 < 64; ++k4) {
            size_t kr = (size_t)(kh * 256 + k4 * 4);
            float w0 = W[(kr + 0) * HDIM + j];
            float w1 = W[(kr + 1) * HDIM + j];
            float w2 = W[(kr + 2) * HDIM + j];
            float w3 = W[(kr + 3) * HDIM + j];
            float4 x0 = *reinterpret_cast<const float4*>(&sh[k4 * 4]);
            float4 x1 = *reinterpret_cast<const float4*>(&sh[256 + k4 * 4]);
            s0a += x0.x * w0 + x0.y * w1;
            s0b += x0.z * w2 + x0.w * w3;
            s1a += x1.x * w0 + x1.y * w1;
            s1b += x1.z * w2 + x1.w * w3;
        }
        float a0 = s0a + s0b, a1 = s1a + s1b;
        float* dst = role ? (kh ? u1 : u0) : (kh ? n1b : n1a);
        dst[(size_t)(b0 + 0) * HDIM + j] = a0;
        dst[(size_t)(b0 + 1) * HDIM + j] = a1;
    } else if (bx < 1152) {
        // ---- role size head: 2 batches (full h computed locally) ----------
        int b0 = (bx - 1024) * 2;
        float* sin_ = smem;            // [2][132]
        float* sh   = smem + 264;      // [2][512]
        float* s1b  = smem + 264 + 1024;  // [2][256]
        float* slg  = smem + 264 + 1024 + 512;  // [2][50]
        for (int q = t; q < 2 * 131; q += 256) {
            int bi = q / 131, k = q % 131;
            sin_[bi * 132 + k] = (k < LDIM) ? z[(size_t)(b0 + bi) * LDIM + k]
                                            : tp[(size_t)(b0 + bi) * PDIM + (k - LDIM)];
        }
        __syncthreads();
        {
            float bi0 = b_in[t], bi1 = b_in[t + 256];
            float a00 = bi0, a01 = bi1, a10 = bi0, a11 = bi1;
            for (int k = 0; k < LDIM + PDIM; ++k) {
                float w0 = W_in[(size_t)k * HDIM + t];
                float w1 = W_in[(size_t)k * HDIM + t + 256];
                float x0 = sin_[k], x1 = sin_[132 + k];
                a00 += x0 * w0; a01 += x0 * w1;
                a10 += x1 * w0; a11 += x1 * w1;
            }
            sh[t] = fmaxf(a00, 0.f); sh[t + 256] = fmaxf(a01, 0.f);
            sh[512 + t] = fmaxf(a10, 0.f); sh[512 + t + 256] = fmaxf(a11, 0.f);
        }
        __syncthreads();
        {
            float bv = b_s1[t];
            float a0 = bv, a1 = bv;
            for (int k = 0; k < HDIM; ++k) {
                float w = W_s1[(size_t)k * (HDIM / 2) + t];
                a0 += sh[k] * w;
                a1 += sh[512 + k] * w;
            }
            s1b[t] = fmaxf(a0, 0.f);
            s1b[256 + t] = fmaxf(a1, 0.f);
        }
        __syncthreads();
        int b4 = t / NDIM, o = t % NDIM;
        if (t < 2 * NDIM) {
            float a = b_s2[o];
            for (int k = 0; k < HDIM / 2; ++k)
                a += s1b[b4 * 256 + k] * W_s2[(size_t)k * NDIM + o];
            slg[b4 * NDIM + o] = a;
        }
        __syncthreads();
        if (t < 2 * NDIM) {
            float m = slg[b4 * NDIM];
            for (int k = 1; k < NDIM; ++k) m = fmaxf(m, slg[b4 * NDIM + k]);
            float s = 0.f;
            for (int k = 0; k < NDIM; ++k) s += expf(slg[b4 * NDIM + k] - m);
            out_sp[(size_t)(b0 + b4) * NDIM + o] = expf(slg[b4 * NDIM + o] - m) / s;
        }
    } else {
        // ---- role pW1: 0.5 * pe @ W1h, 4 rows x 256-col half --------------
        int g = bx - 1152, rg = g >> 1, jh = g & 1;
        int r[4];
#pragma unroll
        for (int q = 0; q < 4; ++q) { int rr = rg * 4 + q; r[q] = (rr < NDIM) ? rr : NDIM - 1; }
        float* spe = smem;   // [4][512]
        for (int q = t; q < 4 * HDIM / 4; q += 256) {
            int lin = q * 4, row = lin >> 9, col = lin & 511;
            *reinterpret_cast<float4*>(&spe[row * HDIM + col]) =
                *reinterpret_cast<const float4*>(&pe[(size_t)r[row] * HDIM + col]);
        }
        __syncthreads();
        int j = jh * 256 + t;
        float a0 = 0.f, a1 = 0.f, a2 = 0.f, a3 = 0.f;
        for (int k4 = 0; k4 < HDIM / 4; ++k4) {
            float w0 = W_e1[(size_t)(k4 * 4 + 0) * HDIM + j];
            float w1 = W_e1[(size_t)(k4 * 4 + 1) * HDIM + j];
            float w2 = W_e1[(size_t)(k4 * 4 + 2) * HDIM + j];
            float w3 = W_e1[(size_t)(k4 * 4 + 3) * HDIM + j];
            float4 x0 = *reinterpret_cast<const float4*>(&spe[0 * HDIM + k4 * 4]);
            float4 x1 = *reinterpret_cast<const float4*>(&spe[1 * HDIM + k4 * 4]);
            float4 x2 = *reinterpret_cast<const float4*>(&spe[2 * HDIM + k4 * 4]);
            float4 x3 = *reinterpret_cast<const float4*>(&spe[3 * HDIM + k4 * 4]);
            a0 += x0.x * w0 + x0.y * w1 + x0.z * w2 + x0.w * w3;
            a1 += x1.x * w0 + x1.y * w1 + x1.z * w2 + x1.w * w3;
            a2 += x2.x * w0 + x2.y * w1 + x2.z * w2 + x2.w * w3;
            a3 += x3.x * w0 + x3.y * w1 + x3.z * w2 + x3.w * w3;
        }
        pW1[(size_t)r[0] * HDIM + j] = 0.5f * a0;
        pW1[(size_t)r[1] * HDIM + j] = 0.5f * a1;
        pW1[(size_t)r[2] * HDIM + j] = 0.5f * a2;
        pW1[(size_t)r[3] * HDIM + j] = 0.5f * a3;
    }
}

// ============ k_nl: K-split GEMM -> atomicAdd into zeroed out_nl ===========
// grid (64,5,2), 320 thr, 4 batches/block. Stages relu(n1a+n1b+b_n1) for its
// K-half. kh=0 folds b_n2 into its partial. fp32 add commutative -> determ.
__global__ __launch_bounds__(320) void k_nl(const float* __restrict__ n1a,
                                            const float* __restrict__ n1b,
                                            const float* __restrict__ b_n1,
                                            const float* __restrict__ W_n2,
                                            const float* __restrict__ b_n2,
                                            float* __restrict__ out_nl) {
    const int NOUT = NDIM * DDIM;   // 1600
    int t = threadIdx.x;
    int j = blockIdx.y * 320 + t;
    int bg = blockIdx.x;            // 4 batches
    int kh = blockIdx.z;
    __shared__ float s[4][256];
    for (int idx = t; idx < 4 * 256; idx += 320) {
        int row = idx >> 8, col = idx & 255;
        size_t g = (size_t)(bg * 4 + row) * HDIM + kh * 256 + col;
        s[row][col] = fmaxf(n1a[g] + n1b[g] + b_n1[kh * 256 + col], 0.f);
    }
    __syncthreads();
    float acc[4];
    float bias = (kh == 0) ? b_n2[j] : 0.f;
#pragma unroll
    for (int b = 0; b < 4; ++b) acc[b] = bias;
    for (int k4 = 0; k4 < 64; ++k4) {
        size_t kr = (size_t)(kh * 256 + k4 * 4);
        float w0 = W_n2[(kr + 0) * NOUT + j];
        float w1 = W_n2[(kr + 1) * NOUT + j];
        float w2 = W_n2[(kr + 2) * NOUT + j];
        float w3 = W_n2[(kr + 3) * NOUT + j];
#pragma unroll
        for (int b = 0; b < 4; ++b) {
            float4 nv = *reinterpret_cast<const float4*>(&s[b][k4 * 4]);
            acc[b] += nv.x * w0 + nv.y * w1 + nv.z * w2 + nv.w * w3;
        }
    }
#pragma unroll
    for (int b = 0; b < 4; ++b)
        atomicAdd(&out_nl[(size_t)(bg * 4 + b) * NOUT + j], acc[b]);
}

// ============ k_edge: round-11 exact (74us) + u0+u1 ========================
// grid (256,3), block 256, LDS 38.4KB -> 3 blocks/CU.
__global__ __launch_bounds__(256) void k_edge(
        const float* __restrict__ nl,    // [256,50,32]
        const float* __restrict__ u0,    // [256,512] partial
        const float* __restrict__ u1,    // [256,512] partial
        const float* __restrict__ pW1,   // [50,512]
        const float* __restrict__ W_e1,  // [576,512]
        const float* __restrict__ b_e1,  // [512]
        const float* __restrict__ W_e2,  // [512,5]
        float* __restrict__ P) {         // [3][256][1225][5]
    int b  = blockIdx.x;
    int rh = blockIdx.y;
    int t  = threadIdx.x;
    int rbase = rh * 192;
    int ECH = (rh < 2) ? 96 : 64;       // chunk cols (2 chunks per block)
    int ech4 = ECH >> 2;

    __shared__ float As[NDIM * 96];   // 19.2 KB
    __shared__ float Bs[NDIM * 96];   // 19.2 KB

    bool has = (t < 225);
    int pp = 0, qq = 0;
    if (has) {
        int tt = t;
        for (pp = 0; pp < 25; ++pp) {
            int qmin = pp ? ((2 * pp - 2) / 3 + 1) : 0;
            int cnt = 17 - qmin;
            if (tt < cnt) { qq = qmin + tt; break; }
            tt -= cnt;
        }
    }
    int i0 = 2 * pp, i1 = i0 + 1;
    int j0 = 3 * qq, j1 = j0 + 1, j2r = (3 * qq + 2 < NDIM) ? 3 * qq + 2 : NDIM - 1;

    float acc[6][EOUT];
#pragma unroll
    for (int e = 0; e < 6; ++e)
#pragma unroll
        for (int o = 0; o < EOUT; ++o) acc[e][o] = 0.f;

    bool prod = (t < 2 * ECH);
    int arr = (t >= ECH) ? 1 : 0;
    int c = t - (arr ? ECH : 0);
    const float4* nl4 = reinterpret_cast<const float4*>(nl + (size_t)b * (NDIM * DDIM));

    for (int ch = 0; ch < 2; ++ch) {
        // ---- produce ----
        if (prod) {
            int col = rbase + ch * ECH + c;
            float w[DDIM];
#pragma unroll
            for (int k = 0; k < DDIM; ++k)
                w[k] = W_e1[(size_t)(HDIM + arr * DDIM + k) * HDIM + col];
            float cm = 0.5f * (u0[(size_t)b * HDIM + col] + u1[(size_t)b * HDIM + col]
                               + b_e1[col]);
            float* dst = arr ? Bs : As;
            float pc = pW1[col];   // row 0, rotate-prefetched
            for (int n = 0; n < NDIM; ++n) {
                float pn = (n < NDIM - 1) ? pW1[(size_t)(n + 1) * HDIM + col] : 0.f;
                float s0 = 0.f, s1 = 0.f, s2 = 0.f, s3 = 0.f;
#pragma unroll
                for (int h = 0; h < 2; ++h) {
                    int q = h * 4;
                    float4 xA = nl4[n * 8 + q + 0];
                    float4 xB = nl4[n * 8 + q + 1];
                    float4 xC = nl4[n * 8 + q + 2];
                    float4 xD = nl4[n * 8 + q + 3];
                    s0 += xA.x * w[4*q+0]  + xA.y * w[4*q+1]  + xA.z * w[4*q+2]  + xA.w * w[4*q+3];
                    s1 += xB.x * w[4*q+4]  + xB.y * w[4*q+5]  + xB.z * w[4*q+6]  + xB.w * w[4*q+7];
                    s2 += xC.x * w[4*q+8]  + xC.y * w[4*q+9]  + xC.z * w[4*q+10] + xC.w * w[4*q+11];
                    s3 += xD.x * w[4*q+12] + xD.y * w[4*q+13] + xD.z * w[4*q+14] + xD.w * w[4*q+15];
                }
                dst[n * ECH + ((((c >> 2) ^ (n & 7)) << 2) | (c & 3))] =
                    (cm + pc) + ((s0 + s1) + (s2 + s3));
                pc = pn;
            }
        }
        __syncthreads();
        // ---- consume ----
        if (has) {
            const float4* A4 = reinterpret_cast<const float4*>(As);
            const float4* B4 = reinterpret_cast<const float4*>(Bs);
            const float* wch = W_e2 + (size_t)(rbase + ch * ECH) * EOUT;
            int iA = i0 * ech4, iB = i1 * ech4;
            int jA = j0 * ech4, jB = j1 * ech4, jC = j2r * ech4;
            int sA = i0 & 7, sB = i1 & 7, s0m = j0 & 7, s1m = j1 & 7, s2m = j2r & 7;
            for (int r4 = 0; r4 < ech4; ++r4) {
                const float* wr = wch + r4 * 4 * EOUT;   // uniform -> s_load
                float4 a0 = A4[iA + (r4 ^ sA)];
                float4 a1 = A4[iB + (r4 ^ sB)];
                float4 b0 = B4[jA + (r4 ^ s0m)];
                float4 b1 = B4[jB + (r4 ^ s1m)];
                float4 b2 = B4[jC + (r4 ^ s2m)];
                float v[6][4];
#pragma unroll
                for (int rr = 0; rr < 4; ++rr) {
                    float av0 = (&a0.x)[rr], av1 = (&a1.x)[rr];
                    float bv0 = (&b0.x)[rr], bv1 = (&b1.x)[rr], bv2 = (&b2.x)[rr];
                    v[0][rr] = fmaxf(av0 + bv0, 0.f);
                    v[1][rr] = fmaxf(av0 + bv1, 0.f);
                    v[2][rr] = fmaxf(av0 + bv2, 0.f);
                    v[3][rr] = fmaxf(av1 + bv0, 0.f);
                    v[4][rr] = fmaxf(av1 + bv1, 0.f);
                    v[5][rr] = fmaxf(av1 + bv2, 0.f);
                }
#pragma unroll
                for (int rr = 0; rr < 4; ++rr) {
#pragma unroll
                    for (int o = 0; o < EOUT; ++o) {
                        float wv = wr[rr * EOUT + o];
#pragma unroll
                        for (int e = 0; e < 6; ++e)
                            acc[e][o] += v[e][rr] * wv;
                    }
                }
            }
        }
        __syncthreads();
    }

    if (has) {
        float* Pb = P + ((size_t)rh * BSZ + b) * NEDGE * EOUT;
        int js[3] = {j0, j1, 3 * qq + 2};
#pragma unroll
        for (int r = 0; r < 2; ++r) {
            int i = i0 + r;
#pragma unroll
            for (int cc = 0; cc < 3; ++cc) {
                int j = js[cc];
                if (i < j && j < NDIM) {
                    int e = i * (NDIM - 1) - (i * (i - 1)) / 2 + (j - i - 1);
#pragma unroll
                    for (int o = 0; o < EOUT; ++o)
                        Pb[(size_t)e * EOUT + o] = acc[r * 3 + cc][o];
                }
            }
        }
    }
}

// ============ k_comb: out_el = P0+P1+P2 + bias (float4 x5/thread) ==========
__global__ __launch_bounds__(256) void k_comb(const float* __restrict__ P,
                                              const float* __restrict__ b_e2,
                                              float* __restrict__ out_el,
                                              float* __restrict__ out_idx) {
    int blk = blockIdx.x, t = threadIdx.x;
    const size_t PS = (size_t)BSZ * NEDGE * EOUT;
    if (blk < 307) {
        int tid = blk * 256 + t;       // 20 floats per thread; 78400 total
        if (tid < 78400) {
            const float4* p0 = reinterpret_cast<const float4*>(P) + (size_t)tid * 5;
            const float4* p1 = reinterpret_cast<const float4*>(P + PS) + (size_t)tid * 5;
            const float4* p2 = reinterpret_cast<const float4*>(P + 2 * PS) + (size_t)tid * 5;
            float4* o = reinterpret_cast<float4*>(out_el) + (size_t)tid * 5;
            float b5[5];
#pragma unroll
            for (int cc = 0; cc < 5; ++cc) b5[cc] = b_e2[cc];
#pragma unroll
            for (int q = 0; q < 5; ++q) {
                float4 a = p0[q], b = p1[q], cq = p2[q];
                float4 r;
                r.x = a.x + b.x + cq.x + b5[(q * 4 + 0) % 5];
                r.y = a.y + b.y + cq.y + b5[(q * 4 + 1) % 5];
                r.z = a.z + b.z + cq.z + b5[(q * 4 + 2) % 5];
                r.w = a.w + b.w + cq.w + b5[(q * 4 + 3) % 5];
                o[q] = r;
            }
        }
    } else {
        int e = (blk - 307) * 256 + t;
        if (e < NEDGE) {
            int i = 0, rem = e;
            while (rem >= (NDIM - 1 - i)) { rem -= (NDIM - 1 - i); ++i; }
            int j = i + 1 + rem;
            out_idx[e * 2] = (float)i;
            out_idx[e * 2 + 1] = (float)j;
        }
    }
}

extern "C" void kernel_launch(void* const* d_in, const int* in_sizes, int n_in,
                              void* d_out, int out_size, void* d_ws, size_t ws_size,
                              hipStream_t stream) {
    const float* z    = (const float*)d_in[0];
    const float* tp   = (const float*)d_in[1];
    const float* W_in = (const float*)d_in[2];
    const float* b_in = (const float*)d_in[3];
    const float* W_s1 = (const float*)d_in[4];
    const float* b_s1 = (const float*)d_in[5];
    const float* W_s2 = (const float*)d_in[6];
    const float* b_s2 = (const float*)d_in[7];
    const float* W_n1 = (const float*)d_in[8];
    const float* b_n1 = (const float*)d_in[9];
    const float* W_n2 = (const float*)d_in[10];
    const float* b_n2 = (const float*)d_in[11];
    const float* W_e1 = (const float*)d_in[12];
    const float* b_e1 = (const float*)d_in[13];
    const float* W_e2 = (const float*)d_in[14];
    const float* b_e2 = (const float*)d_in[15];
    const float* pe   = (const float*)d_in[16];

    float* out     = (float*)d_out;
    float* out_nl  = out;                 // node_logits
    float* out_el  = out + 409600;        // edge_logits
    float* out_sp  = out + 1977600;       // size_probs
    float* out_idx = out + 1990400;       // edge_indices (as float)

    float* ws  = (float*)d_ws;
    float* u0_  = ws;
    float* u1_  = ws + 131072;
    float* n1a = ws + 262144;
    float* n1b = ws + 393216;
    float* pW1 = ws + 524288;
    float* P   = ws + 549888;             // [3][256][1225][5]

    hipMemsetAsync(out_nl, 0, (size_t)409600 * sizeof(float), stream);
    k_pre<<<1178, 256, 0, stream>>>(z, tp, W_in, b_in, W_s1, b_s1, W_s2, b_s2,
                                    W_n1, W_e1, pe, n1a, n1b, u0_, u1_, pW1, out_sp);
    k_nl<<<dim3(64, 5, 2), 320, 0, stream>>>(n1a, n1b, b_n1, W_n2, b_n2, out_nl);
    k_edge<<<dim3(BSZ, NRH), 256, 0, stream>>>(out_nl, u0_, u1_, pW1, W_e1, b_e1, W_e2, P);
    k_comb<<<312, 256, 0, stream>>>(P, b_e2, out_el, out_idx);
}

// Round 17
// 145.031 us; speedup vs baseline: 1.1325x; 1.1325x over previous
//
#include <hip/hip_runtime.h>
#include <math.h>

// Problem dims
#define BSZ   256
#define LDIM  128
#define PDIM  3
#define HDIM  512
#define DDIM  32
#define NDIM  50
#define NEDGE 1225   // N*(N-1)/2
#define EOUT  5      // EDIM+1
#define NRH   3      // r-splits: cols {192,192,128}

// out layout (floats)
//   node_logits  [256,50,32]   @ 0        (409600)
//   edge_logits  [256,1225,5]  @ 409600   (1568000)
//   size_probs   [256,50]      @ 1977600  (12800)
//   edge_indices [1225,2]      @ 1990400  (2450, float values)
// ws layout (floats): u @0 (131072), pW1 @131072 (25600), n1 @156672 (131072),
//                     P @287744 (3 x 1568000)

typedef _Float16 v2h __attribute__((ext_vector_type(2)));

__device__ __forceinline__ float fdot2f(v2h a, v2h b, float c) {
    return __builtin_amdgcn_fdot2(a, b, c, false);
}
__device__ __forceinline__ v2h relu2(v2h a, v2h b) {
    v2h s = a + b;                       // v_pk_add_f16
    v2h z = {(_Float16)0.f, (_Float16)0.f};
    return __builtin_elementwise_max(s, z);   // v_pk_max_f16
}

// ============ k_pre: 256-thr blocks, col-split roles (round-11, proven) ====
__global__ __launch_bounds__(256) void k_pre(
        const float* __restrict__ z, const float* __restrict__ tp,
        const float* __restrict__ W_in, const float* __restrict__ b_in,
        const float* __restrict__ W_s1, const float* __restrict__ b_s1,
        const float* __restrict__ W_s2, const float* __restrict__ b_s2,
        const float* __restrict__ W_n1, const float* __restrict__ b_n1,
        const float* __restrict__ W_e1, const float* __restrict__ pe,
        float* __restrict__ n1, float* __restrict__ u,
        float* __restrict__ pW1, float* __restrict__ out_sp) {
    int bx = blockIdx.x, t = threadIdx.x;
    __shared__ float smem[2368];

    if (bx < 512) {
        int role = bx >> 8;
        int idx2 = bx & 255;
        int bg = idx2 >> 1, jh = idx2 & 1;
        int b0 = bg * 2;
        float* sin_ = smem;            // [2][132]
        float* sh   = smem + 264;      // [2][512]
        for (int q = t; q < 2 * 131; q += 256) {
            int bi = q / 131, k = q % 131;
            sin_[bi * 132 + k] = (k < LDIM) ? z[(size_t)(b0 + bi) * LDIM + k]
                                            : tp[(size_t)(b0 + bi) * PDIM + (k - LDIM)];
        }
        __syncthreads();
        {
            float bi0 = b_in[t], bi1 = b_in[t + 256];
            float a00 = bi0, a01 = bi1, a10 = bi0, a11 = bi1;
            for (int k = 0; k < LDIM + PDIM; ++k) {
                float w0 = W_in[(size_t)k * HDIM + t];
                float w1 = W_in[(size_t)k * HDIM + t + 256];
                float x0 = sin_[k], x1 = sin_[132 + k];
                a00 += x0 * w0; a01 += x0 * w1;
                a10 += x1 * w0; a11 += x1 * w1;
            }
            sh[t] = fmaxf(a00, 0.f); sh[t + 256] = fmaxf(a01, 0.f);
            sh[512 + t] = fmaxf(a10, 0.f); sh[512 + t + 256] = fmaxf(a11, 0.f);
        }
        __syncthreads();
        int j = jh * 256 + t;
        const float* W = role ? W_e1 : W_n1;   // W1h = rows 0..511 of W_e1
        float s0a = 0.f, s0b = 0.f, s1a = 0.f, s1b = 0.f;
        for (int k4 = 0; k4 < HDIM / 4; ++k4) {
            float w0 = W[(size_t)(k4 * 4 + 0) * HDIM + j];
            float w1 = W[(size_t)(k4 * 4 + 1) * HDIM + j];
            float w2 = W[(size_t)(k4 * 4 + 2) * HDIM + j];
            float w3 = W[(size_t)(k4 * 4 + 3) * HDIM + j];
            float4 x0 = *reinterpret_cast<const float4*>(&sh[k4 * 4]);
            float4 x1 = *reinterpret_cast<const float4*>(&sh[512 + k4 * 4]);
            s0a += x0.x * w0 + x0.y * w1;
            s0b += x0.z * w2 + x0.w * w3;
            s1a += x1.x * w0 + x1.y * w1;
            s1b += x1.z * w2 + x1.w * w3;
        }
        float a0 = s0a + s0b, a1 = s1a + s1b;
        if (role == 0) {
            float bb = b_n1[j];
            n1[(size_t)(b0 + 0) * HDIM + j] = fmaxf(a0 + bb, 0.f);
            n1[(size_t)(b0 + 1) * HDIM + j] = fmaxf(a1 + bb, 0.f);
        } else {
            u[(size_t)(b0 + 0) * HDIM + j] = a0;
            u[(size_t)(b0 + 1) * HDIM + j] = a1;
        }
    } else if (bx < 640) {
        // ---- role size head: 2 batches ------------------------------------
        int b0 = (bx - 512) * 2;
        float* sin_ = smem;            // [2][132]
        float* sh   = smem + 264;      // [2][512]
        float* s1b  = smem + 264 + 1024;  // [2][256]
        float* slg  = smem + 264 + 1024 + 512;  // [2][50]
        for (int q = t; q < 2 * 131; q += 256) {
            int bi = q / 131, k = q % 131;
            sin_[bi * 132 + k] = (k < LDIM) ? z[(size_t)(b0 + bi) * LDIM + k]
                                            : tp[(size_t)(b0 + bi) * PDIM + (k - LDIM)];
        }
        __syncthreads();
        {
            float bi0 = b_in[t], bi1 = b_in[t + 256];
            float a00 = bi0, a01 = bi1, a10 = bi0, a11 = bi1;
            for (int k = 0; k < LDIM + PDIM; ++k) {
                float w0 = W_in[(size_t)k * HDIM + t];
                float w1 = W_in[(size_t)k * HDIM + t + 256];
                float x0 = sin_[k], x1 = sin_[132 + k];
                a00 += x0 * w0; a01 += x0 * w1;
                a10 += x1 * w0; a11 += x1 * w1;
            }
            sh[t] = fmaxf(a00, 0.f); sh[t + 256] = fmaxf(a01, 0.f);
            sh[512 + t] = fmaxf(a10, 0.f); sh[512 + t + 256] = fmaxf(a11, 0.f);
        }
        __syncthreads();
        {
            float bv = b_s1[t];
            float a0 = bv, a1 = bv;
            for (int k = 0; k < HDIM; ++k) {
                float w = W_s1[(size_t)k * (HDIM / 2) + t];
                a0 += sh[k] * w;
                a1 += sh[512 + k] * w;
            }
            s1b[t] = fmaxf(a0, 0.f);
            s1b[256 + t] = fmaxf(a1, 0.f);
        }
        __syncthreads();
        int b4 = t / NDIM, o = t % NDIM;
        if (t < 2 * NDIM) {
            float a = b_s2[o];
            for (int k = 0; k < HDIM / 2; ++k)
                a += s1b[b4 * 256 + k] * W_s2[(size_t)k * NDIM + o];
            slg[b4 * NDIM + o] = a;
        }
        __syncthreads();
        if (t < 2 * NDIM) {
            float m = slg[b4 * NDIM];
            for (int k = 1; k < NDIM; ++k) m = fmaxf(m, slg[b4 * NDIM + k]);
            float s = 0.f;
            for (int k = 0; k < NDIM; ++k) s += expf(slg[b4 * NDIM + k] - m);
            out_sp[(size_t)(b0 + b4) * NDIM + o] = expf(slg[b4 * NDIM + o] - m) / s;
        }
    } else {
        // ---- role pW1: 0.5 * pe @ W1h, 4 rows x 256-col half --------------
        int g = bx - 640, rg = g >> 1, jh = g & 1;
        int r[4];
#pragma unroll
        for (int q = 0; q < 4; ++q) { int rr = rg * 4 + q; r[q] = (rr < NDIM) ? rr : NDIM - 1; }
        float* spe = smem;   // [4][512]
        for (int q = t; q < 4 * HDIM / 4; q += 256) {
            int lin = q * 4, row = lin >> 9, col = lin & 511;
            *reinterpret_cast<float4*>(&spe[row * HDIM + col]) =
                *reinterpret_cast<const float4*>(&pe[(size_t)r[row] * HDIM + col]);
        }
        __syncthreads();
        int j = jh * 256 + t;
        float a0 = 0.f, a1 = 0.f, a2 = 0.f, a3 = 0.f;
        for (int k4 = 0; k4 < HDIM / 4; ++k4) {
            float w0 = W_e1[(size_t)(k4 * 4 + 0) * HDIM + j];
            float w1 = W_e1[(size_t)(k4 * 4 + 1) * HDIM + j];
            float w2 = W_e1[(size_t)(k4 * 4 + 2) * HDIM + j];
            float w3 = W_e1[(size_t)(k4 * 4 + 3) * HDIM + j];
            float4 x0 = *reinterpret_cast<const float4*>(&spe[0 * HDIM + k4 * 4]);
            float4 x1 = *reinterpret_cast<const float4*>(&spe[1 * HDIM + k4 * 4]);
            float4 x2 = *reinterpret_cast<const float4*>(&spe[2 * HDIM + k4 * 4]);
            float4 x3 = *reinterpret_cast<const float4*>(&spe[3 * HDIM + k4 * 4]);
            a0 += x0.x * w0 + x0.y * w1 + x0.z * w2 + x0.w * w3;
            a1 += x1.x * w0 + x1.y * w1 + x1.z * w2 + x1.w * w3;
            a2 += x2.x * w0 + x2.y * w1 + x2.z * w2 + x2.w * w3;
            a3 += x3.x * w0 + x3.y * w1 + x3.z * w2 + x3.w * w3;
        }
        pW1[(size_t)r[0] * HDIM + j] = 0.5f * a0;
        pW1[(size_t)r[1] * HDIM + j] = 0.5f * a1;
        pW1[(size_t)r[2] * HDIM + j] = 0.5f * a2;
        pW1[(size_t)r[3] * HDIM + j] = 0.5f * a3;
    }
}

// ============ k_nl: [256,512]@[512,1600]+b, 2 batches/block (round-11) =====
__global__ __launch_bounds__(320) void k_nl(const float* __restrict__ n1,
                                            const float* __restrict__ W_n2,
                                            const float* __restrict__ b_n2,
                                            float* __restrict__ out_nl) {
    const int NOUT = NDIM * DDIM;   // 1600
    int t = threadIdx.x;
    int j = blockIdx.y * 320 + t;
    int bg = blockIdx.x;            // 2 batches
    __shared__ float s[2 * HDIM];
    for (int idx = t; idx < 2 * HDIM / 4; idx += 320) {
        int lin = idx * 4;
        int row = lin >> 9, col = lin & 511;
        *reinterpret_cast<float4*>(&s[row * HDIM + col]) =
            *reinterpret_cast<const float4*>(&n1[(size_t)(bg * 2 + row) * HDIM + col]);
    }
    __syncthreads();
    float s0a = 0.f, s0b = 0.f, s1a = 0.f, s1b = 0.f;
    for (int k4 = 0; k4 < HDIM / 4; ++k4) {
        float w0 = W_n2[(size_t)(k4 * 4 + 0) * NOUT + j];
        float w1 = W_n2[(size_t)(k4 * 4 + 1) * NOUT + j];
        float w2 = W_n2[(size_t)(k4 * 4 + 2) * NOUT + j];
        float w3 = W_n2[(size_t)(k4 * 4 + 3) * NOUT + j];
        float4 x0 = *reinterpret_cast<const float4*>(&s[k4 * 4]);
        float4 x1 = *reinterpret_cast<const float4*>(&s[HDIM + k4 * 4]);
        s0a += x0.x * w0 + x0.y * w1;
        s0b += x0.z * w2 + x0.w * w3;
        s1a += x1.x * w0 + x1.y * w1;
        s1b += x1.z * w2 + x1.w * w3;
    }
    float bias = b_n2[j];
    out_nl[(size_t)(bg * 2 + 0) * NOUT + j] = bias + s0a + s0b;
    out_nl[(size_t)(bg * 2 + 1) * NOUT + j] = bias + s1a + s1b;
}

// ============ k_edge: round-11 shape, fp16 consume via v_dot2_f32_f16 ======
// grid (256,3), block 256, LDS ~24.6KB. Produce fp32 -> store _Float16;
// consume v_pk_add/max_f16 + fdot2 (fp32 accum).
__global__ __launch_bounds__(256) void k_edge(
        const float* __restrict__ nl,    // [256,50,32]
        const float* __restrict__ u,     // [256,512]
        const float* __restrict__ pW1,   // [50,512]
        const float* __restrict__ W_e1,  // [576,512]
        const float* __restrict__ b_e1,  // [512]
        const float* __restrict__ W_e2,  // [512,5]
        float* __restrict__ P) {         // [3][256][1225][5]
    int b  = blockIdx.x;
    int rh = blockIdx.y;
    int t  = threadIdx.x;
    int rbase = rh * 192;
    int ECH = (rh < 2) ? 96 : 64;       // chunk cols (2 chunks per block)
    int ech4 = ECH >> 2;

    __shared__ __align__(16) _Float16 Ah[NDIM * 96];   // 9.6 KB
    __shared__ __align__(16) _Float16 Bh[NDIM * 96];   // 9.6 KB
    __shared__ v2h W2h[256][EOUT];                     // 5.12 KB

    // stage W_e2 as half2 r-pairs (256 pairs x 5 outs)
    for (int i = t; i < 256 * EOUT; i += 256) {
        int p = i / EOUT, o = i - p * EOUT;
        v2h w;
        w.x = (_Float16)W_e2[(size_t)(2 * p) * EOUT + o];
        w.y = (_Float16)W_e2[(size_t)(2 * p + 1) * EOUT + o];
        W2h[p][o] = w;
    }

    // task decode: (p,q): rows i0=2p,i0+1; cols j0=3q..3q+2; 225 valid tiles
    bool has = (t < 225);
    int pp = 0, qq = 0;
    if (has) {
        int tt = t;
        for (pp = 0; pp < 25; ++pp) {
            int qmin = pp ? ((2 * pp - 2) / 3 + 1) : 0;
            int cnt = 17 - qmin;
            if (tt < cnt) { qq = qmin + tt; break; }
            tt -= cnt;
        }
    }
    int i0 = 2 * pp, i1 = i0 + 1;
    int j0 = 3 * qq, j1 = j0 + 1, j2r = (3 * qq + 2 < NDIM) ? 3 * qq + 2 : NDIM - 1;

    float acc[6][EOUT];
#pragma unroll
    for (int e = 0; e < 6; ++e)
#pragma unroll
        for (int o = 0; o < EOUT; ++o) acc[e][o] = 0.f;

    bool prod = (t < 2 * ECH);
    int arr = (t >= ECH) ? 1 : 0;
    int c = t - (arr ? ECH : 0);
    const float4* nl4 = reinterpret_cast<const float4*>(nl + (size_t)b * (NDIM * DDIM));

    for (int ch = 0; ch < 2; ++ch) {
        // ---- produce (fp32 math, _Float16 store) ----
        if (prod) {
            int col = rbase + ch * ECH + c;
            float w[DDIM];
#pragma unroll
            for (int k = 0; k < DDIM; ++k)
                w[k] = W_e1[(size_t)(HDIM + arr * DDIM + k) * HDIM + col];
            float cm = 0.5f * (u[(size_t)b * HDIM + col] + b_e1[col]);
            _Float16* dst = arr ? Bh : Ah;
            float pc = pW1[col];   // row 0, rotate-prefetched
            for (int n = 0; n < NDIM; ++n) {
                float pn = (n < NDIM - 1) ? pW1[(size_t)(n + 1) * HDIM + col] : 0.f;
                float s0 = 0.f, s1 = 0.f, s2 = 0.f, s3 = 0.f;
#pragma unroll
                for (int h = 0; h < 2; ++h) {
                    int q = h * 4;
                    float4 xA = nl4[n * 8 + q + 0];
                    float4 xB = nl4[n * 8 + q + 1];
                    float4 xC = nl4[n * 8 + q + 2];
                    float4 xD = nl4[n * 8 + q + 3];
                    s0 += xA.x * w[4*q+0]  + xA.y * w[4*q+1]  + xA.z * w[4*q+2]  + xA.w * w[4*q+3];
                    s1 += xB.x * w[4*q+4]  + xB.y * w[4*q+5]  + xB.z * w[4*q+6]  + xB.w * w[4*q+7];
                    s2 += xC.x * w[4*q+8]  + xC.y * w[4*q+9]  + xC.z * w[4*q+10] + xC.w * w[4*q+11];
                    s3 += xD.x * w[4*q+12] + xD.y * w[4*q+13] + xD.z * w[4*q+14] + xD.w * w[4*q+15];
                }
                float val = (cm + pc) + ((s0 + s1) + (s2 + s3));
                dst[n * ECH + ((((c >> 2) ^ (n & 7)) << 2) | (c & 3))] = (_Float16)val;
                pc = pn;
            }
        }
        __syncthreads();
        // ---- consume (v2h + fdot2) ----
        if (has) {
            int pb0 = (rbase + ch * ECH) >> 1;   // base r-pair index
            int sA = i0 & 7, sB = i1 & 7, s0m = j0 & 7, s1m = j1 & 7, s2m = j2r & 7;
            for (int r4 = 0; r4 < ech4; ++r4) {
                struct h4 { v2h lo, hi; };
                h4 ra0 = *reinterpret_cast<const h4*>(&Ah[i0 * ECH + (((r4 ^ sA) % ech4) << 2)]);
                h4 ra1 = *reinterpret_cast<const h4*>(&Ah[i1 * ECH + (((r4 ^ sB) % ech4) << 2)]);
                h4 rb0 = *reinterpret_cast<const h4*>(&Bh[j0 * ECH + (((r4 ^ s0m) % ech4) << 2)]);
                h4 rb1 = *reinterpret_cast<const h4*>(&Bh[j1 * ECH + (((r4 ^ s1m) % ech4) << 2)]);
                h4 rb2 = *reinterpret_cast<const h4*>(&Bh[j2r * ECH + (((r4 ^ s2m) % ech4) << 2)]);
                v2h v0l = relu2(ra0.lo, rb0.lo), v0h = relu2(ra0.hi, rb0.hi);
                v2h v1l = relu2(ra0.lo, rb1.lo), v1h = relu2(ra0.hi, rb1.hi);
                v2h v2l = relu2(ra0.lo, rb2.lo), v2hh = relu2(ra0.hi, rb2.hi);
                v2h v3l = relu2(ra1.lo, rb0.lo), v3h = relu2(ra1.hi, rb0.hi);
                v2h v4l = relu2(ra1.lo, rb1.lo), v4h = relu2(ra1.hi, rb1.hi);
                v2h v5l = relu2(ra1.lo, rb2.lo), v5h = relu2(ra1.hi, rb2.hi);
                int pb = pb0 + r4 * 2;
#pragma unroll
                for (int o = 0; o < EOUT; ++o) {
                    v2h wl = W2h[pb][o], wh = W2h[pb + 1][o];
                    acc[0][o] = fdot2f(v0h, wh, fdot2f(v0l, wl, acc[0][o]));
                    acc[1][o] = fdot2f(v1h, wh, fdot2f(v1l, wl, acc[1][o]));
                    acc[2][o] = fdot2f(v2hh, wh, fdot2f(v2l, wl, acc[2][o]));
                    acc[3][o] = fdot2f(v3h, wh, fdot2f(v3l, wl, acc[3][o]));
                    acc[4][o] = fdot2f(v4h, wh, fdot2f(v4l, wl, acc[4][o]));
                    acc[5][o] = fdot2f(v5h, wh, fdot2f(v5l, wl, acc[5][o]));
                }
            }
        }
        __syncthreads();
    }

    if (has) {
        float* Pb = P + ((size_t)rh * BSZ + b) * NEDGE * EOUT;
        int js[3] = {j0, j1, 3 * qq + 2};
#pragma unroll
        for (int r = 0; r < 2; ++r) {
            int i = i0 + r;
#pragma unroll
            for (int cc = 0; cc < 3; ++cc) {
                int j = js[cc];
                if (i < j && j < NDIM) {
                    int e = i * (NDIM - 1) - (i * (i - 1)) / 2 + (j - i - 1);
#pragma unroll
                    for (int o = 0; o < EOUT; ++o)
                        Pb[(size_t)e * EOUT + o] = acc[r * 3 + cc][o];
                }
            }
        }
    }
}

// ============ k_comb: out_el = P0+P1+P2 + bias (float4 x5/thread) ==========
__global__ __launch_bounds__(256) void k_comb(const float* __restrict__ P,
                                              const float* __restrict__ b_e2,
                                              float* __restrict__ out_el,
                                              float* __restrict__ out_idx) {
    int blk = blockIdx.x, t = threadIdx.x;
    const size_t PS = (size_t)BSZ * NEDGE * EOUT;
    if (blk < 307) {
        int tid = blk * 256 + t;       // 20 floats per thread; 78400 total
        if (tid < 78400) {
            const float4* p0 = reinterpret_cast<const float4*>(P) + (size_t)tid * 5;
            const float4* p1 = reinterpret_cast<const float4*>(P + PS) + (size_t)tid * 5;
            const float4* p2 = reinterpret_cast<const float4*>(P + 2 * PS) + (size_t)tid * 5;
            float4* o = reinterpret_cast<float4*>(out_el) + (size_t)tid * 5;
            float b5[5];
#pragma unroll
            for (int cc = 0; cc < 5; ++cc) b5[cc] = b_e2[cc];
#pragma unroll
            for (int q = 0; q < 5; ++q) {
                float4 a = p0[q], b = p1[q], cq = p2[q];
                float4 r;
                r.x = a.x + b.x + cq.x + b5[(q * 4 + 0) % 5];
                r.y = a.y + b.y + cq.y + b5[(q * 4 + 1) % 5];
                r.z = a.z + b.z + cq.z + b5[(q * 4 + 2) % 5];
                r.w = a.w + b.w + cq.w + b5[(q * 4 + 3) % 5];
                o[q] = r;
            }
        }
    } else {
        int e = (blk - 307) * 256 + t;
        if (e < NEDGE) {
            int i = 0, rem = e;
            while (rem >= (NDIM - 1 - i)) { rem -= (NDIM - 1 - i); ++i; }
            int j = i + 1 + rem;
            out_idx[e * 2] = (float)i;
            out_idx[e * 2 + 1] = (float)j;
        }
    }
}

extern "C" void kernel_launch(void* const* d_in, const int* in_sizes, int n_in,
                              void* d_out, int out_size, void* d_ws, size_t ws_size,
                              hipStream_t stream) {
    const float* z    = (const float*)d_in[0];
    const float* tp   = (const float*)d_in[1];
    const float* W_in = (const float*)d_in[2];
    const float* b_in = (const float*)d_in[3];
    const float* W_s1 = (const float*)d_in[4];
    const float* b_s1 = (const float*)d_in[5];
    const float* W_s2 = (const float*)d_in[6];
    const float* b_s2 = (const float*)d_in[7];
    const float* W_n1 = (const float*)d_in[8];
    const float* b_n1 = (const float*)d_in[9];
    const float* W_n2 = (const float*)d_in[10];
    const float* b_n2 = (const float*)d_in[11];
    const float* W_e1 = (const float*)d_in[12];
    const float* b_e1 = (const float*)d_in[13];
    const float* W_e2 = (const float*)d_in[14];
    const float* b_e2 = (const float*)d_in[15];
    const float* pe   = (const float*)d_in[16];

    float* out     = (float*)d_out;
    float* out_nl  = out;                 // node_logits
    float* out_el  = out + 409600;        // edge_logits
    float* out_sp  = out + 1977600;       // size_probs
    float* out_idx = out + 1990400;       // edge_indices (as float)

    float* ws  = (float*)d_ws;
    float* u   = ws;
    float* pW1 = ws + 131072;
    float* n1  = ws + 156672;
    float* P   = ws + 287744;             // [3][256][1225][5]

    k_pre<<<666, 256, 0, stream>>>(z, tp, W_in, b_in, W_s1, b_s1, W_s2, b_s2,
                                   W_n1, b_n1, W_e1, pe, n1, u, pW1, out_sp);
    k_nl<<<dim3(128, 5), 320, 0, stream>>>(n1, W_n2, b_n2, out_nl);
    k_edge<<<dim3(BSZ, NRH), 256, 0, stream>>>(out_nl, u, pW1, W_e1, b_e1, W_e2, P);
    k_comb<<<312, 256, 0, stream>>>(P, b_e2, out_el, out_idx);
}

// Round 18
// 137.118 us; speedup vs baseline: 1.1979x; 1.0577x over previous
//
#include <hip/hip_runtime.h>
#include <math.h>

// Problem dims
#define BSZ   256
#define LDIM  128
#define PDIM  3
#define HDIM  512
#define DDIM  32
#define NDIM  50
#define NEDGE 1225   // N*(N-1)/2
#define EOUT  5      // EDIM+1
#define NRH   3      // r-splits: cols {192,192,128}

// out layout (floats)
//   node_logits  [256,50,32]   @ 0        (409600)
//   edge_logits  [256,1225,5]  @ 409600   (1568000)
//   size_probs   [256,50]      @ 1977600  (12800)
//   edge_indices [1225,2]      @ 1990400  (2450, float values)
// ws layout (floats): u @0 (131072), pW1 @131072 (25600), n1 @156672 (131072),
//                     P @287744 (3 x 1568000)

typedef _Float16 v2h __attribute__((ext_vector_type(2)));

__device__ __forceinline__ float fdot2f(v2h a, v2h b, float c) {
    return __builtin_amdgcn_fdot2(a, b, c, false);
}
__device__ __forceinline__ v2h relu2(v2h a, v2h b) {
    v2h s = a + b;                       // v_pk_add_f16
    v2h z = {(_Float16)0.f, (_Float16)0.f};
    return __builtin_elementwise_max(s, z);   // v_pk_max_f16
}
struct h4 { v2h lo, hi; };

// ============ k_pre: 256-thr blocks, col-split roles (round-11, proven) ====
__global__ __launch_bounds__(256) void k_pre(
        const float* __restrict__ z, const float* __restrict__ tp,
        const float* __restrict__ W_in, const float* __restrict__ b_in,
        const float* __restrict__ W_s1, const float* __restrict__ b_s1,
        const float* __restrict__ W_s2, const float* __restrict__ b_s2,
        const float* __restrict__ W_n1, const float* __restrict__ b_n1,
        const float* __restrict__ W_e1, const float* __restrict__ pe,
        float* __restrict__ n1, float* __restrict__ u,
        float* __restrict__ pW1, float* __restrict__ out_sp) {
    int bx = blockIdx.x, t = threadIdx.x;
    __shared__ float smem[2368];

    if (bx < 512) {
        int role = bx >> 8;
        int idx2 = bx & 255;
        int bg = idx2 >> 1, jh = idx2 & 1;
        int b0 = bg * 2;
        float* sin_ = smem;            // [2][132]
        float* sh   = smem + 264;      // [2][512]
        for (int q = t; q < 2 * 131; q += 256) {
            int bi = q / 131, k = q % 131;
            sin_[bi * 132 + k] = (k < LDIM) ? z[(size_t)(b0 + bi) * LDIM + k]
                                            : tp[(size_t)(b0 + bi) * PDIM + (k - LDIM)];
        }
        __syncthreads();
        {
            float bi0 = b_in[t], bi1 = b_in[t + 256];
            float a00 = bi0, a01 = bi1, a10 = bi0, a11 = bi1;
            for (int k = 0; k < LDIM + PDIM; ++k) {
                float w0 = W_in[(size_t)k * HDIM + t];
                float w1 = W_in[(size_t)k * HDIM + t + 256];
                float x0 = sin_[k], x1 = sin_[132 + k];
                a00 += x0 * w0; a01 += x0 * w1;
                a10 += x1 * w0; a11 += x1 * w1;
            }
            sh[t] = fmaxf(a00, 0.f); sh[t + 256] = fmaxf(a01, 0.f);
            sh[512 + t] = fmaxf(a10, 0.f); sh[512 + t + 256] = fmaxf(a11, 0.f);
        }
        __syncthreads();
        int j = jh * 256 + t;
        const float* W = role ? W_e1 : W_n1;   // W1h = rows 0..511 of W_e1
        float s0a = 0.f, s0b = 0.f, s1a = 0.f, s1b = 0.f;
        for (int k4 = 0; k4 < HDIM / 4; ++k4) {
            float w0 = W[(size_t)(k4 * 4 + 0) * HDIM + j];
            float w1 = W[(size_t)(k4 * 4 + 1) * HDIM + j];
            float w2 = W[(size_t)(k4 * 4 + 2) * HDIM + j];
            float w3 = W[(size_t)(k4 * 4 + 3) * HDIM + j];
            float4 x0 = *reinterpret_cast<const float4*>(&sh[k4 * 4]);
            float4 x1 = *reinterpret_cast<const float4*>(&sh[512 + k4 * 4]);
            s0a += x0.x * w0 + x0.y * w1;
            s0b += x0.z * w2 + x0.w * w3;
            s1a += x1.x * w0 + x1.y * w1;
            s1b += x1.z * w2 + x1.w * w3;
        }
        float a0 = s0a + s0b, a1 = s1a + s1b;
        if (role == 0) {
            float bb = b_n1[j];
            n1[(size_t)(b0 + 0) * HDIM + j] = fmaxf(a0 + bb, 0.f);
            n1[(size_t)(b0 + 1) * HDIM + j] = fmaxf(a1 + bb, 0.f);
        } else {
            u[(size_t)(b0 + 0) * HDIM + j] = a0;
            u[(size_t)(b0 + 1) * HDIM + j] = a1;
        }
    } else if (bx < 640) {
        // ---- role size head: 2 batches ------------------------------------
        int b0 = (bx - 512) * 2;
        float* sin_ = smem;            // [2][132]
        float* sh   = smem + 264;      // [2][512]
        float* s1b  = smem + 264 + 1024;  // [2][256]
        float* slg  = smem + 264 + 1024 + 512;  // [2][50]
        for (int q = t; q < 2 * 131; q += 256) {
            int bi = q / 131, k = q % 131;
            sin_[bi * 132 + k] = (k < LDIM) ? z[(size_t)(b0 + bi) * LDIM + k]
                                            : tp[(size_t)(b0 + bi) * PDIM + (k - LDIM)];
        }
        __syncthreads();
        {
            float bi0 = b_in[t], bi1 = b_in[t + 256];
            float a00 = bi0, a01 = bi1, a10 = bi0, a11 = bi1;
            for (int k = 0; k < LDIM + PDIM; ++k) {
                float w0 = W_in[(size_t)k * HDIM + t];
                float w1 = W_in[(size_t)k * HDIM + t + 256];
                float x0 = sin_[k], x1 = sin_[132 + k];
                a00 += x0 * w0; a01 += x0 * w1;
                a10 += x1 * w0; a11 += x1 * w1;
            }
            sh[t] = fmaxf(a00, 0.f); sh[t + 256] = fmaxf(a01, 0.f);
            sh[512 + t] = fmaxf(a10, 0.f); sh[512 + t + 256] = fmaxf(a11, 0.f);
        }
        __syncthreads();
        {
            float bv = b_s1[t];
            float a0 = bv, a1 = bv;
            for (int k = 0; k < HDIM; ++k) {
                float w = W_s1[(size_t)k * (HDIM / 2) + t];
                a0 += sh[k] * w;
                a1 += sh[512 + k] * w;
            }
            s1b[t] = fmaxf(a0, 0.f);
            s1b[256 + t] = fmaxf(a1, 0.f);
        }
        __syncthreads();
        int b4 = t / NDIM, o = t % NDIM;
        if (t < 2 * NDIM) {
            float a = b_s2[o];
            for (int k = 0; k < HDIM / 2; ++k)
                a += s1b[b4 * 256 + k] * W_s2[(size_t)k * NDIM + o];
            slg[b4 * NDIM + o] = a;
        }
        __syncthreads();
        if (t < 2 * NDIM) {
            float m = slg[b4 * NDIM];
            for (int k = 1; k < NDIM; ++k) m = fmaxf(m, slg[b4 * NDIM + k]);
            float s = 0.f;
            for (int k = 0; k < NDIM; ++k) s += expf(slg[b4 * NDIM + k] - m);
            out_sp[(size_t)(b0 + b4) * NDIM + o] = expf(slg[b4 * NDIM + o] - m) / s;
        }
    } else {
        // ---- role pW1: 0.5 * pe @ W1h, 4 rows x 256-col half --------------
        int g = bx - 640, rg = g >> 1, jh = g & 1;
        int r[4];
#pragma unroll
        for (int q = 0; q < 4; ++q) { int rr = rg * 4 + q; r[q] = (rr < NDIM) ? rr : NDIM - 1; }
        float* spe = smem;   // [4][512]
        for (int q = t; q < 4 * HDIM / 4; q += 256) {
            int lin = q * 4, row = lin >> 9, col = lin & 511;
            *reinterpret_cast<float4*>(&spe[row * HDIM + col]) =
                *reinterpret_cast<const float4*>(&pe[(size_t)r[row] * HDIM + col]);
        }
        __syncthreads();
        int j = jh * 256 + t;
        float a0 = 0.f, a1 = 0.f, a2 = 0.f, a3 = 0.f;
        for (int k4 = 0; k4 < HDIM / 4; ++k4) {
            float w0 = W_e1[(size_t)(k4 * 4 + 0) * HDIM + j];
            float w1 = W_e1[(size_t)(k4 * 4 + 1) * HDIM + j];
            float w2 = W_e1[(size_t)(k4 * 4 + 2) * HDIM + j];
            float w3 = W_e1[(size_t)(k4 * 4 + 3) * HDIM + j];
            float4 x0 = *reinterpret_cast<const float4*>(&spe[0 * HDIM + k4 * 4]);
            float4 x1 = *reinterpret_cast<const float4*>(&spe[1 * HDIM + k4 * 4]);
            float4 x2 = *reinterpret_cast<const float4*>(&spe[2 * HDIM + k4 * 4]);
            float4 x3 = *reinterpret_cast<const float4*>(&spe[3 * HDIM + k4 * 4]);
            a0 += x0.x * w0 + x0.y * w1 + x0.z * w2 + x0.w * w3;
            a1 += x1.x * w0 + x1.y * w1 + x1.z * w2 + x1.w * w3;
            a2 += x2.x * w0 + x2.y * w1 + x2.z * w2 + x2.w * w3;
            a3 += x3.x * w0 + x3.y * w1 + x3.z * w2 + x3.w * w3;
        }
        pW1[(size_t)r[0] * HDIM + j] = 0.5f * a0;
        pW1[(size_t)r[1] * HDIM + j] = 0.5f * a1;
        pW1[(size_t)r[2] * HDIM + j] = 0.5f * a2;
        pW1[(size_t)r[3] * HDIM + j] = 0.5f * a3;
    }
}

// ============ k_nl: [256,512]@[512,1600]+b, 2 batches/block (round-11) =====
__global__ __launch_bounds__(320) void k_nl(const float* __restrict__ n1,
                                            const float* __restrict__ W_n2,
                                            const float* __restrict__ b_n2,
                                            float* __restrict__ out_nl) {
    const int NOUT = NDIM * DDIM;   // 1600
    int t = threadIdx.x;
    int j = blockIdx.y * 320 + t;
    int bg = blockIdx.x;            // 2 batches
    __shared__ float s[2 * HDIM];
    for (int idx = t; idx < 2 * HDIM / 4; idx += 320) {
        int lin = idx * 4;
        int row = lin >> 9, col = lin & 511;
        *reinterpret_cast<float4*>(&s[row * HDIM + col]) =
            *reinterpret_cast<const float4*>(&n1[(size_t)(bg * 2 + row) * HDIM + col]);
    }
    __syncthreads();
    float s0a = 0.f, s0b = 0.f, s1a = 0.f, s1b = 0.f;
    for (int k4 = 0; k4 < HDIM / 4; ++k4) {
        float w0 = W_n2[(size_t)(k4 * 4 + 0) * NOUT + j];
        float w1 = W_n2[(size_t)(k4 * 4 + 1) * NOUT + j];
        float w2 = W_n2[(size_t)(k4 * 4 + 2) * NOUT + j];
        float w3 = W_n2[(size_t)(k4 * 4 + 3) * NOUT + j];
        float4 x0 = *reinterpret_cast<const float4*>(&s[k4 * 4]);
        float4 x1 = *reinterpret_cast<const float4*>(&s[HDIM + k4 * 4]);
        s0a += x0.x * w0 + x0.y * w1;
        s0b += x0.z * w2 + x0.w * w3;
        s1a += x1.x * w0 + x1.y * w1;
        s1b += x1.z * w2 + x1.w * w3;
    }
    float bias = b_n2[j];
    out_nl[(size_t)(bg * 2 + 0) * NOUT + j] = bias + s0a + s0b;
    out_nl[(size_t)(bg * 2 + 1) * NOUT + j] = bias + s1a + s1b;
}

// ============ k_edge: fp16 consume, compile-time ECH (no runtime modulo) ===
template<int ECH>
__device__ __forceinline__ void edge_chunk(
        int b, int rh, int rbase, int t,
        const float* __restrict__ nl, const float* __restrict__ u,
        const float* __restrict__ pW1, const float* __restrict__ W_e1,
        const float* __restrict__ b_e1, float* __restrict__ P,
        _Float16* Ah, _Float16* Bh, const v2h (*W2h)[EOUT]) {
    constexpr int ech4 = ECH / 4;
    // task decode: (p,q): rows i0=2p,i0+1; cols j0=3q..3q+2; 225 valid tiles
    bool has = (t < 225);
    int pp = 0, qq = 0;
    if (has) {
        int tt = t;
        for (pp = 0; pp < 25; ++pp) {
            int qmin = pp ? ((2 * pp - 2) / 3 + 1) : 0;
            int cnt = 17 - qmin;
            if (tt < cnt) { qq = qmin + tt; break; }
            tt -= cnt;
        }
    }
    int i0 = 2 * pp, i1 = i0 + 1;
    int j0 = 3 * qq, j1 = j0 + 1, j2r = (3 * qq + 2 < NDIM) ? 3 * qq + 2 : NDIM - 1;

    float acc[6][EOUT];
#pragma unroll
    for (int e = 0; e < 6; ++e)
#pragma unroll
        for (int o = 0; o < EOUT; ++o) acc[e][o] = 0.f;

    bool prod = (t < 2 * ECH);
    int arr = (t >= ECH) ? 1 : 0;
    int c = t - (arr ? ECH : 0);
    const float4* nl4 = reinterpret_cast<const float4*>(nl + (size_t)b * (NDIM * DDIM));

    for (int ch = 0; ch < 2; ++ch) {
        // ---- produce (fp32 math, _Float16 store) ----
        if (prod) {
            int col = rbase + ch * ECH + c;
            float w[DDIM];
#pragma unroll
            for (int k = 0; k < DDIM; ++k)
                w[k] = W_e1[(size_t)(HDIM + arr * DDIM + k) * HDIM + col];
            float cm = 0.5f * (u[(size_t)b * HDIM + col] + b_e1[col]);
            _Float16* dst = arr ? Bh : Ah;
            float pc = pW1[col];
            for (int n = 0; n < NDIM; ++n) {
                float pn = (n < NDIM - 1) ? pW1[(size_t)(n + 1) * HDIM + col] : 0.f;
                float s0 = 0.f, s1 = 0.f, s2 = 0.f, s3 = 0.f;
#pragma unroll
                for (int h = 0; h < 2; ++h) {
                    int q = h * 4;
                    float4 xA = nl4[n * 8 + q + 0];
                    float4 xB = nl4[n * 8 + q + 1];
                    float4 xC = nl4[n * 8 + q + 2];
                    float4 xD = nl4[n * 8 + q + 3];
                    s0 += xA.x * w[4*q+0]  + xA.y * w[4*q+1]  + xA.z * w[4*q+2]  + xA.w * w[4*q+3];
                    s1 += xB.x * w[4*q+4]  + xB.y * w[4*q+5]  + xB.z * w[4*q+6]  + xB.w * w[4*q+7];
                    s2 += xC.x * w[4*q+8]  + xC.y * w[4*q+9]  + xC.z * w[4*q+10] + xC.w * w[4*q+11];
                    s3 += xD.x * w[4*q+12] + xD.y * w[4*q+13] + xD.z * w[4*q+14] + xD.w * w[4*q+15];
                }
                float val = (cm + pc) + ((s0 + s1) + (s2 + s3));
                dst[n * ECH + ((((c >> 2) ^ (n & 7)) << 2) | (c & 3))] = (_Float16)val;
                pc = pn;
            }
        }
        __syncthreads();
        // ---- consume (v2h + fdot2, compile-time indices) ----
        if (has) {
            int pb0 = (rbase + ch * ECH) >> 1;   // base r-pair index
            int sA = i0 & 7, sB = i1 & 7, s0m = j0 & 7, s1m = j1 & 7, s2m = j2r & 7;
            for (int r4 = 0; r4 < ech4; ++r4) {
                h4 ra0 = *reinterpret_cast<const h4*>(&Ah[i0 * ECH + ((r4 ^ sA) << 2)]);
                h4 ra1 = *reinterpret_cast<const h4*>(&Ah[i1 * ECH + ((r4 ^ sB) << 2)]);
                h4 rb0 = *reinterpret_cast<const h4*>(&Bh[j0 * ECH + ((r4 ^ s0m) << 2)]);
                h4 rb1 = *reinterpret_cast<const h4*>(&Bh[j1 * ECH + ((r4 ^ s1m) << 2)]);
                h4 rb2 = *reinterpret_cast<const h4*>(&Bh[j2r * ECH + ((r4 ^ s2m) << 2)]);
                v2h v0l = relu2(ra0.lo, rb0.lo), v0h = relu2(ra0.hi, rb0.hi);
                v2h v1l = relu2(ra0.lo, rb1.lo), v1h = relu2(ra0.hi, rb1.hi);
                v2h v2l = relu2(ra0.lo, rb2.lo), v2hh = relu2(ra0.hi, rb2.hi);
                v2h v3l = relu2(ra1.lo, rb0.lo), v3h = relu2(ra1.hi, rb0.hi);
                v2h v4l = relu2(ra1.lo, rb1.lo), v4h = relu2(ra1.hi, rb1.hi);
                v2h v5l = relu2(ra1.lo, rb2.lo), v5h = relu2(ra1.hi, rb2.hi);
                int pb = pb0 + r4 * 2;
#pragma unroll
                for (int o = 0; o < EOUT; ++o) {
                    v2h wl = W2h[pb][o], wh = W2h[pb + 1][o];
                    acc[0][o] = fdot2f(v0h, wh, fdot2f(v0l, wl, acc[0][o]));
                    acc[1][o] = fdot2f(v1h, wh, fdot2f(v1l, wl, acc[1][o]));
                    acc[2][o] = fdot2f(v2hh, wh, fdot2f(v2l, wl, acc[2][o]));
                    acc[3][o] = fdot2f(v3h, wh, fdot2f(v3l, wl, acc[3][o]));
                    acc[4][o] = fdot2f(v4h, wh, fdot2f(v4l, wl, acc[4][o]));
                    acc[5][o] = fdot2f(v5h, wh, fdot2f(v5l, wl, acc[5][o]));
                }
            }
        }
        __syncthreads();
    }

    if (has) {
        float* Pb = P + ((size_t)rh * BSZ + b) * NEDGE * EOUT;
        int js[3] = {j0, j1, 3 * qq + 2};
#pragma unroll
        for (int r = 0; r < 2; ++r) {
            int i = i0 + r;
#pragma unroll
            for (int cc = 0; cc < 3; ++cc) {
                int j = js[cc];
                if (i < j && j < NDIM) {
                    int e = i * (NDIM - 1) - (i * (i - 1)) / 2 + (j - i - 1);
#pragma unroll
                    for (int o = 0; o < EOUT; ++o)
                        Pb[(size_t)e * EOUT + o] = acc[r * 3 + cc][o];
                }
            }
        }
    }
}

__global__ __launch_bounds__(256) void k_edge(
        const float* __restrict__ nl,    // [256,50,32]
        const float* __restrict__ u,     // [256,512]
        const float* __restrict__ pW1,   // [50,512]
        const float* __restrict__ W_e1,  // [576,512]
        const float* __restrict__ b_e1,  // [512]
        const float* __restrict__ W_e2,  // [512,5]
        float* __restrict__ P) {         // [3][256][1225][5]
    int b  = blockIdx.x;
    int rh = blockIdx.y;
    int t  = threadIdx.x;

    __shared__ __align__(16) _Float16 Ah[NDIM * 96];   // 9.6 KB
    __shared__ __align__(16) _Float16 Bh[NDIM * 96];   // 9.6 KB
    __shared__ v2h W2h[256][EOUT];                     // 5.12 KB

    // stage W_e2 as half2 r-pairs (256 pairs x 5 outs)
    for (int i = t; i < 256 * EOUT; i += 256) {
        int p = i / EOUT, o = i - p * EOUT;
        v2h w;
        w.x = (_Float16)W_e2[(size_t)(2 * p) * EOUT + o];
        w.y = (_Float16)W_e2[(size_t)(2 * p + 1) * EOUT + o];
        W2h[p][o] = w;
    }

    if (rh < 2)
        edge_chunk<96>(b, rh, rh * 192, t, nl, u, pW1, W_e1, b_e1, P, Ah, Bh, W2h);
    else
        edge_chunk<64>(b, rh, 384, t, nl, u, pW1, W_e1, b_e1, P, Ah, Bh, W2h);
}

// ============ k_comb: out_el = P0+P1+P2 + bias (float4 x5/thread) ==========
__global__ __launch_bounds__(256) void k_comb(const float* __restrict__ P,
                                              const float* __restrict__ b_e2,
                                              float* __restrict__ out_el,
                                              float* __restrict__ out_idx) {
    int blk = blockIdx.x, t = threadIdx.x;
    const size_t PS = (size_t)BSZ * NEDGE * EOUT;
    if (blk < 307) {
        int tid = blk * 256 + t;       // 20 floats per thread; 78400 total
        if (tid < 78400) {
            const float4* p0 = reinterpret_cast<const float4*>(P) + (size_t)tid * 5;
            const float4* p1 = reinterpret_cast<const float4*>(P + PS) + (size_t)tid * 5;
            const float4* p2 = reinterpret_cast<const float4*>(P + 2 * PS) + (size_t)tid * 5;
            float4* o = reinterpret_cast<float4*>(out_el) + (size_t)tid * 5;
            float b5[5];
#pragma unroll
            for (int cc = 0; cc < 5; ++cc) b5[cc] = b_e2[cc];
#pragma unroll
            for (int q = 0; q < 5; ++q) {
                float4 a = p0[q], b = p1[q], cq = p2[q];
                float4 r;
                r.x = a.x + b.x + cq.x + b5[(q * 4 + 0) % 5];
                r.y = a.y + b.y + cq.y + b5[(q * 4 + 1) % 5];
                r.z = a.z + b.z + cq.z + b5[(q * 4 + 2) % 5];
                r.w = a.w + b.w + cq.w + b5[(q * 4 + 3) % 5];
                o[q] = r;
            }
        }
    } else {
        int e = (blk - 307) * 256 + t;
        if (e < NEDGE) {
            int i = 0, rem = e;
            while (rem >= (NDIM - 1 - i)) { rem -= (NDIM - 1 - i); ++i; }
            int j = i + 1 + rem;
            out_idx[e * 2] = (float)i;
            out_idx[e * 2 + 1] = (float)j;
        }
    }
}

extern "C" void kernel_launch(void* const* d_in, const int* in_sizes, int n_in,
                              void* d_out, int out_size, void* d_ws, size_t ws_size,
                              hipStream_t stream) {
    const float* z    = (const float*)d_in[0];
    const float* tp   = (const float*)d_in[1];
    const float* W_in = (const float*)d_in[2];
    const float* b_in = (const float*)d_in[3];
    const float* W_s1 = (const float*)d_in[4];
    const float* b_s1 = (const float*)d_in[5];
    const float* W_s2 = (const float*)d_in[6];
    const float* b_s2 = (const float*)d_in[7];
    const float* W_n1 = (const float*)d_in[8];
    const float* b_n1 = (const float*)d_in[9];
    const float* W_n2 = (const float*)d_in[10];
    const float* b_n2 = (const float*)d_in[11];
    const float* W_e1 = (const float*)d_in[12];
    const float* b_e1 = (const float*)d_in[13];
    const float* W_e2 = (const float*)d_in[14];
    const float* b_e2 = (const float*)d_in[15];
    const float* pe   = (const float*)d_in[16];

    float* out     = (float*)d_out;
    float* out_nl  = out;                 // node_logits
    float* out_el  = out + 409600;        // edge_logits
    float* out_sp  = out + 1977600;       // size_probs
    float* out_idx = out + 1990400;       // edge_indices (as float)

    float* ws  = (float*)d_ws;
    float* u   = ws;
    float* pW1 = ws + 131072;
    float* n1  = ws + 156672;
    float* P   = ws + 287744;             // [3][256][1225][5]

    k_pre<<<666, 256, 0, stream>>>(z, tp, W_in, b_in, W_s1, b_s1, W_s2, b_s2,
                                   W_n1, b_n1, W_e1, pe, n1, u, pW1, out_sp);
    k_nl<<<dim3(128, 5), 320, 0, stream>>>(n1, W_n2, b_n2, out_nl);
    k_edge<<<dim3(BSZ, NRH), 256, 0, stream>>>(out_nl, u, pW1, W_e1, b_e1, W_e2, P);
    k_comb<<<312, 256, 0, stream>>>(P, b_e2, out_el, out_idx);
}

// Round 19
// 134.456 us; speedup vs baseline: 1.2216x; 1.0198x over previous
//
#include <hip/hip_runtime.h>
#include <math.h>

// Problem dims
#define BSZ   256
#define LDIM  128
#define PDIM  3
#define HDIM  512
#define DDIM  32
#define NDIM  50
#define NEDGE 1225   // N*(N-1)/2
#define EOUT  5      // EDIM+1
#define NRH   3      // r-splits: cols {192,192,128}

// out layout (floats)
//   node_logits  [256,50,32]   @ 0        (409600)
//   edge_logits  [256,1225,5]  @ 409600   (1568000)
//   size_probs   [256,50]      @ 1977600  (12800)
//   edge_indices [1225,2]      @ 1990400  (2450, float values)
// ws layout (floats): u @0 (131072), pW1 @131072 (25600), n1 @156672 (131072),
//                     P @287744 (3 x 1568000), nl_h @4991744 (204800 fl = 409600 f16)

typedef _Float16 v2h __attribute__((ext_vector_type(2)));

__device__ __forceinline__ float fdot2f(v2h a, v2h b, float c) {
    return __builtin_amdgcn_fdot2(a, b, c, false);
}
__device__ __forceinline__ v2h relu2(v2h a, v2h b) {
    v2h s = a + b;                       // v_pk_add_f16
    v2h z = {(_Float16)0.f, (_Float16)0.f};
    return __builtin_elementwise_max(s, z);   // v_pk_max_f16
}
struct h4 { v2h lo, hi; };

// ============ k_pre: 256-thr blocks, col-split roles (round-11, proven) ====
__global__ __launch_bounds__(256) void k_pre(
        const float* __restrict__ z, const float* __restrict__ tp,
        const float* __restrict__ W_in, const float* __restrict__ b_in,
        const float* __restrict__ W_s1, const float* __restrict__ b_s1,
        const float* __restrict__ W_s2, const float* __restrict__ b_s2,
        const float* __restrict__ W_n1, const float* __restrict__ b_n1,
        const float* __restrict__ W_e1, const float* __restrict__ pe,
        float* __restrict__ n1, float* __restrict__ u,
        float* __restrict__ pW1, float* __restrict__ out_sp) {
    int bx = blockIdx.x, t = threadIdx.x;
    __shared__ float smem[2368];

    if (bx < 512) {
        int role = bx >> 8;
        int idx2 = bx & 255;
        int bg = idx2 >> 1, jh = idx2 & 1;
        int b0 = bg * 2;
        float* sin_ = smem;            // [2][132]
        float* sh   = smem + 264;      // [2][512]
        for (int q = t; q < 2 * 131; q += 256) {
            int bi = q / 131, k = q % 131;
            sin_[bi * 132 + k] = (k < LDIM) ? z[(size_t)(b0 + bi) * LDIM + k]
                                            : tp[(size_t)(b0 + bi) * PDIM + (k - LDIM)];
        }
        __syncthreads();
        {
            float bi0 = b_in[t], bi1 = b_in[t + 256];
            float a00 = bi0, a01 = bi1, a10 = bi0, a11 = bi1;
            for (int k = 0; k < LDIM + PDIM; ++k) {
                float w0 = W_in[(size_t)k * HDIM + t];
                float w1 = W_in[(size_t)k * HDIM + t + 256];
                float x0 = sin_[k], x1 = sin_[132 + k];
                a00 += x0 * w0; a01 += x0 * w1;
                a10 += x1 * w0; a11 += x1 * w1;
            }
            sh[t] = fmaxf(a00, 0.f); sh[t + 256] = fmaxf(a01, 0.f);
            sh[512 + t] = fmaxf(a10, 0.f); sh[512 + t + 256] = fmaxf(a11, 0.f);
        }
        __syncthreads();
        int j = jh * 256 + t;
        const float* W = role ? W_e1 : W_n1;   // W1h = rows 0..511 of W_e1
        float s0a = 0.f, s0b = 0.f, s1a = 0.f, s1b = 0.f;
        for (int k4 = 0; k4 < HDIM / 4; ++k4) {
            float w0 = W[(size_t)(k4 * 4 + 0) * HDIM + j];
            float w1 = W[(size_t)(k4 * 4 + 1) * HDIM + j];
            float w2 = W[(size_t)(k4 * 4 + 2) * HDIM + j];
            float w3 = W[(size_t)(k4 * 4 + 3) * HDIM + j];
            float4 x0 = *reinterpret_cast<const float4*>(&sh[k4 * 4]);
            float4 x1 = *reinterpret_cast<const float4*>(&sh[512 + k4 * 4]);
            s0a += x0.x * w0 + x0.y * w1;
            s0b += x0.z * w2 + x0.w * w3;
            s1a += x1.x * w0 + x1.y * w1;
            s1b += x1.z * w2 + x1.w * w3;
        }
        float a0 = s0a + s0b, a1 = s1a + s1b;
        if (role == 0) {
            float bb = b_n1[j];
            n1[(size_t)(b0 + 0) * HDIM + j] = fmaxf(a0 + bb, 0.f);
            n1[(size_t)(b0 + 1) * HDIM + j] = fmaxf(a1 + bb, 0.f);
        } else {
            u[(size_t)(b0 + 0) * HDIM + j] = a0;
            u[(size_t)(b0 + 1) * HDIM + j] = a1;
        }
    } else if (bx < 640) {
        // ---- role size head: 2 batches ------------------------------------
        int b0 = (bx - 512) * 2;
        float* sin_ = smem;            // [2][132]
        float* sh   = smem + 264;      // [2][512]
        float* s1b  = smem + 264 + 1024;  // [2][256]
        float* slg  = smem + 264 + 1024 + 512;  // [2][50]
        for (int q = t; q < 2 * 131; q += 256) {
            int bi = q / 131, k = q % 131;
            sin_[bi * 132 + k] = (k < LDIM) ? z[(size_t)(b0 + bi) * LDIM + k]
                                            : tp[(size_t)(b0 + bi) * PDIM + (k - LDIM)];
        }
        __syncthreads();
        {
            float bi0 = b_in[t], bi1 = b_in[t + 256];
            float a00 = bi0, a01 = bi1, a10 = bi0, a11 = bi1;
            for (int k = 0; k < LDIM + PDIM; ++k) {
                float w0 = W_in[(size_t)k * HDIM + t];
                float w1 = W_in[(size_t)k * HDIM + t + 256];
                float x0 = sin_[k], x1 = sin_[132 + k];
                a00 += x0 * w0; a01 += x0 * w1;
                a10 += x1 * w0; a11 += x1 * w1;
            }
            sh[t] = fmaxf(a00, 0.f); sh[t + 256] = fmaxf(a01, 0.f);
            sh[512 + t] = fmaxf(a10, 0.f); sh[512 + t + 256] = fmaxf(a11, 0.f);
        }
        __syncthreads();
        {
            float bv = b_s1[t];
            float a0 = bv, a1 = bv;
            for (int k = 0; k < HDIM; ++k) {
                float w = W_s1[(size_t)k * (HDIM / 2) + t];
                a0 += sh[k] * w;
                a1 += sh[512 + k] * w;
            }
            s1b[t] = fmaxf(a0, 0.f);
            s1b[256 + t] = fmaxf(a1, 0.f);
        }
        __syncthreads();
        int b4 = t / NDIM, o = t % NDIM;
        if (t < 2 * NDIM) {
            float a = b_s2[o];
            for (int k = 0; k < HDIM / 2; ++k)
                a += s1b[b4 * 256 + k] * W_s2[(size_t)k * NDIM + o];
            slg[b4 * NDIM + o] = a;
        }
        __syncthreads();
        if (t < 2 * NDIM) {
            float m = slg[b4 * NDIM];
            for (int k = 1; k < NDIM; ++k) m = fmaxf(m, slg[b4 * NDIM + k]);
            float s = 0.f;
            for (int k = 0; k < NDIM; ++k) s += expf(slg[b4 * NDIM + k] - m);
            out_sp[(size_t)(b0 + b4) * NDIM + o] = expf(slg[b4 * NDIM + o] - m) / s;
        }
    } else {
        // ---- role pW1: 0.5 * pe @ W1h, 4 rows x 256-col half --------------
        int g = bx - 640, rg = g >> 1, jh = g & 1;
        int r[4];
#pragma unroll
        for (int q = 0; q < 4; ++q) { int rr = rg * 4 + q; r[q] = (rr < NDIM) ? rr : NDIM - 1; }
        float* spe = smem;   // [4][512]
        for (int q = t; q < 4 * HDIM / 4; q += 256) {
            int lin = q * 4, row = lin >> 9, col = lin & 511;
            *reinterpret_cast<float4*>(&spe[row * HDIM + col]) =
                *reinterpret_cast<const float4*>(&pe[(size_t)r[row] * HDIM + col]);
        }
        __syncthreads();
        int j = jh * 256 + t;
        float a0 = 0.f, a1 = 0.f, a2 = 0.f, a3 = 0.f;
        for (int k4 = 0; k4 < HDIM / 4; ++k4) {
            float w0 = W_e1[(size_t)(k4 * 4 + 0) * HDIM + j];
            float w1 = W_e1[(size_t)(k4 * 4 + 1) * HDIM + j];
            float w2 = W_e1[(size_t)(k4 * 4 + 2) * HDIM + j];
            float w3 = W_e1[(size_t)(k4 * 4 + 3) * HDIM + j];
            float4 x0 = *reinterpret_cast<const float4*>(&spe[0 * HDIM + k4 * 4]);
            float4 x1 = *reinterpret_cast<const float4*>(&spe[1 * HDIM + k4 * 4]);
            float4 x2 = *reinterpret_cast<const float4*>(&spe[2 * HDIM + k4 * 4]);
            float4 x3 = *reinterpret_cast<const float4*>(&spe[3 * HDIM + k4 * 4]);
            a0 += x0.x * w0 + x0.y * w1 + x0.z * w2 + x0.w * w3;
            a1 += x1.x * w0 + x1.y * w1 + x1.z * w2 + x1.w * w3;
            a2 += x2.x * w0 + x2.y * w1 + x2.z * w2 + x2.w * w3;
            a3 += x3.x * w0 + x3.y * w1 + x3.z * w2 + x3.w * w3;
        }
        pW1[(size_t)r[0] * HDIM + j] = 0.5f * a0;
        pW1[(size_t)r[1] * HDIM + j] = 0.5f * a1;
        pW1[(size_t)r[2] * HDIM + j] = 0.5f * a2;
        pW1[(size_t)r[3] * HDIM + j] = 0.5f * a3;
    }
}

// ============ k_nl: [256,512]@[512,1600]+b, 2 batches/block ================
// Also writes fp16 copy of node_logits for the edge kernel's produce phase.
__global__ __launch_bounds__(320) void k_nl(const float* __restrict__ n1,
                                            const float* __restrict__ W_n2,
                                            const float* __restrict__ b_n2,
                                            float* __restrict__ out_nl,
                                            _Float16* __restrict__ nl_h) {
    const int NOUT = NDIM * DDIM;   // 1600
    int t = threadIdx.x;
    int j = blockIdx.y * 320 + t;
    int bg = blockIdx.x;            // 2 batches
    __shared__ float s[2 * HDIM];
    for (int idx = t; idx < 2 * HDIM / 4; idx += 320) {
        int lin = idx * 4;
        int row = lin >> 9, col = lin & 511;
        *reinterpret_cast<float4*>(&s[row * HDIM + col]) =
            *reinterpret_cast<const float4*>(&n1[(size_t)(bg * 2 + row) * HDIM + col]);
    }
    __syncthreads();
    float s0a = 0.f, s0b = 0.f, s1a = 0.f, s1b = 0.f;
    for (int k4 = 0; k4 < HDIM / 4; ++k4) {
        float w0 = W_n2[(size_t)(k4 * 4 + 0) * NOUT + j];
        float w1 = W_n2[(size_t)(k4 * 4 + 1) * NOUT + j];
        float w2 = W_n2[(size_t)(k4 * 4 + 2) * NOUT + j];
        float w3 = W_n2[(size_t)(k4 * 4 + 3) * NOUT + j];
        float4 x0 = *reinterpret_cast<const float4*>(&s[k4 * 4]);
        float4 x1 = *reinterpret_cast<const float4*>(&s[HDIM + k4 * 4]);
        s0a += x0.x * w0 + x0.y * w1;
        s0b += x0.z * w2 + x0.w * w3;
        s1a += x1.x * w0 + x1.y * w1;
        s1b += x1.z * w2 + x1.w * w3;
    }
    float bias = b_n2[j];
    float r0 = bias + s0a + s0b;
    float r1 = bias + s1a + s1b;
    out_nl[(size_t)(bg * 2 + 0) * NOUT + j] = r0;
    out_nl[(size_t)(bg * 2 + 1) * NOUT + j] = r1;
    nl_h[(size_t)(bg * 2 + 0) * NOUT + j] = (_Float16)r0;
    nl_h[(size_t)(bg * 2 + 1) * NOUT + j] = (_Float16)r1;
}

// ============ k_edge: fp16 produce (fdot2) + fp16 consume ==================
template<int ECH>
__device__ __forceinline__ void edge_chunk(
        int b, int rh, int rbase, int t,
        const _Float16* __restrict__ nl_h, const float* __restrict__ u,
        const float* __restrict__ pW1, const float* __restrict__ W_e1,
        const float* __restrict__ b_e1, float* __restrict__ P,
        _Float16* Ah, _Float16* Bh, const v2h (*W2h)[EOUT]) {
    constexpr int ech4 = ECH / 4;
    // task decode: (p,q): rows i0=2p,i0+1; cols j0=3q..3q+2; 225 valid tiles
    bool has = (t < 225);
    int pp = 0, qq = 0;
    if (has) {
        int tt = t;
        for (pp = 0; pp < 25; ++pp) {
            int qmin = pp ? ((2 * pp - 2) / 3 + 1) : 0;
            int cnt = 17 - qmin;
            if (tt < cnt) { qq = qmin + tt; break; }
            tt -= cnt;
        }
    }
    int i0 = 2 * pp, i1 = i0 + 1;
    int j0 = 3 * qq, j1 = j0 + 1, j2r = (3 * qq + 2 < NDIM) ? 3 * qq + 2 : NDIM - 1;

    float acc[6][EOUT];
#pragma unroll
    for (int e = 0; e < 6; ++e)
#pragma unroll
        for (int o = 0; o < EOUT; ++o) acc[e][o] = 0.f;

    bool prod = (t < 2 * ECH);
    int arr = (t >= ECH) ? 1 : 0;
    int c = t - (arr ? ECH : 0);
    const v2h* nlh = reinterpret_cast<const v2h*>(nl_h + (size_t)b * (NDIM * DDIM));

    for (int ch = 0; ch < 2; ++ch) {
        // ---- produce (fp16 dot2, fp32 accum, _Float16 store) ----
        if (prod) {
            int col = rbase + ch * ECH + c;
            v2h wv[16];
#pragma unroll
            for (int k2 = 0; k2 < 16; ++k2) {
                v2h w;
                w.x = (_Float16)W_e1[(size_t)(HDIM + arr * DDIM + 2 * k2) * HDIM + col];
                w.y = (_Float16)W_e1[(size_t)(HDIM + arr * DDIM + 2 * k2 + 1) * HDIM + col];
                wv[k2] = w;
            }
            float cm = 0.5f * (u[(size_t)b * HDIM + col] + b_e1[col]);
            _Float16* dst = arr ? Bh : Ah;
            float pc = pW1[col];
            for (int n = 0; n < NDIM; ++n) {
                float pn = (n < NDIM - 1) ? pW1[(size_t)(n + 1) * HDIM + col] : 0.f;
                const v2h* nr = nlh + n * 16;   // wave-uniform -> s_load
                float s0 = 0.f, s1 = 0.f, s2 = 0.f, s3 = 0.f;
#pragma unroll
                for (int q = 0; q < 4; ++q) {
                    s0 = fdot2f(nr[q],      wv[q],      s0);
                    s1 = fdot2f(nr[4 + q],  wv[4 + q],  s1);
                    s2 = fdot2f(nr[8 + q],  wv[8 + q],  s2);
                    s3 = fdot2f(nr[12 + q], wv[12 + q], s3);
                }
                float val = (cm + pc) + ((s0 + s1) + (s2 + s3));
                dst[n * ECH + ((((c >> 2) ^ (n & 7)) << 2) | (c & 3))] = (_Float16)val;
                pc = pn;
            }
        }
        __syncthreads();
        // ---- consume (v2h + fdot2, compile-time indices) ----
        if (has) {
            int pb0 = (rbase + ch * ECH) >> 1;   // base r-pair index
            int sA = i0 & 7, sB = i1 & 7, s0m = j0 & 7, s1m = j1 & 7, s2m = j2r & 7;
            for (int r4 = 0; r4 < ech4; ++r4) {
                h4 ra0 = *reinterpret_cast<const h4*>(&Ah[i0 * ECH + ((r4 ^ sA) << 2)]);
                h4 ra1 = *reinterpret_cast<const h4*>(&Ah[i1 * ECH + ((r4 ^ sB) << 2)]);
                h4 rb0 = *reinterpret_cast<const h4*>(&Bh[j0 * ECH + ((r4 ^ s0m) << 2)]);
                h4 rb1 = *reinterpret_cast<const h4*>(&Bh[j1 * ECH + ((r4 ^ s1m) << 2)]);
                h4 rb2 = *reinterpret_cast<const h4*>(&Bh[j2r * ECH + ((r4 ^ s2m) << 2)]);
                v2h v0l = relu2(ra0.lo, rb0.lo), v0h = relu2(ra0.hi, rb0.hi);
                v2h v1l = relu2(ra0.lo, rb1.lo), v1h = relu2(ra0.hi, rb1.hi);
                v2h v2l = relu2(ra0.lo, rb2.lo), v2hh = relu2(ra0.hi, rb2.hi);
                v2h v3l = relu2(ra1.lo, rb0.lo), v3h = relu2(ra1.hi, rb0.hi);
                v2h v4l = relu2(ra1.lo, rb1.lo), v4h = relu2(ra1.hi, rb1.hi);
                v2h v5l = relu2(ra1.lo, rb2.lo), v5h = relu2(ra1.hi, rb2.hi);
                int pb = pb0 + r4 * 2;
#pragma unroll
                for (int o = 0; o < EOUT; ++o) {
                    v2h wl = W2h[pb][o], wh = W2h[pb + 1][o];
                    acc[0][o] = fdot2f(v0h, wh, fdot2f(v0l, wl, acc[0][o]));
                    acc[1][o] = fdot2f(v1h, wh, fdot2f(v1l, wl, acc[1][o]));
                    acc[2][o] = fdot2f(v2hh, wh, fdot2f(v2l, wl, acc[2][o]));
                    acc[3][o] = fdot2f(v3h, wh, fdot2f(v3l, wl, acc[3][o]));
                    acc[4][o] = fdot2f(v4h, wh, fdot2f(v4l, wl, acc[4][o]));
                    acc[5][o] = fdot2f(v5h, wh, fdot2f(v5l, wl, acc[5][o]));
                }
            }
        }
        __syncthreads();
    }

    if (has) {
        float* Pb = P + ((size_t)rh * BSZ + b) * NEDGE * EOUT;
        int js[3] = {j0, j1, 3 * qq + 2};
#pragma unroll
        for (int r = 0; r < 2; ++r) {
            int i = i0 + r;
#pragma unroll
            for (int cc = 0; cc < 3; ++cc) {
                int j = js[cc];
                if (i < j && j < NDIM) {
                    int e = i * (NDIM - 1) - (i * (i - 1)) / 2 + (j - i - 1);
#pragma unroll
                    for (int o = 0; o < EOUT; ++o)
                        Pb[(size_t)e * EOUT + o] = acc[r * 3 + cc][o];
                }
            }
        }
    }
}

__global__ __launch_bounds__(256) void k_edge(
        const _Float16* __restrict__ nl_h,  // [256,50,32] fp16
        const float* __restrict__ u,        // [256,512]
        const float* __restrict__ pW1,      // [50,512]
        const float* __restrict__ W_e1,     // [576,512]
        const float* __restrict__ b_e1,     // [512]
        const float* __restrict__ W_e2,     // [512,5]
        float* __restrict__ P) {            // [3][256][1225][5]
    int b  = blockIdx.x;
    int rh = blockIdx.y;
    int t  = threadIdx.x;

    __shared__ __align__(16) _Float16 Ah[NDIM * 96];   // 9.6 KB
    __shared__ __align__(16) _Float16 Bh[NDIM * 96];   // 9.6 KB
    __shared__ v2h W2h[256][EOUT];                     // 5.12 KB

    // stage W_e2 as half2 r-pairs (256 pairs x 5 outs)
    for (int i = t; i < 256 * EOUT; i += 256) {
        int p = i / EOUT, o = i - p * EOUT;
        v2h w;
        w.x = (_Float16)W_e2[(size_t)(2 * p) * EOUT + o];
        w.y = (_Float16)W_e2[(size_t)(2 * p + 1) * EOUT + o];
        W2h[p][o] = w;
    }

    if (rh < 2)
        edge_chunk<96>(b, rh, rh * 192, t, nl_h, u, pW1, W_e1, b_e1, P, Ah, Bh, W2h);
    else
        edge_chunk<64>(b, rh, 384, t, nl_h, u, pW1, W_e1, b_e1, P, Ah, Bh, W2h);
}

// ============ k_comb: out_el = P0+P1+P2 + bias (float4 x5/thread) ==========
__global__ __launch_bounds__(256) void k_comb(const float* __restrict__ P,
                                              const float* __restrict__ b_e2,
                                              float* __restrict__ out_el,
                                              float* __restrict__ out_idx) {
    int blk = blockIdx.x, t = threadIdx.x;
    const size_t PS = (size_t)BSZ * NEDGE * EOUT;
    if (blk < 307) {
        int tid = blk * 256 + t;       // 20 floats per thread; 78400 total
        if (tid < 78400) {
            const float4* p0 = reinterpret_cast<const float4*>(P) + (size_t)tid * 5;
            const float4* p1 = reinterpret_cast<const float4*>(P + PS) + (size_t)tid * 5;
            const float4* p2 = reinterpret_cast<const float4*>(P + 2 * PS) + (size_t)tid * 5;
            float4* o = reinterpret_cast<float4*>(out_el) + (size_t)tid * 5;
            float b5[5];
#pragma unroll
            for (int cc = 0; cc < 5; ++cc) b5[cc] = b_e2[cc];
#pragma unroll
            for (int q = 0; q < 5; ++q) {
                float4 a = p0[q], b = p1[q], cq = p2[q];
                float4 r;
                r.x = a.x + b.x + cq.x + b5[(q * 4 + 0) % 5];
                r.y = a.y + b.y + cq.y + b5[(q * 4 + 1) % 5];
                r.z = a.z + b.z + cq.z + b5[(q * 4 + 2) % 5];
                r.w = a.w + b.w + cq.w + b5[(q * 4 + 3) % 5];
                o[q] = r;
            }
        }
    } else {
        int e = (blk - 307) * 256 + t;
        if (e < NEDGE) {
            int i = 0, rem = e;
            while (rem >= (NDIM - 1 - i)) { rem -= (NDIM - 1 - i); ++i; }
            int j = i + 1 + rem;
            out_idx[e * 2] = (float)i;
            out_idx[e * 2 + 1] = (float)j;
        }
    }
}

extern "C" void kernel_launch(void* const* d_in, const int* in_sizes, int n_in,
                              void* d_out, int out_size, void* d_ws, size_t ws_size,
                              hipStream_t stream) {
    const float* z    = (const float*)d_in[0];
    const float* tp   = (const float*)d_in[1];
    const float* W_in = (const float*)d_in[2];
    const float* b_in = (const float*)d_in[3];
    const float* W_s1 = (const float*)d_in[4];
    const float* b_s1 = (const float*)d_in[5];
    const float* W_s2 = (const float*)d_in[6];
    const float* b_s2 = (const float*)d_in[7];
    const float* W_n1 = (const float*)d_in[8];
    const float* b_n1 = (const float*)d_in[9];
    const float* W_n2 = (const float*)d_in[10];
    const float* b_n2 = (const float*)d_in[11];
    const float* W_e1 = (const float*)d_in[12];
    const float* b_e1 = (const float*)d_in[13];
    const float* W_e2 = (const float*)d_in[14];
    const float* b_e2 = (const float*)d_in[15];
    const float* pe   = (const float*)d_in[16];

    float* out     = (float*)d_out;
    float* out_nl  = out;                 // node_logits
    float* out_el  = out + 409600;        // edge_logits
    float* out_sp  = out + 1977600;       // size_probs
    float* out_idx = out + 1990400;       // edge_indices (as float)

    float* ws   = (float*)d_ws;
    float* u    = ws;
    float* pW1  = ws + 131072;
    float* n1   = ws + 156672;
    float* P    = ws + 287744;            // [3][256][1225][5]
    _Float16* nl_h = (_Float16*)(ws + 4991744);  // [256,50,32] fp16

    k_pre<<<666, 256, 0, stream>>>(z, tp, W_in, b_in, W_s1, b_s1, W_s2, b_s2,
                                   W_n1, b_n1, W_e1, pe, n1, u, pW1, out_sp);
    k_nl<<<dim3(128, 5), 320, 0, stream>>>(n1, W_n2, b_n2, out_nl, nl_h);
    k_edge<<<dim3(BSZ, NRH), 256, 0, stream>>>(nl_h, u, pW1, W_e1, b_e1, W_e2, P);
    k_comb<<<312, 256, 0, stream>>>(P, b_e2, out_el, out_idx);
}

// Round 20
// 127.130 us; speedup vs baseline: 1.2920x; 1.0576x over previous
//
#include <hip/hip_runtime.h>
#include <math.h>

// Problem dims
#define BSZ   256
#define LDIM  128
#define PDIM  3
#define HDIM  512
#define DDIM  32
#define NDIM  50
#define NEDGE 1225   // N*(N-1)/2
#define EOUT  5      // EDIM+1
#define NRH   4      // r-splits: 4 x 128 cols
#define ECH   128    // cols per block (single chunk)

// out layout (floats)
//   node_logits  [256,50,32]   @ 0        (409600)
//   edge_logits  [256,1225,5]  @ 409600   (1568000)
//   size_probs   [256,50]      @ 1977600  (12800)
//   edge_indices [1225,2]      @ 1990400  (2450, float values)
// ws layout (floats): u @0 (131072), pW1 @131072 (25600), n1 @156672 (131072),
//                     P @287744 (4 x 1568000 = 6272000), nl_h @6559744 (204800 fl)

typedef _Float16 v2h __attribute__((ext_vector_type(2)));

__device__ __forceinline__ float fdot2f(v2h a, v2h b, float c) {
    return __builtin_amdgcn_fdot2(a, b, c, false);
}
__device__ __forceinline__ v2h relu2(v2h a, v2h b) {
    v2h s = a + b;                       // v_pk_add_f16
    v2h z = {(_Float16)0.f, (_Float16)0.f};
    return __builtin_elementwise_max(s, z);   // v_pk_max_f16
}
struct h4 { v2h lo, hi; };

// ============ k_pre: 256-thr blocks, col-split roles (round-11, proven) ====
__global__ __launch_bounds__(256) void k_pre(
        const float* __restrict__ z, const float* __restrict__ tp,
        const float* __restrict__ W_in, const float* __restrict__ b_in,
        const float* __restrict__ W_s1, const float* __restrict__ b_s1,
        const float* __restrict__ W_s2, const float* __restrict__ b_s2,
        const float* __restrict__ W_n1, const float* __restrict__ b_n1,
        const float* __restrict__ W_e1, const float* __restrict__ pe,
        float* __restrict__ n1, float* __restrict__ u,
        float* __restrict__ pW1, float* __restrict__ out_sp) {
    int bx = blockIdx.x, t = threadIdx.x;
    __shared__ float smem[2368];

    if (bx < 512) {
        int role = bx >> 8;
        int idx2 = bx & 255;
        int bg = idx2 >> 1, jh = idx2 & 1;
        int b0 = bg * 2;
        float* sin_ = smem;            // [2][132]
        float* sh   = smem + 264;      // [2][512]
        for (int q = t; q < 2 * 131; q += 256) {
            int bi = q / 131, k = q % 131;
            sin_[bi * 132 + k] = (k < LDIM) ? z[(size_t)(b0 + bi) * LDIM + k]
                                            : tp[(size_t)(b0 + bi) * PDIM + (k - LDIM)];
        }
        __syncthreads();
        {
            float bi0 = b_in[t], bi1 = b_in[t + 256];
            float a00 = bi0, a01 = bi1, a10 = bi0, a11 = bi1;
            for (int k = 0; k < LDIM + PDIM; ++k) {
                float w0 = W_in[(size_t)k * HDIM + t];
                float w1 = W_in[(size_t)k * HDIM + t + 256];
                float x0 = sin_[k], x1 = sin_[132 + k];
                a00 += x0 * w0; a01 += x0 * w1;
                a10 += x1 * w0; a11 += x1 * w1;
            }
            sh[t] = fmaxf(a00, 0.f); sh[t + 256] = fmaxf(a01, 0.f);
            sh[512 + t] = fmaxf(a10, 0.f); sh[512 + t + 256] = fmaxf(a11, 0.f);
        }
        __syncthreads();
        int j = jh * 256 + t;
        const float* W = role ? W_e1 : W_n1;   // W1h = rows 0..511 of W_e1
        float s0a = 0.f, s0b = 0.f, s1a = 0.f, s1b = 0.f;
        for (int k4 = 0; k4 < HDIM / 4; ++k4) {
            float w0 = W[(size_t)(k4 * 4 + 0) * HDIM + j];
            float w1 = W[(size_t)(k4 * 4 + 1) * HDIM + j];
            float w2 = W[(size_t)(k4 * 4 + 2) * HDIM + j];
            float w3 = W[(size_t)(k4 * 4 + 3) * HDIM + j];
            float4 x0 = *reinterpret_cast<const float4*>(&sh[k4 * 4]);
            float4 x1 = *reinterpret_cast<const float4*>(&sh[512 + k4 * 4]);
            s0a += x0.x * w0 + x0.y * w1;
            s0b += x0.z * w2 + x0.w * w3;
            s1a += x1.x * w0 + x1.y * w1;
            s1b += x1.z * w2 + x1.w * w3;
        }
        float a0 = s0a + s0b, a1 = s1a + s1b;
        if (role == 0) {
            float bb = b_n1[j];
            n1[(size_t)(b0 + 0) * HDIM + j] = fmaxf(a0 + bb, 0.f);
            n1[(size_t)(b0 + 1) * HDIM + j] = fmaxf(a1 + bb, 0.f);
        } else {
            u[(size_t)(b0 + 0) * HDIM + j] = a0;
            u[(size_t)(b0 + 1) * HDIM + j] = a1;
        }
    } else if (bx < 640) {
        // ---- role size head: 2 batches ------------------------------------
        int b0 = (bx - 512) * 2;
        float* sin_ = smem;            // [2][132]
        float* sh   = smem + 264;      // [2][512]
        float* s1b  = smem + 264 + 1024;  // [2][256]
        float* slg  = smem + 264 + 1024 + 512;  // [2][50]
        for (int q = t; q < 2 * 131; q += 256) {
            int bi = q / 131, k = q % 131;
            sin_[bi * 132 + k] = (k < LDIM) ? z[(size_t)(b0 + bi) * LDIM + k]
                                            : tp[(size_t)(b0 + bi) * PDIM + (k - LDIM)];
        }
        __syncthreads();
        {
            float bi0 = b_in[t], bi1 = b_in[t + 256];
            float a00 = bi0, a01 = bi1, a10 = bi0, a11 = bi1;
            for (int k = 0; k < LDIM + PDIM; ++k) {
                float w0 = W_in[(size_t)k * HDIM + t];
                float w1 = W_in[(size_t)k * HDIM + t + 256];
                float x0 = sin_[k], x1 = sin_[132 + k];
                a00 += x0 * w0; a01 += x0 * w1;
                a10 += x1 * w0; a11 += x1 * w1;
            }
            sh[t] = fmaxf(a00, 0.f); sh[t + 256] = fmaxf(a01, 0.f);
            sh[512 + t] = fmaxf(a10, 0.f); sh[512 + t + 256] = fmaxf(a11, 0.f);
        }
        __syncthreads();
        {
            float bv = b_s1[t];
            float a0 = bv, a1 = bv;
            for (int k = 0; k < HDIM; ++k) {
                float w = W_s1[(size_t)k * (HDIM / 2) + t];
                a0 += sh[k] * w;
                a1 += sh[512 + k] * w;
            }
            s1b[t] = fmaxf(a0, 0.f);
            s1b[256 + t] = fmaxf(a1, 0.f);
        }
        __syncthreads();
        int b4 = t / NDIM, o = t % NDIM;
        if (t < 2 * NDIM) {
            float a = b_s2[o];
            for (int k = 0; k < HDIM / 2; ++k)
                a += s1b[b4 * 256 + k] * W_s2[(size_t)k * NDIM + o];
            slg[b4 * NDIM + o] = a;
        }
        __syncthreads();
        if (t < 2 * NDIM) {
            float m = slg[b4 * NDIM];
            for (int k = 1; k < NDIM; ++k) m = fmaxf(m, slg[b4 * NDIM + k]);
            float s = 0.f;
            for (int k = 0; k < NDIM; ++k) s += expf(slg[b4 * NDIM + k] - m);
            out_sp[(size_t)(b0 + b4) * NDIM + o] = expf(slg[b4 * NDIM + o] - m) / s;
        }
    } else {
        // ---- role pW1: 0.5 * pe @ W1h, 4 rows x 256-col half --------------
        int g = bx - 640, rg = g >> 1, jh = g & 1;
        int r[4];
#pragma unroll
        for (int q = 0; q < 4; ++q) { int rr = rg * 4 + q; r[q] = (rr < NDIM) ? rr : NDIM - 1; }
        float* spe = smem;   // [4][512]
        for (int q = t; q < 4 * HDIM / 4; q += 256) {
            int lin = q * 4, row = lin >> 9, col = lin & 511;
            *reinterpret_cast<float4*>(&spe[row * HDIM + col]) =
                *reinterpret_cast<const float4*>(&pe[(size_t)r[row] * HDIM + col]);
        }
        __syncthreads();
        int j = jh * 256 + t;
        float a0 = 0.f, a1 = 0.f, a2 = 0.f, a3 = 0.f;
        for (int k4 = 0; k4 < HDIM / 4; ++k4) {
            float w0 = W_e1[(size_t)(k4 * 4 + 0) * HDIM + j];
            float w1 = W_e1[(size_t)(k4 * 4 + 1) * HDIM + j];
            float w2 = W_e1[(size_t)(k4 * 4 + 2) * HDIM + j];
            float w3 = W_e1[(size_t)(k4 * 4 + 3) * HDIM + j];
            float4 x0 = *reinterpret_cast<const float4*>(&spe[0 * HDIM + k4 * 4]);
            float4 x1 = *reinterpret_cast<const float4*>(&spe[1 * HDIM + k4 * 4]);
            float4 x2 = *reinterpret_cast<const float4*>(&spe[2 * HDIM + k4 * 4]);
            float4 x3 = *reinterpret_cast<const float4*>(&spe[3 * HDIM + k4 * 4]);
            a0 += x0.x * w0 + x0.y * w1 + x0.z * w2 + x0.w * w3;
            a1 += x1.x * w0 + x1.y * w1 + x1.z * w2 + x1.w * w3;
            a2 += x2.x * w0 + x2.y * w1 + x2.z * w2 + x2.w * w3;
            a3 += x3.x * w0 + x3.y * w1 + x3.z * w2 + x3.w * w3;
        }
        pW1[(size_t)r[0] * HDIM + j] = 0.5f * a0;
        pW1[(size_t)r[1] * HDIM + j] = 0.5f * a1;
        pW1[(size_t)r[2] * HDIM + j] = 0.5f * a2;
        pW1[(size_t)r[3] * HDIM + j] = 0.5f * a3;
    }
}

// ============ k_nl: [256,512]@[512,1600]+b, 2 batches/block ================
// Also writes fp16 copy of node_logits for the edge kernel's produce phase.
__global__ __launch_bounds__(320) void k_nl(const float* __restrict__ n1,
                                            const float* __restrict__ W_n2,
                                            const float* __restrict__ b_n2,
                                            float* __restrict__ out_nl,
                                            _Float16* __restrict__ nl_h) {
    const int NOUT = NDIM * DDIM;   // 1600
    int t = threadIdx.x;
    int j = blockIdx.y * 320 + t;
    int bg = blockIdx.x;            // 2 batches
    __shared__ float s[2 * HDIM];
    for (int idx = t; idx < 2 * HDIM / 4; idx += 320) {
        int lin = idx * 4;
        int row = lin >> 9, col = lin & 511;
        *reinterpret_cast<float4*>(&s[row * HDIM + col]) =
            *reinterpret_cast<const float4*>(&n1[(size_t)(bg * 2 + row) * HDIM + col]);
    }
    __syncthreads();
    float s0a = 0.f, s0b = 0.f, s1a = 0.f, s1b = 0.f;
    for (int k4 = 0; k4 < HDIM / 4; ++k4) {
        float w0 = W_n2[(size_t)(k4 * 4 + 0) * NOUT + j];
        float w1 = W_n2[(size_t)(k4 * 4 + 1) * NOUT + j];
        float w2 = W_n2[(size_t)(k4 * 4 + 2) * NOUT + j];
        float w3 = W_n2[(size_t)(k4 * 4 + 3) * NOUT + j];
        float4 x0 = *reinterpret_cast<const float4*>(&s[k4 * 4]);
        float4 x1 = *reinterpret_cast<const float4*>(&s[HDIM + k4 * 4]);
        s0a += x0.x * w0 + x0.y * w1;
        s0b += x0.z * w2 + x0.w * w3;
        s1a += x1.x * w0 + x1.y * w1;
        s1b += x1.z * w2 + x1.w * w3;
    }
    float bias = b_n2[j];
    float r0 = bias + s0a + s0b;
    float r1 = bias + s1a + s1b;
    out_nl[(size_t)(bg * 2 + 0) * NOUT + j] = r0;
    out_nl[(size_t)(bg * 2 + 1) * NOUT + j] = r1;
    nl_h[(size_t)(bg * 2 + 0) * NOUT + j] = (_Float16)r0;
    nl_h[(size_t)(bg * 2 + 1) * NOUT + j] = (_Float16)r1;
}

// ============ k_edge: uniform 4x128 split, single chunk, 2 barriers ========
// grid (256,4), block 256, LDS ~26.9KB -> 4 blocks/CU exactly (one pass).
// Produce: all 256 threads (arr = t>>7, c = t&127), 50 rows each.
// Consume: 225 tasks of 2x3 tiles x 32 r4-iters.
__global__ __launch_bounds__(256) void k_edge(
        const _Float16* __restrict__ nl_h,  // [256,50,32] fp16
        const float* __restrict__ u,        // [256,512]
        const float* __restrict__ pW1,      // [50,512]
        const float* __restrict__ W_e1,     // [576,512]
        const float* __restrict__ b_e1,     // [512]
        const float* __restrict__ W_e2,     // [512,5]
        float* __restrict__ P) {            // [4][256][1225][5]
    int b  = blockIdx.x;
    int rh = blockIdx.y;
    int t  = threadIdx.x;
    int rbase = rh * ECH;
    constexpr int ech4 = ECH / 4;           // 32

    __shared__ __align__(16) _Float16 Ah[NDIM * ECH];  // 12.8 KB
    __shared__ __align__(16) _Float16 Bh[NDIM * ECH];  // 12.8 KB
    __shared__ v2h W2h[ECH / 2][EOUT];                 // 1.28 KB

    // stage W_e2 chunk as half2 r-pairs (64 pairs x 5 outs)
    for (int i = t; i < (ECH / 2) * EOUT; i += 256) {
        int p = i / EOUT, o = i - p * EOUT;
        v2h w;
        w.x = (_Float16)W_e2[(size_t)(rbase + 2 * p) * EOUT + o];
        w.y = (_Float16)W_e2[(size_t)(rbase + 2 * p + 1) * EOUT + o];
        W2h[p][o] = w;
    }

    // task decode: (p,q): rows i0=2p,i0+1; cols j0=3q..3q+2; 225 valid tiles
    bool has = (t < 225);
    int pp = 0, qq = 0;
    if (has) {
        int tt = t;
        for (pp = 0; pp < 25; ++pp) {
            int qmin = pp ? ((2 * pp - 2) / 3 + 1) : 0;
            int cnt = 17 - qmin;
            if (tt < cnt) { qq = qmin + tt; break; }
            tt -= cnt;
        }
    }
    int i0 = 2 * pp, i1 = i0 + 1;
    int j0 = 3 * qq, j1 = j0 + 1, j2r = (3 * qq + 2 < NDIM) ? 3 * qq + 2 : NDIM - 1;

    float acc[6][EOUT];
#pragma unroll
    for (int e = 0; e < 6; ++e)
#pragma unroll
        for (int o = 0; o < EOUT; ++o) acc[e][o] = 0.f;

    // ---- produce (fp16 dot2, fp32 accum, _Float16 store) ----
    {
        int arr = t >> 7, c = t & 127;
        int col = rbase + c;
        const v2h* nlh = reinterpret_cast<const v2h*>(nl_h + (size_t)b * (NDIM * DDIM));
        v2h wv[16];
#pragma unroll
        for (int k2 = 0; k2 < 16; ++k2) {
            v2h w;
            w.x = (_Float16)W_e1[(size_t)(HDIM + arr * DDIM + 2 * k2) * HDIM + col];
            w.y = (_Float16)W_e1[(size_t)(HDIM + arr * DDIM + 2 * k2 + 1) * HDIM + col];
            wv[k2] = w;
        }
        float cm = 0.5f * (u[(size_t)b * HDIM + col] + b_e1[col]);
        _Float16* dst = arr ? Bh : Ah;
        float pc = pW1[col];
        for (int n = 0; n < NDIM; ++n) {
            float pn = (n < NDIM - 1) ? pW1[(size_t)(n + 1) * HDIM + col] : 0.f;
            const v2h* nr = nlh + n * 16;   // wave-uniform -> s_load
            float s0 = 0.f, s1 = 0.f, s2 = 0.f, s3 = 0.f;
#pragma unroll
            for (int q = 0; q < 4; ++q) {
                s0 = fdot2f(nr[q],      wv[q],      s0);
                s1 = fdot2f(nr[4 + q],  wv[4 + q],  s1);
                s2 = fdot2f(nr[8 + q],  wv[8 + q],  s2);
                s3 = fdot2f(nr[12 + q], wv[12 + q], s3);
            }
            float val = (cm + pc) + ((s0 + s1) + (s2 + s3));
            dst[n * ECH + ((((c >> 2) ^ (n & 7)) << 2) | (c & 3))] = (_Float16)val;
            pc = pn;
        }
    }
    __syncthreads();

    // ---- consume (v2h + fdot2, compile-time indices) ----
    if (has) {
        int sA = i0 & 7, sB = i1 & 7, s0m = j0 & 7, s1m = j1 & 7, s2m = j2r & 7;
        for (int r4 = 0; r4 < ech4; ++r4) {
            h4 ra0 = *reinterpret_cast<const h4*>(&Ah[i0 * ECH + ((r4 ^ sA) << 2)]);
            h4 ra1 = *reinterpret_cast<const h4*>(&Ah[i1 * ECH + ((r4 ^ sB) << 2)]);
            h4 rb0 = *reinterpret_cast<const h4*>(&Bh[j0 * ECH + ((r4 ^ s0m) << 2)]);
            h4 rb1 = *reinterpret_cast<const h4*>(&Bh[j1 * ECH + ((r4 ^ s1m) << 2)]);
            h4 rb2 = *reinterpret_cast<const h4*>(&Bh[j2r * ECH + ((r4 ^ s2m) << 2)]);
            v2h v0l = relu2(ra0.lo, rb0.lo), v0h = relu2(ra0.hi, rb0.hi);
            v2h v1l = relu2(ra0.lo, rb1.lo), v1h = relu2(ra0.hi, rb1.hi);
            v2h v2l = relu2(ra0.lo, rb2.lo), v2hh = relu2(ra0.hi, rb2.hi);
            v2h v3l = relu2(ra1.lo, rb0.lo), v3h = relu2(ra1.hi, rb0.hi);
            v2h v4l = relu2(ra1.lo, rb1.lo), v4h = relu2(ra1.hi, rb1.hi);
            v2h v5l = relu2(ra1.lo, rb2.lo), v5h = relu2(ra1.hi, rb2.hi);
            int pb = r4 * 2;
#pragma unroll
            for (int o = 0; o < EOUT; ++o) {
                v2h wl = W2h[pb][o], wh = W2h[pb + 1][o];
                acc[0][o] = fdot2f(v0h, wh, fdot2f(v0l, wl, acc[0][o]));
                acc[1][o] = fdot2f(v1h, wh, fdot2f(v1l, wl, acc[1][o]));
                acc[2][o] = fdot2f(v2hh, wh, fdot2f(v2l, wl, acc[2][o]));
                acc[3][o] = fdot2f(v3h, wh, fdot2f(v3l, wl, acc[3][o]));
                acc[4][o] = fdot2f(v4h, wh, fdot2f(v4l, wl, acc[4][o]));
                acc[5][o] = fdot2f(v5h, wh, fdot2f(v5l, wl, acc[5][o]));
            }
        }
    }
    __syncthreads();

    if (has) {
        float* Pb = P + ((size_t)rh * BSZ + b) * NEDGE * EOUT;
        int js[3] = {j0, j1, 3 * qq + 2};
#pragma unroll
        for (int r = 0; r < 2; ++r) {
            int i = i0 + r;
#pragma unroll
            for (int cc = 0; cc < 3; ++cc) {
                int j = js[cc];
                if (i < j && j < NDIM) {
                    int e = i * (NDIM - 1) - (i * (i - 1)) / 2 + (j - i - 1);
#pragma unroll
                    for (int o = 0; o < EOUT; ++o)
                        Pb[(size_t)e * EOUT + o] = acc[r * 3 + cc][o];
                }
            }
        }
    }
}

// ============ k_comb: out_el = P0+P1+P2+P3 + bias (float4 x5/thread) =======
__global__ __launch_bounds__(256) void k_comb(const float* __restrict__ P,
                                              const float* __restrict__ b_e2,
                                              float* __restrict__ out_el,
                                              float* __restrict__ out_idx) {
    int blk = blockIdx.x, t = threadIdx.x;
    const size_t PS = (size_t)BSZ * NEDGE * EOUT;
    if (blk < 307) {
        int tid = blk * 256 + t;       // 20 floats per thread; 78400 total
        if (tid < 78400) {
            float b5[5];
#pragma unroll
            for (int cc = 0; cc < 5; ++cc) b5[cc] = b_e2[cc];
#pragma unroll
            for (int q = 0; q < 5; ++q) {
                float4 s = make_float4(0.f, 0.f, 0.f, 0.f);
#pragma unroll
                for (int p = 0; p < NRH; ++p) {
                    float4 v = reinterpret_cast<const float4*>(P + (size_t)p * PS)[(size_t)tid * 5 + q];
                    s.x += v.x; s.y += v.y; s.z += v.z; s.w += v.w;
                }
                float4 r;
                r.x = s.x + b5[(q * 4 + 0) % 5];
                r.y = s.y + b5[(q * 4 + 1) % 5];
                r.z = s.z + b5[(q * 4 + 2) % 5];
                r.w = s.w + b5[(q * 4 + 3) % 5];
                reinterpret_cast<float4*>(out_el)[(size_t)tid * 5 + q] = r;
            }
        }
    } else {
        int e = (blk - 307) * 256 + t;
        if (e < NEDGE) {
            int i = 0, rem = e;
            while (rem >= (NDIM - 1 - i)) { rem -= (NDIM - 1 - i); ++i; }
            int j = i + 1 + rem;
            out_idx[e * 2] = (float)i;
            out_idx[e * 2 + 1] = (float)j;
        }
    }
}

extern "C" void kernel_launch(void* const* d_in, const int* in_sizes, int n_in,
                              void* d_out, int out_size, void* d_ws, size_t ws_size,
                              hipStream_t stream) {
    const float* z    = (const float*)d_in[0];
    const float* tp   = (const float*)d_in[1];
    const float* W_in = (const float*)d_in[2];
    const float* b_in = (const float*)d_in[3];
    const float* W_s1 = (const float*)d_in[4];
    const float* b_s1 = (const float*)d_in[5];
    const float* W_s2 = (const float*)d_in[6];
    const float* b_s2 = (const float*)d_in[7];
    const float* W_n1 = (const float*)d_in[8];
    const float* b_n1 = (const float*)d_in[9];
    const float* W_n2 = (const float*)d_in[10];
    const float* b_n2 = (const float*)d_in[11];
    const float* W_e1 = (const float*)d_in[12];
    const float* b_e1 = (const float*)d_in[13];
    const float* W_e2 = (const float*)d_in[14];
    const float* b_e2 = (const float*)d_in[15];
    const float* pe   = (const float*)d_in[16];

    float* out     = (float*)d_out;
    float* out_nl  = out;                 // node_logits
    float* out_el  = out + 409600;        // edge_logits
    float* out_sp  = out + 1977600;       // size_probs
    float* out_idx = out + 1990400;       // edge_indices (as float)

    float* ws   = (float*)d_ws;
    float* u    = ws;
    float* pW1  = ws + 131072;
    float* n1   = ws + 156672;
    float* P    = ws + 287744;            // [4][256][1225][5]
    _Float16* nl_h = (_Float16*)(ws + 6559744);  // [256,50,32] fp16

    k_pre<<<666, 256, 0, stream>>>(z, tp, W_in, b_in, W_s1, b_s1, W_s2, b_s2,
                                   W_n1, b_n1, W_e1, pe, n1, u, pW1, out_sp);
    k_nl<<<dim3(128, 5), 320, 0, stream>>>(n1, W_n2, b_n2, out_nl, nl_h);
    k_edge<<<dim3(BSZ, NRH), 256, 0, stream>>>(nl_h, u, pW1, W_e1, b_e1, W_e2, P);
    k_comb<<<312, 256, 0, stream>>>(P, b_e2, out_el, out_idx);
}

// Round 21
// 116.350 us; speedup vs baseline: 1.4117x; 1.0927x over previous
//
#include <hip/hip_runtime.h>
#include <math.h>

// Problem dims
#define BSZ   256
#define LDIM  128
#define PDIM  3
#define HDIM  512
#define DDIM  32
#define NDIM  50
#define NEDGE 1225   // N*(N-1)/2
#define EOUT  5      // EDIM+1
#define NRH   4      // r-splits: 4 x 128 cols
#define ECH   128    // cols per edge block

// out layout (floats)
//   node_logits  [256,50,32]   @ 0        (409600)
//   edge_logits  [256,1225,5]  @ 409600   (1568000)
//   size_probs   [256,50]      @ 1977600  (12800)
//   edge_indices [1225,2]      @ 1990400  (2450, float values)
// ws layout (floats):
//   u @0 (131072), pW1 @131072 (25600), n1 @156672 (131072),
//   P @287744 (4 x 1568000 = 6272000), nl_h @6559744 (204800),
//   W1p @6764544 (131072), Wep @6895616 (131072), Wsp @7026688 (65536),
//   Winp @7092224 (34816)

typedef _Float16 v2h __attribute__((ext_vector_type(2)));

__device__ __forceinline__ float fdot2f(v2h a, v2h b, float c) {
    return __builtin_amdgcn_fdot2(a, b, c, false);
}
__device__ __forceinline__ v2h relu2(v2h a, v2h b) {
    v2h s = a + b;
    v2h z = {(_Float16)0.f, (_Float16)0.f};
    return __builtin_elementwise_max(s, z);
}
struct h4 { v2h lo, hi; };
struct h8 { v2h a, b, c, d; };   // 16B

// ============ k_prep: pack weights into fp16 k-pair [k8][N][4] layout ======
// W1p (W_n1, N=512), Wep (W_e1 rows 0..511, N=512), Wsp (W_s1, N=256),
// Winp (W_in 131 rows padded to 136, N=512).
__global__ __launch_bounds__(256) void k_prep(
        const float* __restrict__ W_n1, const float* __restrict__ W_e1,
        const float* __restrict__ W_s1, const float* __restrict__ W_in,
        v2h* __restrict__ W1p, v2h* __restrict__ Wep,
        v2h* __restrict__ Wsp, v2h* __restrict__ Winp) {
    int f = blockIdx.x * 256 + threadIdx.x;
    if (f < 131072) {
        int q = f & 3, t1 = f >> 2, j = t1 & 511, k8 = t1 >> 9;
        int k2 = k8 * 4 + q;
        v2h w;
        w.x = (_Float16)W_n1[(size_t)(2 * k2) * HDIM + j];
        w.y = (_Float16)W_n1[(size_t)(2 * k2 + 1) * HDIM + j];
        W1p[f] = w;
    } else if (f < 262144) {
        int g = f - 131072;
        int q = g & 3, t1 = g >> 2, j = t1 & 511, k8 = t1 >> 9;
        int k2 = k8 * 4 + q;
        v2h w;
        w.x = (_Float16)W_e1[(size_t)(2 * k2) * HDIM + j];
        w.y = (_Float16)W_e1[(size_t)(2 * k2 + 1) * HDIM + j];
        Wep[g] = w;
    } else if (f < 327680) {
        int g = f - 262144;
        int q = g & 3, t1 = g >> 2, j = t1 & 255, k8 = t1 >> 8;
        int k2 = k8 * 4 + q;
        v2h w;
        w.x = (_Float16)W_s1[(size_t)(2 * k2) * (HDIM / 2) + j];
        w.y = (_Float16)W_s1[(size_t)(2 * k2 + 1) * (HDIM / 2) + j];
        Wsp[g] = w;
    } else if (f < 362496) {
        int g = f - 327680;
        int q = g & 3, t1 = g >> 2, j = t1 & 511, k8 = t1 >> 9;
        int k2 = k8 * 4 + q;     // 0..67
        int r0 = 2 * k2, r1 = 2 * k2 + 1;
        v2h w;
        w.x = (r0 < LDIM + PDIM) ? (_Float16)W_in[(size_t)r0 * HDIM + j] : (_Float16)0.f;
        w.y = (r1 < LDIM + PDIM) ? (_Float16)W_in[(size_t)r1 * HDIM + j] : (_Float16)0.f;
        Winp[g] = w;
    }
}

// helper: stage packed inputs [2][68] v2h from z/tp
__device__ __forceinline__ void stage_sin2(v2h* sin2, const float* z, const float* tp,
                                           int b0, int t) {
    if (t < 136) {
        int bi = (t >= 68) ? 1 : 0;
        int k2 = t - (bi ? 68 : 0);
        int k0 = 2 * k2, k1 = 2 * k2 + 1;
        float v0 = (k0 < LDIM) ? z[(size_t)(b0 + bi) * LDIM + k0]
                 : (k0 < LDIM + PDIM) ? tp[(size_t)(b0 + bi) * PDIM + (k0 - LDIM)] : 0.f;
        float v1 = (k1 < LDIM) ? z[(size_t)(b0 + bi) * LDIM + k1]
                 : (k1 < LDIM + PDIM) ? tp[(size_t)(b0 + bi) * PDIM + (k1 - LDIM)] : 0.f;
        v2h v; v.x = (_Float16)v0; v.y = (_Float16)v1;
        sin2[bi * 68 + k2] = v;
    }
}

// helper: phase1 h for 2 batches via packed W_in; writes sh[2][512] fp32
__device__ __forceinline__ void phase1_h(const v2h* sin2, const v2h* Winp,
                                         const float* b_in, float* sh, int t) {
    float bin0 = b_in[t], bin1 = b_in[t + 256];
    float a00 = bin0, a01 = bin1, a10 = bin0, a11 = bin1;
    for (int k8 = 0; k8 < 17; ++k8) {
        h8 s0 = *reinterpret_cast<const h8*>(&sin2[k8 * 4]);
        h8 s1 = *reinterpret_cast<const h8*>(&sin2[68 + k8 * 4]);
        h8 w0 = *reinterpret_cast<const h8*>(&Winp[(size_t)(k8 * 512 + t) * 4]);
        h8 w1 = *reinterpret_cast<const h8*>(&Winp[(size_t)(k8 * 512 + t + 256) * 4]);
        a00 = fdot2f(s0.a, w0.a, a00); a00 = fdot2f(s0.b, w0.b, a00);
        a00 = fdot2f(s0.c, w0.c, a00); a00 = fdot2f(s0.d, w0.d, a00);
        a01 = fdot2f(s0.a, w1.a, a01); a01 = fdot2f(s0.b, w1.b, a01);
        a01 = fdot2f(s0.c, w1.c, a01); a01 = fdot2f(s0.d, w1.d, a01);
        a10 = fdot2f(s1.a, w0.a, a10); a10 = fdot2f(s1.b, w0.b, a10);
        a10 = fdot2f(s1.c, w0.c, a10); a10 = fdot2f(s1.d, w0.d, a10);
        a11 = fdot2f(s1.a, w1.a, a11); a11 = fdot2f(s1.b, w1.b, a11);
        a11 = fdot2f(s1.c, w1.c, a11); a11 = fdot2f(s1.d, w1.d, a11);
    }
    sh[t] = fmaxf(a00, 0.f); sh[t + 256] = fmaxf(a01, 0.f);
    sh[512 + t] = fmaxf(a10, 0.f); sh[512 + t + 256] = fmaxf(a11, 0.f);
}

// ============ k_pre: fp16-packed sweeps ====================================
// grid 666: [0,512) n1/u roles, [512,640) size head, [640,666) pW1
__global__ __launch_bounds__(256) void k_pre(
        const float* __restrict__ z, const float* __restrict__ tp,
        const float* __restrict__ b_in,
        const float* __restrict__ b_s1,
        const float* __restrict__ W_s2, const float* __restrict__ b_s2,
        const float* __restrict__ b_n1,
        const float* __restrict__ pe,
        const v2h* __restrict__ W1p, const v2h* __restrict__ Wep,
        const v2h* __restrict__ Wsp, const v2h* __restrict__ Winp,
        float* __restrict__ n1, float* __restrict__ u,
        float* __restrict__ pW1, float* __restrict__ out_sp) {
    int bx = blockIdx.x, t = threadIdx.x;
    __shared__ float smem[2560];

    if (bx < 512) {
        // ---- role n1 (bx<256) or u: 2 batches, one 256-col half -----------
        int role = bx >> 8;
        int idx2 = bx & 255;
        int bg = idx2 >> 1, jh = idx2 & 1;
        int b0 = bg * 2;
        v2h* sin2 = reinterpret_cast<v2h*>(smem);        // 136 v2h
        float* sh  = smem + 136;                          // [2][512]
        v2h* h2    = reinterpret_cast<v2h*>(smem + 1160); // [2][256] v2h
        stage_sin2(sin2, z, tp, b0, t);
        __syncthreads();
        phase1_h(sin2, Winp, b_in, sh, t);
        __syncthreads();
        // pack h -> h2
        for (int idx = t; idx < 512; idx += 256) {
            int bi = idx >> 8, k2 = idx & 255;
            v2h v; v.x = (_Float16)sh[bi * 512 + 2 * k2];
            v.y = (_Float16)sh[bi * 512 + 2 * k2 + 1];
            h2[bi * 256 + k2] = v;
        }
        __syncthreads();
        int j = jh * 256 + t;
        const v2h* Wp = role ? Wep : W1p;
        float a0 = 0.f, a0b = 0.f, a1 = 0.f, a1b = 0.f;
        for (int k8 = 0; k8 < 64; ++k8) {
            h8 ha = *reinterpret_cast<const h8*>(&h2[k8 * 4]);
            h8 hb = *reinterpret_cast<const h8*>(&h2[256 + k8 * 4]);
            h8 w  = *reinterpret_cast<const h8*>(&Wp[(size_t)(k8 * 512 + j) * 4]);
            a0  = fdot2f(ha.a, w.a, a0);  a0  = fdot2f(ha.b, w.b, a0);
            a0b = fdot2f(ha.c, w.c, a0b); a0b = fdot2f(ha.d, w.d, a0b);
            a1  = fdot2f(hb.a, w.a, a1);  a1  = fdot2f(hb.b, w.b, a1);
            a1b = fdot2f(hb.c, w.c, a1b); a1b = fdot2f(hb.d, w.d, a1b);
        }
        float r0 = a0 + a0b, r1 = a1 + a1b;
        if (role == 0) {
            float bb = b_n1[j];
            n1[(size_t)(b0 + 0) * HDIM + j] = fmaxf(r0 + bb, 0.f);
            n1[(size_t)(b0 + 1) * HDIM + j] = fmaxf(r1 + bb, 0.f);
        } else {
            u[(size_t)(b0 + 0) * HDIM + j] = r0;
            u[(size_t)(b0 + 1) * HDIM + j] = r1;
        }
    } else if (bx < 640) {
        // ---- role size head: 2 batches ------------------------------------
        int b0 = (bx - 512) * 2;
        v2h* sin2 = reinterpret_cast<v2h*>(smem);        // 136 v2h
        float* sh  = smem + 136;                          // [2][512]
        v2h* h2    = reinterpret_cast<v2h*>(smem + 1160); // [2][256] v2h
        float* s1b = smem + 1672;                         // [2][256]
        float* slg = smem + 2184;                         // [2][50]
        stage_sin2(sin2, z, tp, b0, t);
        __syncthreads();
        phase1_h(sin2, Winp, b_in, sh, t);
        __syncthreads();
        for (int idx = t; idx < 512; idx += 256) {
            int bi = idx >> 8, k2 = idx & 255;
            v2h v; v.x = (_Float16)sh[bi * 512 + 2 * k2];
            v.y = (_Float16)sh[bi * 512 + 2 * k2 + 1];
            h2[bi * 256 + k2] = v;
        }
        __syncthreads();
        {
            float bv = b_s1[t];
            float a0 = bv, a0b = 0.f, a1 = bv, a1b = 0.f;
            for (int k8 = 0; k8 < 64; ++k8) {
                h8 ha = *reinterpret_cast<const h8*>(&h2[k8 * 4]);
                h8 hb = *reinterpret_cast<const h8*>(&h2[256 + k8 * 4]);
                h8 w  = *reinterpret_cast<const h8*>(&Wsp[(size_t)(k8 * 256 + t) * 4]);
                a0  = fdot2f(ha.a, w.a, a0);  a0  = fdot2f(ha.b, w.b, a0);
                a0b = fdot2f(ha.c, w.c, a0b); a0b = fdot2f(ha.d, w.d, a0b);
                a1  = fdot2f(hb.a, w.a, a1);  a1  = fdot2f(hb.b, w.b, a1);
                a1b = fdot2f(hb.c, w.c, a1b); a1b = fdot2f(hb.d, w.d, a1b);
            }
            s1b[t] = fmaxf(a0 + a0b, 0.f);
            s1b[256 + t] = fmaxf(a1 + a1b, 0.f);
        }
        __syncthreads();
        int b4 = t / NDIM, o = t % NDIM;
        if (t < 2 * NDIM) {
            float a = b_s2[o];
            for (int k = 0; k < HDIM / 2; ++k)
                a += s1b[b4 * 256 + k] * W_s2[(size_t)k * NDIM + o];
            slg[b4 * NDIM + o] = a;
        }
        __syncthreads();
        if (t < 2 * NDIM) {
            float m = slg[b4 * NDIM];
            for (int k = 1; k < NDIM; ++k) m = fmaxf(m, slg[b4 * NDIM + k]);
            float s = 0.f;
            for (int k = 0; k < NDIM; ++k) s += expf(slg[b4 * NDIM + k] - m);
            out_sp[(size_t)(b0 + b4) * NDIM + o] = expf(slg[b4 * NDIM + o] - m) / s;
        }
    } else {
        // ---- role pW1: 0.5 * pe @ W1h, 4 rows x 256-col half --------------
        int g = bx - 640, rg = g >> 1, jh = g & 1;
        int r[4];
#pragma unroll
        for (int q = 0; q < 4; ++q) { int rr = rg * 4 + q; r[q] = (rr < NDIM) ? rr : NDIM - 1; }
        v2h* pe2 = reinterpret_cast<v2h*>(smem);   // [4][256] v2h
        for (int idx = t; idx < 4 * 256; idx += 256) {
            int row = idx >> 8, k2 = idx & 255;
            v2h v;
            v.x = (_Float16)pe[(size_t)r[row] * HDIM + 2 * k2];
            v.y = (_Float16)pe[(size_t)r[row] * HDIM + 2 * k2 + 1];
            pe2[idx] = v;
        }
        __syncthreads();
        int j = jh * 256 + t;
        float a0 = 0.f, a0b = 0.f, a1 = 0.f, a1b = 0.f;
        float a2 = 0.f, a2b = 0.f, a3 = 0.f, a3b = 0.f;
        for (int k8 = 0; k8 < 64; ++k8) {
            h8 p0 = *reinterpret_cast<const h8*>(&pe2[0 * 256 + k8 * 4]);
            h8 p1 = *reinterpret_cast<const h8*>(&pe2[1 * 256 + k8 * 4]);
            h8 p2 = *reinterpret_cast<const h8*>(&pe2[2 * 256 + k8 * 4]);
            h8 p3 = *reinterpret_cast<const h8*>(&pe2[3 * 256 + k8 * 4]);
            h8 w  = *reinterpret_cast<const h8*>(&Wep[(size_t)(k8 * 512 + j) * 4]);
            a0  = fdot2f(p0.a, w.a, a0);  a0  = fdot2f(p0.b, w.b, a0);
            a0b = fdot2f(p0.c, w.c, a0b); a0b = fdot2f(p0.d, w.d, a0b);
            a1  = fdot2f(p1.a, w.a, a1);  a1  = fdot2f(p1.b, w.b, a1);
            a1b = fdot2f(p1.c, w.c, a1b); a1b = fdot2f(p1.d, w.d, a1b);
            a2  = fdot2f(p2.a, w.a, a2);  a2  = fdot2f(p2.b, w.b, a2);
            a2b = fdot2f(p2.c, w.c, a2b); a2b = fdot2f(p2.d, w.d, a2b);
            a3  = fdot2f(p3.a, w.a, a3);  a3  = fdot2f(p3.b, w.b, a3);
            a3b = fdot2f(p3.c, w.c, a3b); a3b = fdot2f(p3.d, w.d, a3b);
        }
        pW1[(size_t)r[0] * HDIM + j] = 0.5f * (a0 + a0b);
        pW1[(size_t)r[1] * HDIM + j] = 0.5f * (a1 + a1b);
        pW1[(size_t)r[2] * HDIM + j] = 0.5f * (a2 + a2b);
        pW1[(size_t)r[3] * HDIM + j] = 0.5f * (a3 + a3b);
    }
}

// ============ k_nl: [256,512]@[512,1600]+b, 2 batches/block (fp32) =========
__global__ __launch_bounds__(320) void k_nl(const float* __restrict__ n1,
                                            const float* __restrict__ W_n2,
                                            const float* __restrict__ b_n2,
                                            float* __restrict__ out_nl,
                                            _Float16* __restrict__ nl_h) {
    const int NOUT = NDIM * DDIM;   // 1600
    int t = threadIdx.x;
    int j = blockIdx.y * 320 + t;
    int bg = blockIdx.x;            // 2 batches
    __shared__ float s[2 * HDIM];
    for (int idx = t; idx < 2 * HDIM / 4; idx += 320) {
        int lin = idx * 4;
        int row = lin >> 9, col = lin & 511;
        *reinterpret_cast<float4*>(&s[row * HDIM + col]) =
            *reinterpret_cast<const float4*>(&n1[(size_t)(bg * 2 + row) * HDIM + col]);
    }
    __syncthreads();
    float s0a = 0.f, s0b = 0.f, s1a = 0.f, s1b = 0.f;
    for (int k4 = 0; k4 < HDIM / 4; ++k4) {
        float w0 = W_n2[(size_t)(k4 * 4 + 0) * NOUT + j];
        float w1 = W_n2[(size_t)(k4 * 4 + 1) * NOUT + j];
        float w2 = W_n2[(size_t)(k4 * 4 + 2) * NOUT + j];
        float w3 = W_n2[(size_t)(k4 * 4 + 3) * NOUT + j];
        float4 x0 = *reinterpret_cast<const float4*>(&s[k4 * 4]);
        float4 x1 = *reinterpret_cast<const float4*>(&s[HDIM + k4 * 4]);
        s0a += x0.x * w0 + x0.y * w1;
        s0b += x0.z * w2 + x0.w * w3;
        s1a += x1.x * w0 + x1.y * w1;
        s1b += x1.z * w2 + x1.w * w3;
    }
    float bias = b_n2[j];
    float r0 = bias + s0a + s0b;
    float r1 = bias + s1a + s1b;
    out_nl[(size_t)(bg * 2 + 0) * NOUT + j] = r0;
    out_nl[(size_t)(bg * 2 + 1) * NOUT + j] = r1;
    nl_h[(size_t)(bg * 2 + 0) * NOUT + j] = (_Float16)r0;
    nl_h[(size_t)(bg * 2 + 1) * NOUT + j] = (_Float16)r1;
}

// ============ k_edge: round-20 champion (uniform 4x128, fp16) ==============
__global__ __launch_bounds__(256) void k_edge(
        const _Float16* __restrict__ nl_h,  // [256,50,32] fp16
        const float* __restrict__ u,        // [256,512]
        const float* __restrict__ pW1,      // [50,512]
        const float* __restrict__ W_e1,     // [576,512]
        const float* __restrict__ b_e1,     // [512]
        const float* __restrict__ W_e2,     // [512,5]
        float* __restrict__ P) {            // [4][256][1225][5]
    int b  = blockIdx.x;
    int rh = blockIdx.y;
    int t  = threadIdx.x;
    int rbase = rh * ECH;
    constexpr int ech4 = ECH / 4;           // 32

    __shared__ __align__(16) _Float16 Ah[NDIM * ECH];  // 12.8 KB
    __shared__ __align__(16) _Float16 Bh[NDIM * ECH];  // 12.8 KB
    __shared__ v2h W2h[ECH / 2][EOUT];                 // 1.28 KB

    for (int i = t; i < (ECH / 2) * EOUT; i += 256) {
        int p = i / EOUT, o = i - p * EOUT;
        v2h w;
        w.x = (_Float16)W_e2[(size_t)(rbase + 2 * p) * EOUT + o];
        w.y = (_Float16)W_e2[(size_t)(rbase + 2 * p + 1) * EOUT + o];
        W2h[p][o] = w;
    }

    bool has = (t < 225);
    int pp = 0, qq = 0;
    if (has) {
        int tt = t;
        for (pp = 0; pp < 25; ++pp) {
            int qmin = pp ? ((2 * pp - 2) / 3 + 1) : 0;
            int cnt = 17 - qmin;
            if (tt < cnt) { qq = qmin + tt; break; }
            tt -= cnt;
        }
    }
    int i0 = 2 * pp, i1 = i0 + 1;
    int j0 = 3 * qq, j1 = j0 + 1, j2r = (3 * qq + 2 < NDIM) ? 3 * qq + 2 : NDIM - 1;

    float acc[6][EOUT];
#pragma unroll
    for (int e = 0; e < 6; ++e)
#pragma unroll
        for (int o = 0; o < EOUT; ++o) acc[e][o] = 0.f;

    // ---- produce ----
    {
        int arr = t >> 7, c = t & 127;
        int col = rbase + c;
        const v2h* nlh = reinterpret_cast<const v2h*>(nl_h + (size_t)b * (NDIM * DDIM));
        v2h wv[16];
#pragma unroll
        for (int k2 = 0; k2 < 16; ++k2) {
            v2h w;
            w.x = (_Float16)W_e1[(size_t)(HDIM + arr * DDIM + 2 * k2) * HDIM + col];
            w.y = (_Float16)W_e1[(size_t)(HDIM + arr * DDIM + 2 * k2 + 1) * HDIM + col];
            wv[k2] = w;
        }
        float cm = 0.5f * (u[(size_t)b * HDIM + col] + b_e1[col]);
        _Float16* dst = arr ? Bh : Ah;
        float pc = pW1[col];
        for (int n = 0; n < NDIM; ++n) {
            float pn = (n < NDIM - 1) ? pW1[(size_t)(n + 1) * HDIM + col] : 0.f;
            const v2h* nr = nlh + n * 16;
            float s0 = 0.f, s1 = 0.f, s2 = 0.f, s3 = 0.f;
#pragma unroll
            for (int q = 0; q < 4; ++q) {
                s0 = fdot2f(nr[q],      wv[q],      s0);
                s1 = fdot2f(nr[4 + q],  wv[4 + q],  s1);
                s2 = fdot2f(nr[8 + q],  wv[8 + q],  s2);
                s3 = fdot2f(nr[12 + q], wv[12 + q], s3);
            }
            float val = (cm + pc) + ((s0 + s1) + (s2 + s3));
            dst[n * ECH + ((((c >> 2) ^ (n & 7)) << 2) | (c & 3))] = (_Float16)val;
            pc = pn;
        }
    }
    __syncthreads();

    // ---- consume ----
    if (has) {
        int sA = i0 & 7, sB = i1 & 7, s0m = j0 & 7, s1m = j1 & 7, s2m = j2r & 7;
        for (int r4 = 0; r4 < ech4; ++r4) {
            h4 ra0 = *reinterpret_cast<const h4*>(&Ah[i0 * ECH + ((r4 ^ sA) << 2)]);
            h4 ra1 = *reinterpret_cast<const h4*>(&Ah[i1 * ECH + ((r4 ^ sB) << 2)]);
            h4 rb0 = *reinterpret_cast<const h4*>(&Bh[j0 * ECH + ((r4 ^ s0m) << 2)]);
            h4 rb1 = *reinterpret_cast<const h4*>(&Bh[j1 * ECH + ((r4 ^ s1m) << 2)]);
            h4 rb2 = *reinterpret_cast<const h4*>(&Bh[j2r * ECH + ((r4 ^ s2m) << 2)]);
            v2h v0l = relu2(ra0.lo, rb0.lo), v0h = relu2(ra0.hi, rb0.hi);
            v2h v1l = relu2(ra0.lo, rb1.lo), v1h = relu2(ra0.hi, rb1.hi);
            v2h v2l = relu2(ra0.lo, rb2.lo), v2hh = relu2(ra0.hi, rb2.hi);
            v2h v3l = relu2(ra1.lo, rb0.lo), v3h = relu2(ra1.hi, rb0.hi);
            v2h v4l = relu2(ra1.lo, rb1.lo), v4h = relu2(ra1.hi, rb1.hi);
            v2h v5l = relu2(ra1.lo, rb2.lo), v5h = relu2(ra1.hi, rb2.hi);
            int pb = r4 * 2;
#pragma unroll
            for (int o = 0; o < EOUT; ++o) {
                v2h wl = W2h[pb][o], wh = W2h[pb + 1][o];
                acc[0][o] = fdot2f(v0h, wh, fdot2f(v0l, wl, acc[0][o]));
                acc[1][o] = fdot2f(v1h, wh, fdot2f(v1l, wl, acc[1][o]));
                acc[2][o] = fdot2f(v2hh, wh, fdot2f(v2l, wl, acc[2][o]));
                acc[3][o] = fdot2f(v3h, wh, fdot2f(v3l, wl, acc[3][o]));
                acc[4][o] = fdot2f(v4h, wh, fdot2f(v4l, wl, acc[4][o]));
                acc[5][o] = fdot2f(v5h, wh, fdot2f(v5l, wl, acc[5][o]));
            }
        }
    }
    __syncthreads();

    if (has) {
        float* Pb = P + ((size_t)rh * BSZ + b) * NEDGE * EOUT;
        int js[3] = {j0, j1, 3 * qq + 2};
#pragma unroll
        for (int r = 0; r < 2; ++r) {
            int i = i0 + r;
#pragma unroll
            for (int cc = 0; cc < 3; ++cc) {
                int j = js[cc];
                if (i < j && j < NDIM) {
                    int e = i * (NDIM - 1) - (i * (i - 1)) / 2 + (j - i - 1);
#pragma unroll
                    for (int o = 0; o < EOUT; ++o)
                        Pb[(size_t)e * EOUT + o] = acc[r * 3 + cc][o];
                }
            }
        }
    }
}

// ============ k_comb: out_el = P0+P1+P2+P3 + bias ==========================
__global__ __launch_bounds__(256) void k_comb(const float* __restrict__ P,
                                              const float* __restrict__ b_e2,
                                              float* __restrict__ out_el,
                                              float* __restrict__ out_idx) {
    int blk = blockIdx.x, t = threadIdx.x;
    const size_t PS = (size_t)BSZ * NEDGE * EOUT;
    if (blk < 307) {
        int tid = blk * 256 + t;
        if (tid < 78400) {
            float b5[5];
#pragma unroll
            for (int cc = 0; cc < 5; ++cc) b5[cc] = b_e2[cc];
#pragma unroll
            for (int q = 0; q < 5; ++q) {
                float4 s = make_float4(0.f, 0.f, 0.f, 0.f);
#pragma unroll
                for (int p = 0; p < NRH; ++p) {
                    float4 v = reinterpret_cast<const float4*>(P + (size_t)p * PS)[(size_t)tid * 5 + q];
                    s.x += v.x; s.y += v.y; s.z += v.z; s.w += v.w;
                }
                float4 r;
                r.x = s.x + b5[(q * 4 + 0) % 5];
                r.y = s.y + b5[(q * 4 + 1) % 5];
                r.z = s.z + b5[(q * 4 + 2) % 5];
                r.w = s.w + b5[(q * 4 + 3) % 5];
                reinterpret_cast<float4*>(out_el)[(size_t)tid * 5 + q] = r;
            }
        }
    } else {
        int e = (blk - 307) * 256 + t;
        if (e < NEDGE) {
            int i = 0, rem = e;
            while (rem >= (NDIM - 1 - i)) { rem -= (NDIM - 1 - i); ++i; }
            int j = i + 1 + rem;
            out_idx[e * 2] = (float)i;
            out_idx[e * 2 + 1] = (float)j;
        }
    }
}

extern "C" void kernel_launch(void* const* d_in, const int* in_sizes, int n_in,
                              void* d_out, int out_size, void* d_ws, size_t ws_size,
                              hipStream_t stream) {
    const float* z    = (const float*)d_in[0];
    const float* tp   = (const float*)d_in[1];
    const float* W_in = (const float*)d_in[2];
    const float* b_in = (const float*)d_in[3];
    const float* W_s1 = (const float*)d_in[4];
    const float* b_s1 = (const float*)d_in[5];
    const float* W_s2 = (const float*)d_in[6];
    const float* b_s2 = (const float*)d_in[7];
    const float* W_n1 = (const float*)d_in[8];
    const float* b_n1 = (const float*)d_in[9];
    const float* W_n2 = (const float*)d_in[10];
    const float* b_n2 = (const float*)d_in[11];
    const float* W_e1 = (const float*)d_in[12];
    const float* b_e1 = (const float*)d_in[13];
    const float* W_e2 = (const float*)d_in[14];
    const float* b_e2 = (const float*)d_in[15];
    const float* pe   = (const float*)d_in[16];

    float* out     = (float*)d_out;
    float* out_nl  = out;                 // node_logits
    float* out_el  = out + 409600;        // edge_logits
    float* out_sp  = out + 1977600;       // size_probs
    float* out_idx = out + 1990400;       // edge_indices (as float)

    float* ws   = (float*)d_ws;
    float* u    = ws;
    float* pW1  = ws + 131072;
    float* n1   = ws + 156672;
    float* P    = ws + 287744;            // [4][256][1225][5]
    _Float16* nl_h = (_Float16*)(ws + 6559744);  // [256,50,32] fp16
    v2h* W1p  = (v2h*)(ws + 6764544);
    v2h* Wep  = (v2h*)(ws + 6895616);
    v2h* Wsp  = (v2h*)(ws + 7026688);
    v2h* Winp = (v2h*)(ws + 7092224);

    k_prep<<<1416, 256, 0, stream>>>(W_n1, W_e1, W_s1, W_in, W1p, Wep, Wsp, Winp);
    k_pre<<<666, 256, 0, stream>>>(z, tp, b_in, b_s1, W_s2, b_s2, b_n1, pe,
                                   W1p, Wep, Wsp, Winp, n1, u, pW1, out_sp);
    k_nl<<<dim3(128, 5), 320, 0, stream>>>(n1, W_n2, b_n2, out_nl, nl_h);
    k_edge<<<dim3(BSZ, NRH), 256, 0, stream>>>(nl_h, u, pW1, W_e1, b_e1, W_e2, P);
    k_comb<<<312, 256, 0, stream>>>(P, b_e2, out_el, out_idx);
}

// Round 23
// 97.923 us; speedup vs baseline: 1.6774x; 1.1882x over previous
//
#include <hip/hip_runtime.h>
#include <math.h>

// Problem dims
#define BSZ   256
#define LDIM  128
#define PDIM  3
#define HDIM  512
#define DDIM  32
#define NDIM  50
#define NEDGE 1225   // N*(N-1)/2
#define EOUT  5      // EDIM+1
#define NRH   4      // r-splits: 4 x 128 cols
#define ECH   128    // cols per edge block

// out layout (floats)
//   node_logits  [256,50,32]   @ 0        (409600)
//   edge_logits  [256,1225,5]  @ 409600   (1568000)
//   size_probs   [256,50]      @ 1977600  (12800)
//   edge_indices [1225,2]      @ 1990400  (2450, float values)
// ws layout (floats):
//   u @0 (131072), pW1 @131072 (25600), n1 @156672 (131072),
//   P_h @287744 (4 x 1568000 halves = 3136000 fl), nl_h @6559744 (204800),
//   W1p @6764544 (131072), Wep @6895616 (131072), Wsp @7026688 (65536),
//   Winp @7092224 (34816), Wn2p @7127040 (409600)

typedef _Float16 v2h __attribute__((ext_vector_type(2)));

__device__ __forceinline__ float fdot2f(v2h a, v2h b, float c) {
    return __builtin_amdgcn_fdot2(a, b, c, false);
}
__device__ __forceinline__ v2h relu2(v2h a, v2h b) {
    v2h s = a + b;
    v2h z = {(_Float16)0.f, (_Float16)0.f};
    return __builtin_elementwise_max(s, z);
}
struct h4 { v2h lo, hi; };
struct h8 { v2h a, b, c, d; };   // 16B

// ============ k_prep: pack weights into fp16 k-pair layouts ================
// W1p (W_n1), Wep (W_e1 rows 0..511), Wsp (W_s1), Winp (W_in padded),
// Wn2p (W_n2, [k8=64][1600][4] = 409600 v2h).
__global__ __launch_bounds__(256) void k_prep(
        const float* __restrict__ W_n1, const float* __restrict__ W_e1,
        const float* __restrict__ W_s1, const float* __restrict__ W_in,
        const float* __restrict__ W_n2,
        v2h* __restrict__ W1p, v2h* __restrict__ Wep,
        v2h* __restrict__ Wsp, v2h* __restrict__ Winp,
        v2h* __restrict__ Wn2p) {
    int f = blockIdx.x * 256 + threadIdx.x;
    if (f < 131072) {
        int q = f & 3, t1 = f >> 2, j = t1 & 511, k8 = t1 >> 9;
        int k2 = k8 * 4 + q;
        v2h w;
        w.x = (_Float16)W_n1[(size_t)(2 * k2) * HDIM + j];
        w.y = (_Float16)W_n1[(size_t)(2 * k2 + 1) * HDIM + j];
        W1p[f] = w;
    } else if (f < 262144) {
        int g = f - 131072;
        int q = g & 3, t1 = g >> 2, j = t1 & 511, k8 = t1 >> 9;
        int k2 = k8 * 4 + q;
        v2h w;
        w.x = (_Float16)W_e1[(size_t)(2 * k2) * HDIM + j];
        w.y = (_Float16)W_e1[(size_t)(2 * k2 + 1) * HDIM + j];
        Wep[g] = w;
    } else if (f < 327680) {
        int g = f - 262144;
        int q = g & 3, t1 = g >> 2, j = t1 & 255, k8 = t1 >> 8;
        int k2 = k8 * 4 + q;
        v2h w;
        w.x = (_Float16)W_s1[(size_t)(2 * k2) * (HDIM / 2) + j];
        w.y = (_Float16)W_s1[(size_t)(2 * k2 + 1) * (HDIM / 2) + j];
        Wsp[g] = w;
    } else if (f < 362496) {
        int g = f - 327680;
        int q = g & 3, t1 = g >> 2, j = t1 & 511, k8 = t1 >> 9;
        int k2 = k8 * 4 + q;     // 0..67
        int r0 = 2 * k2, r1 = 2 * k2 + 1;
        v2h w;
        w.x = (r0 < LDIM + PDIM) ? (_Float16)W_in[(size_t)r0 * HDIM + j] : (_Float16)0.f;
        w.y = (r1 < LDIM + PDIM) ? (_Float16)W_in[(size_t)r1 * HDIM + j] : (_Float16)0.f;
        Winp[g] = w;
    } else if (f < 362496 + 409600) {
        int g = f - 362496;
        int q = g & 3, t1 = g >> 2;      // t1 < 102400
        int j = t1 % 1600, k8 = t1 / 1600;   // k8 < 64
        int k2 = k8 * 4 + q;             // < 256
        v2h w;
        w.x = (_Float16)W_n2[(size_t)(2 * k2) * 1600 + j];
        w.y = (_Float16)W_n2[(size_t)(2 * k2 + 1) * 1600 + j];
        Wn2p[g] = w;
    }
}

// helper: stage packed inputs [2][68] v2h from z/tp
__device__ __forceinline__ void stage_sin2(v2h* sin2, const float* z, const float* tp,
                                           int b0, int t) {
    if (t < 136) {
        int bi = (t >= 68) ? 1 : 0;
        int k2 = t - (bi ? 68 : 0);
        int k0 = 2 * k2, k1 = 2 * k2 + 1;
        float v0 = (k0 < LDIM) ? z[(size_t)(b0 + bi) * LDIM + k0]
                 : (k0 < LDIM + PDIM) ? tp[(size_t)(b0 + bi) * PDIM + (k0 - LDIM)] : 0.f;
        float v1 = (k1 < LDIM) ? z[(size_t)(b0 + bi) * LDIM + k1]
                 : (k1 < LDIM + PDIM) ? tp[(size_t)(b0 + bi) * PDIM + (k1 - LDIM)] : 0.f;
        v2h v; v.x = (_Float16)v0; v.y = (_Float16)v1;
        sin2[bi * 68 + k2] = v;
    }
}

// helper: phase1 h for 2 batches via packed W_in; writes sh[2][512] fp32
__device__ __forceinline__ void phase1_h(const v2h* sin2, const v2h* Winp,
                                         const float* b_in, float* sh, int t) {
    float bin0 = b_in[t], bin1 = b_in[t + 256];
    float a00 = bin0, a01 = bin1, a10 = bin0, a11 = bin1;
    for (int k8 = 0; k8 < 17; ++k8) {
        h8 s0 = *reinterpret_cast<const h8*>(&sin2[k8 * 4]);
        h8 s1 = *reinterpret_cast<const h8*>(&sin2[68 + k8 * 4]);
        h8 w0 = *reinterpret_cast<const h8*>(&Winp[(size_t)(k8 * 512 + t) * 4]);
        h8 w1 = *reinterpret_cast<const h8*>(&Winp[(size_t)(k8 * 512 + t + 256) * 4]);
        a00 = fdot2f(s0.a, w0.a, a00); a00 = fdot2f(s0.b, w0.b, a00);
        a00 = fdot2f(s0.c, w0.c, a00); a00 = fdot2f(s0.d, w0.d, a00);
        a01 = fdot2f(s0.a, w1.a, a01); a01 = fdot2f(s0.b, w1.b, a01);
        a01 = fdot2f(s0.c, w1.c, a01); a01 = fdot2f(s0.d, w1.d, a01);
        a10 = fdot2f(s1.a, w0.a, a10); a10 = fdot2f(s1.b, w0.b, a10);
        a10 = fdot2f(s1.c, w0.c, a10); a10 = fdot2f(s1.d, w0.d, a10);
        a11 = fdot2f(s1.a, w1.a, a11); a11 = fdot2f(s1.b, w1.b, a11);
        a11 = fdot2f(s1.c, w1.c, a11); a11 = fdot2f(s1.d, w1.d, a11);
    }
    sh[t] = fmaxf(a00, 0.f); sh[t + 256] = fmaxf(a01, 0.f);
    sh[512 + t] = fmaxf(a10, 0.f); sh[512 + t + 256] = fmaxf(a11, 0.f);
}

// ============ k_pre: fp16-packed sweeps (round-21 champion) ================
__global__ __launch_bounds__(256) void k_pre(
        const float* __restrict__ z, const float* __restrict__ tp,
        const float* __restrict__ b_in,
        const float* __restrict__ b_s1,
        const float* __restrict__ W_s2, const float* __restrict__ b_s2,
        const float* __restrict__ b_n1,
        const float* __restrict__ pe,
        const v2h* __restrict__ W1p, const v2h* __restrict__ Wep,
        const v2h* __restrict__ Wsp, const v2h* __restrict__ Winp,
        float* __restrict__ n1, float* __restrict__ u,
        float* __restrict__ pW1, float* __restrict__ out_sp) {
    int bx = blockIdx.x, t = threadIdx.x;
    __shared__ float smem[2560];

    if (bx < 512) {
        int role = bx >> 8;
        int idx2 = bx & 255;
        int bg = idx2 >> 1, jh = idx2 & 1;
        int b0 = bg * 2;
        v2h* sin2 = reinterpret_cast<v2h*>(smem);        // 136 v2h
        float* sh  = smem + 136;                          // [2][512]
        v2h* h2    = reinterpret_cast<v2h*>(smem + 1160); // [2][256] v2h
        stage_sin2(sin2, z, tp, b0, t);
        __syncthreads();
        phase1_h(sin2, Winp, b_in, sh, t);
        __syncthreads();
        for (int idx = t; idx < 512; idx += 256) {
            int bi = idx >> 8, k2 = idx & 255;
            v2h v; v.x = (_Float16)sh[bi * 512 + 2 * k2];
            v.y = (_Float16)sh[bi * 512 + 2 * k2 + 1];
            h2[bi * 256 + k2] = v;
        }
        __syncthreads();
        int j = jh * 256 + t;
        const v2h* Wp = role ? Wep : W1p;
        float a0 = 0.f, a0b = 0.f, a1 = 0.f, a1b = 0.f;
        for (int k8 = 0; k8 < 64; ++k8) {
            h8 ha = *reinterpret_cast<const h8*>(&h2[k8 * 4]);
            h8 hb = *reinterpret_cast<const h8*>(&h2[256 + k8 * 4]);
            h8 w  = *reinterpret_cast<const h8*>(&Wp[(size_t)(k8 * 512 + j) * 4]);
            a0  = fdot2f(ha.a, w.a, a0);  a0  = fdot2f(ha.b, w.b, a0);
            a0b = fdot2f(ha.c, w.c, a0b); a0b = fdot2f(ha.d, w.d, a0b);
            a1  = fdot2f(hb.a, w.a, a1);  a1  = fdot2f(hb.b, w.b, a1);
            a1b = fdot2f(hb.c, w.c, a1b); a1b = fdot2f(hb.d, w.d, a1b);
        }
        float r0 = a0 + a0b, r1 = a1 + a1b;
        if (role == 0) {
            float bb = b_n1[j];
            n1[(size_t)(b0 + 0) * HDIM + j] = fmaxf(r0 + bb, 0.f);
            n1[(size_t)(b0 + 1) * HDIM + j] = fmaxf(r1 + bb, 0.f);
        } else {
            u[(size_t)(b0 + 0) * HDIM + j] = r0;
            u[(size_t)(b0 + 1) * HDIM + j] = r1;
        }
    } else if (bx < 640) {
        int b0 = (bx - 512) * 2;
        v2h* sin2 = reinterpret_cast<v2h*>(smem);
        float* sh  = smem + 136;
        v2h* h2    = reinterpret_cast<v2h*>(smem + 1160);
        float* s1b = smem + 1672;
        float* slg = smem + 2184;
        stage_sin2(sin2, z, tp, b0, t);
        __syncthreads();
        phase1_h(sin2, Winp, b_in, sh, t);
        __syncthreads();
        for (int idx = t; idx < 512; idx += 256) {
            int bi = idx >> 8, k2 = idx & 255;
            v2h v; v.x = (_Float16)sh[bi * 512 + 2 * k2];
            v.y = (_Float16)sh[bi * 512 + 2 * k2 + 1];
            h2[bi * 256 + k2] = v;
        }
        __syncthreads();
        {
            float bv = b_s1[t];
            float a0 = bv, a0b = 0.f, a1 = bv, a1b = 0.f;
            for (int k8 = 0; k8 < 64; ++k8) {
                h8 ha = *reinterpret_cast<const h8*>(&h2[k8 * 4]);
                h8 hb = *reinterpret_cast<const h8*>(&h2[256 + k8 * 4]);
                h8 w  = *reinterpret_cast<const h8*>(&Wsp[(size_t)(k8 * 256 + t) * 4]);
                a0  = fdot2f(ha.a, w.a, a0);  a0  = fdot2f(ha.b, w.b, a0);
                a0b = fdot2f(ha.c, w.c, a0b); a0b = fdot2f(ha.d, w.d, a0b);
                a1  = fdot2f(hb.a, w.a, a1);  a1  = fdot2f(hb.b, w.b, a1);
                a1b = fdot2f(hb.c, w.c, a1b); a1b = fdot2f(hb.d, w.d, a1b);
            }
            s1b[t] = fmaxf(a0 + a0b, 0.f);
            s1b[256 + t] = fmaxf(a1 + a1b, 0.f);
        }
        __syncthreads();
        int b4 = t / NDIM, o = t % NDIM;
        if (t < 2 * NDIM) {
            float a = b_s2[o];
            for (int k = 0; k < HDIM / 2; ++k)
                a += s1b[b4 * 256 + k] * W_s2[(size_t)k * NDIM + o];
            slg[b4 * NDIM + o] = a;
        }
        __syncthreads();
        if (t < 2 * NDIM) {
            float m = slg[b4 * NDIM];
            for (int k = 1; k < NDIM; ++k) m = fmaxf(m, slg[b4 * NDIM + k]);
            float s = 0.f;
            for (int k = 0; k < NDIM; ++k) s += expf(slg[b4 * NDIM + k] - m);
            out_sp[(size_t)(b0 + b4) * NDIM + o] = expf(slg[b4 * NDIM + o] - m) / s;
        }
    } else {
        int g = bx - 640, rg = g >> 1, jh = g & 1;
        int r[4];
#pragma unroll
        for (int q = 0; q < 4; ++q) { int rr = rg * 4 + q; r[q] = (rr < NDIM) ? rr : NDIM - 1; }
        v2h* pe2 = reinterpret_cast<v2h*>(smem);   // [4][256] v2h
        for (int idx = t; idx < 4 * 256; idx += 256) {
            int row = idx >> 8, k2 = idx & 255;
            v2h v;
            v.x = (_Float16)pe[(size_t)r[row] * HDIM + 2 * k2];
            v.y = (_Float16)pe[(size_t)r[row] * HDIM + 2 * k2 + 1];
            pe2[idx] = v;
        }
        __syncthreads();
        int j = jh * 256 + t;
        float a0 = 0.f, a0b = 0.f, a1 = 0.f, a1b = 0.f;
        float a2 = 0.f, a2b = 0.f, a3 = 0.f, a3b = 0.f;
        for (int k8 = 0; k8 < 64; ++k8) {
            h8 p0 = *reinterpret_cast<const h8*>(&pe2[0 * 256 + k8 * 4]);
            h8 p1 = *reinterpret_cast<const h8*>(&pe2[1 * 256 + k8 * 4]);
            h8 p2 = *reinterpret_cast<const h8*>(&pe2[2 * 256 + k8 * 4]);
            h8 p3 = *reinterpret_cast<const h8*>(&pe2[3 * 256 + k8 * 4]);
            h8 w  = *reinterpret_cast<const h8*>(&Wep[(size_t)(k8 * 512 + j) * 4]);
            a0  = fdot2f(p0.a, w.a, a0);  a0  = fdot2f(p0.b, w.b, a0);
            a0b = fdot2f(p0.c, w.c, a0b); a0b = fdot2f(p0.d, w.d, a0b);
            a1  = fdot2f(p1.a, w.a, a1);  a1  = fdot2f(p1.b, w.b, a1);
            a1b = fdot2f(p1.c, w.c, a1b); a1b = fdot2f(p1.d, w.d, a1b);
            a2  = fdot2f(p2.a, w.a, a2);  a2  = fdot2f(p2.b, w.b, a2);
            a2b = fdot2f(p2.c, w.c, a2b); a2b = fdot2f(p2.d, w.d, a2b);
            a3  = fdot2f(p3.a, w.a, a3);  a3  = fdot2f(p3.b, w.b, a3);
            a3b = fdot2f(p3.c, w.c, a3b); a3b = fdot2f(p3.d, w.d, a3b);
        }
        pW1[(size_t)r[0] * HDIM + j] = 0.5f * (a0 + a0b);
        pW1[(size_t)r[1] * HDIM + j] = 0.5f * (a1 + a1b);
        pW1[(size_t)r[2] * HDIM + j] = 0.5f * (a2 + a2b);
        pW1[(size_t)r[3] * HDIM + j] = 0.5f * (a3 + a3b);
    }
}

// ============ k_nl: fp16-packed W_n2 sweep, 2 batches/block ================
__global__ __launch_bounds__(320) void k_nl(const float* __restrict__ n1,
                                            const v2h* __restrict__ Wn2p,
                                            const float* __restrict__ b_n2,
                                            float* __restrict__ out_nl,
                                            _Float16* __restrict__ nl_h) {
    const int NOUT = NDIM * DDIM;   // 1600
    int t = threadIdx.x;
    int j = blockIdx.y * 320 + t;
    int bg = blockIdx.x;            // 2 batches
    __shared__ v2h h2s[512];        // [2][256]
    for (int idx = t; idx < 512; idx += 320) {
        int bi = idx >> 8, k2 = idx & 255;
        v2h v;
        v.x = (_Float16)n1[(size_t)(bg * 2 + bi) * HDIM + 2 * k2];
        v.y = (_Float16)n1[(size_t)(bg * 2 + bi) * HDIM + 2 * k2 + 1];
        h2s[idx] = v;
    }
    __syncthreads();
    float a0 = 0.f, a0b = 0.f, a1 = 0.f, a1b = 0.f;
    for (int k8 = 0; k8 < 64; ++k8) {
        h8 ha = *reinterpret_cast<const h8*>(&h2s[k8 * 4]);
        h8 hb = *reinterpret_cast<const h8*>(&h2s[256 + k8 * 4]);
        h8 w  = *reinterpret_cast<const h8*>(&Wn2p[((size_t)k8 * 1600 + j) * 4]);
        a0  = fdot2f(ha.a, w.a, a0);  a0  = fdot2f(ha.b, w.b, a0);
        a0b = fdot2f(ha.c, w.c, a0b); a0b = fdot2f(ha.d, w.d, a0b);
        a1  = fdot2f(hb.a, w.a, a1);  a1  = fdot2f(hb.b, w.b, a1);
        a1b = fdot2f(hb.c, w.c, a1b); a1b = fdot2f(hb.d, w.d, a1b);
    }
    float bias = b_n2[j];
    float r0 = bias + a0 + a0b;
    float r1 = bias + a1 + a1b;
    out_nl[(size_t)(bg * 2 + 0) * NOUT + j] = r0;
    out_nl[(size_t)(bg * 2 + 1) * NOUT + j] = r1;
    nl_h[(size_t)(bg * 2 + 0) * NOUT + j] = (_Float16)r0;
    nl_h[(size_t)(bg * 2 + 1) * NOUT + j] = (_Float16)r1;
}

// ============ k_edge: round-20/21 champion, fp16 P partials ================
__global__ __launch_bounds__(256) void k_edge(
        const _Float16* __restrict__ nl_h,  // [256,50,32] fp16
        const float* __restrict__ u,        // [256,512]
        const float* __restrict__ pW1,      // [50,512]
        const float* __restrict__ W_e1,     // [576,512]
        const float* __restrict__ b_e1,     // [512]
        const float* __restrict__ W_e2,     // [512,5]
        _Float16* __restrict__ P) {         // [4][256][1225][5] fp16
    int b  = blockIdx.x;
    int rh = blockIdx.y;
    int t  = threadIdx.x;
    int rbase = rh * ECH;
    constexpr int ech4 = ECH / 4;           // 32

    __shared__ __align__(16) _Float16 Ah[NDIM * ECH];  // 12.8 KB
    __shared__ __align__(16) _Float16 Bh[NDIM * ECH];  // 12.8 KB
    __shared__ v2h W2h[ECH / 2][EOUT];                 // 1.28 KB

    for (int i = t; i < (ECH / 2) * EOUT; i += 256) {
        int p = i / EOUT, o = i - p * EOUT;
        v2h w;
        w.x = (_Float16)W_e2[(size_t)(rbase + 2 * p) * EOUT + o];
        w.y = (_Float16)W_e2[(size_t)(rbase + 2 * p + 1) * EOUT + o];
        W2h[p][o] = w;
    }

    bool has = (t < 225);
    int pp = 0, qq = 0;
    if (has) {
        int tt = t;
        for (pp = 0; pp < 25; ++pp) {
            int qmin = pp ? ((2 * pp - 2) / 3 + 1) : 0;
            int cnt = 17 - qmin;
            if (tt < cnt) { qq = qmin + tt; break; }
            tt -= cnt;
        }
    }
    int i0 = 2 * pp, i1 = i0 + 1;
    int j0 = 3 * qq, j1 = j0 + 1, j2r = (3 * qq + 2 < NDIM) ? 3 * qq + 2 : NDIM - 1;

    float acc[6][EOUT];
#pragma unroll
    for (int e = 0; e < 6; ++e)
#pragma unroll
        for (int o = 0; o < EOUT; ++o) acc[e][o] = 0.f;

    // ---- produce ----
    {
        int arr = t >> 7, c = t & 127;
        int col = rbase + c;
        const v2h* nlh = reinterpret_cast<const v2h*>(nl_h + (size_t)b * (NDIM * DDIM));
        v2h wv[16];
#pragma unroll
        for (int k2 = 0; k2 < 16; ++k2) {
            v2h w;
            w.x = (_Float16)W_e1[(size_t)(HDIM + arr * DDIM + 2 * k2) * HDIM + col];
            w.y = (_Float16)W_e1[(size_t)(HDIM + arr * DDIM + 2 * k2 + 1) * HDIM + col];
            wv[k2] = w;
        }
        float cm = 0.5f * (u[(size_t)b * HDIM + col] + b_e1[col]);
        _Float16* dst = arr ? Bh : Ah;
        float pc = pW1[col];
        for (int n = 0; n < NDIM; ++n) {
            float pn = (n < NDIM - 1) ? pW1[(size_t)(n + 1) * HDIM + col] : 0.f;
            const v2h* nr = nlh + n * 16;
            float s0 = 0.f, s1 = 0.f, s2 = 0.f, s3 = 0.f;
#pragma unroll
            for (int q = 0; q < 4; ++q) {
                s0 = fdot2f(nr[q],      wv[q],      s0);
                s1 = fdot2f(nr[4 + q],  wv[4 + q],  s1);
                s2 = fdot2f(nr[8 + q],  wv[8 + q],  s2);
                s3 = fdot2f(nr[12 + q], wv[12 + q], s3);
            }
            float val = (cm + pc) + ((s0 + s1) + (s2 + s3));
            dst[n * ECH + ((((c >> 2) ^ (n & 7)) << 2) | (c & 3))] = (_Float16)val;
            pc = pn;
        }
    }
    __syncthreads();

    // ---- consume ----
    if (has) {
        int sA = i0 & 7, sB = i1 & 7, s0m = j0 & 7, s1m = j1 & 7, s2m = j2r & 7;
        for (int r4 = 0; r4 < ech4; ++r4) {
            h4 ra0 = *reinterpret_cast<const h4*>(&Ah[i0 * ECH + ((r4 ^ sA) << 2)]);
            h4 ra1 = *reinterpret_cast<const h4*>(&Ah[i1 * ECH + ((r4 ^ sB) << 2)]);
            h4 rb0 = *reinterpret_cast<const h4*>(&Bh[j0 * ECH + ((r4 ^ s0m) << 2)]);
            h4 rb1 = *reinterpret_cast<const h4*>(&Bh[j1 * ECH + ((r4 ^ s1m) << 2)]);
            h4 rb2 = *reinterpret_cast<const h4*>(&Bh[j2r * ECH + ((r4 ^ s2m) << 2)]);
            v2h v0l = relu2(ra0.lo, rb0.lo), v0h = relu2(ra0.hi, rb0.hi);
            v2h v1l = relu2(ra0.lo, rb1.lo), v1h = relu2(ra0.hi, rb1.hi);
            v2h v2l = relu2(ra0.lo, rb2.lo), v2hh = relu2(ra0.hi, rb2.hi);
            v2h v3l = relu2(ra1.lo, rb0.lo), v3h = relu2(ra1.hi, rb0.hi);
            v2h v4l = relu2(ra1.lo, rb1.lo), v4h = relu2(ra1.hi, rb1.hi);
            v2h v5l = relu2(ra1.lo, rb2.lo), v5h = relu2(ra1.hi, rb2.hi);
            int pb = r4 * 2;
#pragma unroll
            for (int o = 0; o < EOUT; ++o) {
                v2h wl = W2h[pb][o], wh = W2h[pb + 1][o];
                acc[0][o] = fdot2f(v0h, wh, fdot2f(v0l, wl, acc[0][o]));
                acc[1][o] = fdot2f(v1h, wh, fdot2f(v1l, wl, acc[1][o]));
                acc[2][o] = fdot2f(v2hh, wh, fdot2f(v2l, wl, acc[2][o]));
                acc[3][o] = fdot2f(v3h, wh, fdot2f(v3l, wl, acc[3][o]));
                acc[4][o] = fdot2f(v4h, wh, fdot2f(v4l, wl, acc[4][o]));
                acc[5][o] = fdot2f(v5h, wh, fdot2f(v5l, wl, acc[5][o]));
            }
        }
    }
    __syncthreads();

    if (has) {
        _Float16* Pb = P + ((size_t)rh * BSZ + b) * NEDGE * EOUT;
        int js[3] = {j0, j1, 3 * qq + 2};
#pragma unroll
        for (int r = 0; r < 2; ++r) {
            int i = i0 + r;
#pragma unroll
            for (int cc = 0; cc < 3; ++cc) {
                int j = js[cc];
                if (i < j && j < NDIM) {
                    int e = i * (NDIM - 1) - (i * (i - 1)) / 2 + (j - i - 1);
#pragma unroll
                    for (int o = 0; o < EOUT; ++o)
                        Pb[(size_t)e * EOUT + o] = (_Float16)acc[r * 3 + cc][o];
                }
            }
        }
    }
}

// ============ k_comb: out_el = sum of 4 fp16 partials + bias ===============
// blocks 0..765: 8 elements/thread (h8 loads); blocks 766..770: edge_indices.
__global__ __launch_bounds__(256) void k_comb(const _Float16* __restrict__ P,
                                              const float* __restrict__ b_e2,
                                              float* __restrict__ out_el,
                                              float* __restrict__ out_idx) {
    int blk = blockIdx.x, t = threadIdx.x;
    const size_t PS = (size_t)BSZ * NEDGE * EOUT;   // 1568000 halves
    if (blk < 766) {
        int tid = blk * 256 + t;       // h8 unit index; 196000 total
        if (tid < 196000) {
            float s[8];
#pragma unroll
            for (int e = 0; e < 8; ++e) s[e] = 0.f;
#pragma unroll
            for (int p = 0; p < NRH; ++p) {
                h8 v = reinterpret_cast<const h8*>(P + (size_t)p * PS)[tid];
                s[0] += (float)v.a.x; s[1] += (float)v.a.y;
                s[2] += (float)v.b.x; s[3] += (float)v.b.y;
                s[4] += (float)v.c.x; s[5] += (float)v.c.y;
                s[6] += (float)v.d.x; s[7] += (float)v.d.y;
            }
            float b5[5];
#pragma unroll
            for (int cc = 0; cc < 5; ++cc) b5[cc] = b_e2[cc];
            size_t base = (size_t)tid * 8;
            int m = (int)(base % 5);
            float4 r0, r1;
#pragma unroll
            for (int e = 0; e < 8; ++e) {
                float val = s[e] + b5[m];
                if (e < 4) (&r0.x)[e] = val; else (&r1.x)[e - 4] = val;
                m = (m + 1 == 5) ? 0 : m + 1;
            }
            reinterpret_cast<float4*>(out_el + base)[0] = r0;
            reinterpret_cast<float4*>(out_el + base)[1] = r1;
        }
    } else {
        int e = (blk - 766) * 256 + t;
        if (e < NEDGE) {
            int i = 0, rem = e;
            while (rem >= (NDIM - 1 - i)) { rem -= (NDIM - 1 - i); ++i; }
            int j = i + 1 + rem;
            out_idx[e * 2] = (float)i;
            out_idx[e * 2 + 1] = (float)j;
        }
    }
}

extern "C" void kernel_launch(void* const* d_in, const int* in_sizes, int n_in,
                              void* d_out, int out_size, void* d_ws, size_t ws_size,
                              hipStream_t stream) {
    const float* z    = (const float*)d_in[0];
    const float* tp   = (const float*)d_in[1];
    const float* W_in = (const float*)d_in[2];
    const float* b_in = (const float*)d_in[3];
    const float* W_s1 = (const float*)d_in[4];
    const float* b_s1 = (const float*)d_in[5];
    const float* W_s2 = (const float*)d_in[6];
    const float* b_s2 = (const float*)d_in[7];
    const float* W_n1 = (const float*)d_in[8];
    const float* b_n1 = (const float*)d_in[9];
    const float* W_n2 = (const float*)d_in[10];
    const float* b_n2 = (const float*)d_in[11];
    const float* W_e1 = (const float*)d_in[12];
    const float* b_e1 = (const float*)d_in[13];
    const float* W_e2 = (const float*)d_in[14];
    const float* b_e2 = (const float*)d_in[15];
    const float* pe   = (const float*)d_in[16];

    float* out     = (float*)d_out;
    float* out_nl  = out;                 // node_logits
    float* out_el  = out + 409600;        // edge_logits
    float* out_sp  = out + 1977600;       // size_probs
    float* out_idx = out + 1990400;       // edge_indices (as float)

    float* ws   = (float*)d_ws;
    float* u    = ws;
    float* pW1  = ws + 131072;
    float* n1   = ws + 156672;
    _Float16* P_h = (_Float16*)(ws + 287744);    // [4][256][1225][5] fp16
    _Float16* nl_h = (_Float16*)(ws + 6559744);  // [256,50,32] fp16
    v2h* W1p  = (v2h*)(ws + 6764544);
    v2h* Wep  = (v2h*)(ws + 6895616);
    v2h* Wsp  = (v2h*)(ws + 7026688);
    v2h* Winp = (v2h*)(ws + 7092224);
    v2h* Wn2p = (v2h*)(ws + 7127040);

    k_prep<<<3017, 256, 0, stream>>>(W_n1, W_e1, W_s1, W_in, W_n2,
                                     W1p, Wep, Wsp, Winp, Wn2p);
    k_pre<<<666, 256, 0, stream>>>(z, tp, b_in, b_s1, W_s2, b_s2, b_n1, pe,
                                   W1p, Wep, Wsp, Winp, n1, u, pW1, out_sp);
    k_nl<<<dim3(128, 5), 320, 0, stream>>>(n1, Wn2p, b_n2, out_nl, nl_h);
    k_edge<<<dim3(BSZ, NRH), 256, 0, stream>>>(nl_h, u, pW1, W_e1, b_e1, W_e2, P_h);
    k_comb<<<771, 256, 0, stream>>>(P_h, b_e2, out_el, out_idx);
}

// Round 24
// 91.925 us; speedup vs baseline: 1.7868x; 1.0653x over previous
//
#include <hip/hip_runtime.h>
#include <math.h>

// Problem dims
#define BSZ   256
#define LDIM  128
#define PDIM  3
#define HDIM  512
#define DDIM  32
#define NDIM  50
#define NEDGE 1225   // N*(N-1)/2
#define EOUT  5      // EDIM+1
#define NRH   4      // r-splits: 4 x 128 cols
#define ECH   128    // cols per edge block

// ws layout (floats):
//   u @0 (131072), pW1 @131072 (25600), n1 @156672 (131072),
//   P_h @287744 (3136000 fl), nl_h @6559744 (204800),
//   W1p @6764544 (131072), Wep @6895616 (131072), Wsp @7026688 (65536),
//   Winp @7092224 (34816), Wn2p @7127040 (409600), Weeh @7536640 (16384)

typedef _Float16 v2h __attribute__((ext_vector_type(2)));

__device__ __forceinline__ float fdot2f(v2h a, v2h b, float c) {
    return __builtin_amdgcn_fdot2(a, b, c, false);
}
__device__ __forceinline__ v2h relu2(v2h a, v2h b) {
    v2h s = a + b;
    v2h z = {(_Float16)0.f, (_Float16)0.f};
    return __builtin_elementwise_max(s, z);
}
struct h4 { v2h lo, hi; };
struct h8 { v2h a, b, c, d; };   // 16B

// ============ k_prep: pack weights into fp16 k-pair layouts ================
// W1p (W_n1), Wep (W_e1 rows 0..511), Wsp (W_s1), Winp (W_in padded),
// Wn2p (W_n2, 409600 v2h), Weeh (W_e1 rows 512..575, [arr*512+col][16]).
__global__ __launch_bounds__(256) void k_prep(
        const float* __restrict__ W_n1, const float* __restrict__ W_e1,
        const float* __restrict__ W_s1, const float* __restrict__ W_in,
        const float* __restrict__ W_n2,
        v2h* __restrict__ W1p, v2h* __restrict__ Wep,
        v2h* __restrict__ Wsp, v2h* __restrict__ Winp,
        v2h* __restrict__ Wn2p, v2h* __restrict__ Weeh) {
    int f = blockIdx.x * 256 + threadIdx.x;
    if (f < 131072) {
        int q = f & 3, t1 = f >> 2, j = t1 & 511, k8 = t1 >> 9;
        int k2 = k8 * 4 + q;
        v2h w;
        w.x = (_Float16)W_n1[(size_t)(2 * k2) * HDIM + j];
        w.y = (_Float16)W_n1[(size_t)(2 * k2 + 1) * HDIM + j];
        W1p[f] = w;
    } else if (f < 262144) {
        int g = f - 131072;
        int q = g & 3, t1 = g >> 2, j = t1 & 511, k8 = t1 >> 9;
        int k2 = k8 * 4 + q;
        v2h w;
        w.x = (_Float16)W_e1[(size_t)(2 * k2) * HDIM + j];
        w.y = (_Float16)W_e1[(size_t)(2 * k2 + 1) * HDIM + j];
        Wep[g] = w;
    } else if (f < 327680) {
        int g = f - 262144;
        int q = g & 3, t1 = g >> 2, j = t1 & 255, k8 = t1 >> 8;
        int k2 = k8 * 4 + q;
        v2h w;
        w.x = (_Float16)W_s1[(size_t)(2 * k2) * (HDIM / 2) + j];
        w.y = (_Float16)W_s1[(size_t)(2 * k2 + 1) * (HDIM / 2) + j];
        Wsp[g] = w;
    } else if (f < 362496) {
        int g = f - 327680;
        int q = g & 3, t1 = g >> 2, j = t1 & 511, k8 = t1 >> 9;
        int k2 = k8 * 4 + q;     // 0..67
        int r0 = 2 * k2, r1 = 2 * k2 + 1;
        v2h w;
        w.x = (r0 < LDIM + PDIM) ? (_Float16)W_in[(size_t)r0 * HDIM + j] : (_Float16)0.f;
        w.y = (r1 < LDIM + PDIM) ? (_Float16)W_in[(size_t)r1 * HDIM + j] : (_Float16)0.f;
        Winp[g] = w;
    } else if (f < 772096) {
        int g = f - 362496;
        int q = g & 3, t1 = g >> 2;      // t1 < 102400
        int j = t1 % 1600, k8 = t1 / 1600;   // k8 < 64
        int k2 = k8 * 4 + q;             // < 256
        v2h w;
        w.x = (_Float16)W_n2[(size_t)(2 * k2) * 1600 + j];
        w.y = (_Float16)W_n2[(size_t)(2 * k2 + 1) * 1600 + j];
        Wn2p[g] = w;
    } else if (f < 772096 + 16384) {
        int g = f - 772096;              // [arr][col][k2]
        int k2 = g & 15, col = (g >> 4) & 511, arr = g >> 13;
        v2h w;
        w.x = (_Float16)W_e1[(size_t)(HDIM + arr * DDIM + 2 * k2) * HDIM + col];
        w.y = (_Float16)W_e1[(size_t)(HDIM + arr * DDIM + 2 * k2 + 1) * HDIM + col];
        Weeh[g] = w;
    }
}

// helper: stage packed inputs [2][68] v2h from z/tp
__device__ __forceinline__ void stage_sin2(v2h* sin2, const float* z, const float* tp,
                                           int b0, int t) {
    if (t < 136) {
        int bi = (t >= 68) ? 1 : 0;
        int k2 = t - (bi ? 68 : 0);
        int k0 = 2 * k2, k1 = 2 * k2 + 1;
        float v0 = (k0 < LDIM) ? z[(size_t)(b0 + bi) * LDIM + k0]
                 : (k0 < LDIM + PDIM) ? tp[(size_t)(b0 + bi) * PDIM + (k0 - LDIM)] : 0.f;
        float v1 = (k1 < LDIM) ? z[(size_t)(b0 + bi) * LDIM + k1]
                 : (k1 < LDIM + PDIM) ? tp[(size_t)(b0 + bi) * PDIM + (k1 - LDIM)] : 0.f;
        v2h v; v.x = (_Float16)v0; v.y = (_Float16)v1;
        sin2[bi * 68 + k2] = v;
    }
}

// helper: phase1 h for 2 batches via packed W_in; writes sh[2][512] fp32
__device__ __forceinline__ void phase1_h(const v2h* sin2, const v2h* Winp,
                                         const float* b_in, float* sh, int t) {
    float bin0 = b_in[t], bin1 = b_in[t + 256];
    float a00 = bin0, a01 = bin1, a10 = bin0, a11 = bin1;
    for (int k8 = 0; k8 < 17; ++k8) {
        h8 s0 = *reinterpret_cast<const h8*>(&sin2[k8 * 4]);
        h8 s1 = *reinterpret_cast<const h8*>(&sin2[68 + k8 * 4]);
        h8 w0 = *reinterpret_cast<const h8*>(&Winp[(size_t)(k8 * 512 + t) * 4]);
        h8 w1 = *reinterpret_cast<const h8*>(&Winp[(size_t)(k8 * 512 + t + 256) * 4]);
        a00 = fdot2f(s0.a, w0.a, a00); a00 = fdot2f(s0.b, w0.b, a00);
        a00 = fdot2f(s0.c, w0.c, a00); a00 = fdot2f(s0.d, w0.d, a00);
        a01 = fdot2f(s0.a, w1.a, a01); a01 = fdot2f(s0.b, w1.b, a01);
        a01 = fdot2f(s0.c, w1.c, a01); a01 = fdot2f(s0.d, w1.d, a01);
        a10 = fdot2f(s1.a, w0.a, a10); a10 = fdot2f(s1.b, w0.b, a10);
        a10 = fdot2f(s1.c, w0.c, a10); a10 = fdot2f(s1.d, w0.d, a10);
        a11 = fdot2f(s1.a, w1.a, a11); a11 = fdot2f(s1.b, w1.b, a11);
        a11 = fdot2f(s1.c, w1.c, a11); a11 = fdot2f(s1.d, w1.d, a11);
    }
    sh[t] = fmaxf(a00, 0.f); sh[t + 256] = fmaxf(a01, 0.f);
    sh[512 + t] = fmaxf(a10, 0.f); sh[512 + t + 256] = fmaxf(a11, 0.f);
}

// ============ k_pre: fp16-packed sweeps (round-21 champion) ================
__global__ __launch_bounds__(256) void k_pre(
        const float* __restrict__ z, const float* __restrict__ tp,
        const float* __restrict__ b_in,
        const float* __restrict__ b_s1,
        const float* __restrict__ W_s2, const float* __restrict__ b_s2,
        const float* __restrict__ b_n1,
        const float* __restrict__ pe,
        const v2h* __restrict__ W1p, const v2h* __restrict__ Wep,
        const v2h* __restrict__ Wsp, const v2h* __restrict__ Winp,
        float* __restrict__ n1, float* __restrict__ u,
        float* __restrict__ pW1, float* __restrict__ out_sp) {
    int bx = blockIdx.x, t = threadIdx.x;
    __shared__ float smem[2560];

    if (bx < 512) {
        int role = bx >> 8;
        int idx2 = bx & 255;
        int bg = idx2 >> 1, jh = idx2 & 1;
        int b0 = bg * 2;
        v2h* sin2 = reinterpret_cast<v2h*>(smem);        // 136 v2h
        float* sh  = smem + 136;                          // [2][512]
        v2h* h2    = reinterpret_cast<v2h*>(smem + 1160); // [2][256] v2h
        stage_sin2(sin2, z, tp, b0, t);
        __syncthreads();
        phase1_h(sin2, Winp, b_in, sh, t);
        __syncthreads();
        for (int idx = t; idx < 512; idx += 256) {
            int bi = idx >> 8, k2 = idx & 255;
            v2h v; v.x = (_Float16)sh[bi * 512 + 2 * k2];
            v.y = (_Float16)sh[bi * 512 + 2 * k2 + 1];
            h2[bi * 256 + k2] = v;
        }
        __syncthreads();
        int j = jh * 256 + t;
        const v2h* Wp = role ? Wep : W1p;
        float a0 = 0.f, a0b = 0.f, a1 = 0.f, a1b = 0.f;
        for (int k8 = 0; k8 < 64; ++k8) {
            h8 ha = *reinterpret_cast<const h8*>(&h2[k8 * 4]);
            h8 hb = *reinterpret_cast<const h8*>(&h2[256 + k8 * 4]);
            h8 w  = *reinterpret_cast<const h8*>(&Wp[(size_t)(k8 * 512 + j) * 4]);
            a0  = fdot2f(ha.a, w.a, a0);  a0  = fdot2f(ha.b, w.b, a0);
            a0b = fdot2f(ha.c, w.c, a0b); a0b = fdot2f(ha.d, w.d, a0b);
            a1  = fdot2f(hb.a, w.a, a1);  a1  = fdot2f(hb.b, w.b, a1);
            a1b = fdot2f(hb.c, w.c, a1b); a1b = fdot2f(hb.d, w.d, a1b);
        }
        float r0 = a0 + a0b, r1 = a1 + a1b;
        if (role == 0) {
            float bb = b_n1[j];
            n1[(size_t)(b0 + 0) * HDIM + j] = fmaxf(r0 + bb, 0.f);
            n1[(size_t)(b0 + 1) * HDIM + j] = fmaxf(r1 + bb, 0.f);
        } else {
            u[(size_t)(b0 + 0) * HDIM + j] = r0;
            u[(size_t)(b0 + 1) * HDIM + j] = r1;
        }
    } else if (bx < 640) {
        int b0 = (bx - 512) * 2;
        v2h* sin2 = reinterpret_cast<v2h*>(smem);
        float* sh  = smem + 136;
        v2h* h2    = reinterpret_cast<v2h*>(smem + 1160);
        float* s1b = smem + 1672;
        float* slg = smem + 2184;
        stage_sin2(sin2, z, tp, b0, t);
        __syncthreads();
        phase1_h(sin2, Winp, b_in, sh, t);
        __syncthreads();
        for (int idx = t; idx < 512; idx += 256) {
            int bi = idx >> 8, k2 = idx & 255;
            v2h v; v.x = (_Float16)sh[bi * 512 + 2 * k2];
            v.y = (_Float16)sh[bi * 512 + 2 * k2 + 1];
            h2[bi * 256 + k2] = v;
        }
        __syncthreads();
        {
            float bv = b_s1[t];
            float a0 = bv, a0b = 0.f, a1 = bv, a1b = 0.f;
            for (int k8 = 0; k8 < 64; ++k8) {
                h8 ha = *reinterpret_cast<const h8*>(&h2[k8 * 4]);
                h8 hb = *reinterpret_cast<const h8*>(&h2[256 + k8 * 4]);
                h8 w  = *reinterpret_cast<const h8*>(&Wsp[(size_t)(k8 * 256 + t) * 4]);
                a0  = fdot2f(ha.a, w.a, a0);  a0  = fdot2f(ha.b, w.b, a0);
                a0b = fdot2f(ha.c, w.c, a0b); a0b = fdot2f(ha.d, w.d, a0b);
                a1  = fdot2f(hb.a, w.a, a1);  a1  = fdot2f(hb.b, w.b, a1);
                a1b = fdot2f(hb.c, w.c, a1b); a1b = fdot2f(hb.d, w.d, a1b);
            }
            s1b[t] = fmaxf(a0 + a0b, 0.f);
            s1b[256 + t] = fmaxf(a1 + a1b, 0.f);
        }
        __syncthreads();
        int b4 = t / NDIM, o = t % NDIM;
        if (t < 2 * NDIM) {
            float a = b_s2[o];
            for (int k = 0; k < HDIM / 2; ++k)
                a += s1b[b4 * 256 + k] * W_s2[(size_t)k * NDIM + o];
            slg[b4 * NDIM + o] = a;
        }
        __syncthreads();
        if (t < 2 * NDIM) {
            float m = slg[b4 * NDIM];
            for (int k = 1; k < NDIM; ++k) m = fmaxf(m, slg[b4 * NDIM + k]);
            float s = 0.f;
            for (int k = 0; k < NDIM; ++k) s += expf(slg[b4 * NDIM + k] - m);
            out_sp[(size_t)(b0 + b4) * NDIM + o] = expf(slg[b4 * NDIM + o] - m) / s;
        }
    } else {
        int g = bx - 640, rg = g >> 1, jh = g & 1;
        int r[4];
#pragma unroll
        for (int q = 0; q < 4; ++q) { int rr = rg * 4 + q; r[q] = (rr < NDIM) ? rr : NDIM - 1; }
        v2h* pe2 = reinterpret_cast<v2h*>(smem);   // [4][256] v2h
        for (int idx = t; idx < 4 * 256; idx += 256) {
            int row = idx >> 8, k2 = idx & 255;
            v2h v;
            v.x = (_Float16)pe[(size_t)r[row] * HDIM + 2 * k2];
            v.y = (_Float16)pe[(size_t)r[row] * HDIM + 2 * k2 + 1];
            pe2[idx] = v;
        }
        __syncthreads();
        int j = jh * 256 + t;
        float a0 = 0.f, a0b = 0.f, a1 = 0.f, a1b = 0.f;
        float a2 = 0.f, a2b = 0.f, a3 = 0.f, a3b = 0.f;
        for (int k8 = 0; k8 < 64; ++k8) {
            h8 p0 = *reinterpret_cast<const h8*>(&pe2[0 * 256 + k8 * 4]);
            h8 p1 = *reinterpret_cast<const h8*>(&pe2[1 * 256 + k8 * 4]);
            h8 p2 = *reinterpret_cast<const h8*>(&pe2[2 * 256 + k8 * 4]);
            h8 p3 = *reinterpret_cast<const h8*>(&pe2[3 * 256 + k8 * 4]);
            h8 w  = *reinterpret_cast<const h8*>(&Wep[(size_t)(k8 * 512 + j) * 4]);
            a0  = fdot2f(p0.a, w.a, a0);  a0  = fdot2f(p0.b, w.b, a0);
            a0b = fdot2f(p0.c, w.c, a0b); a0b = fdot2f(p0.d, w.d, a0b);
            a1  = fdot2f(p1.a, w.a, a1);  a1  = fdot2f(p1.b, w.b, a1);
            a1b = fdot2f(p1.c, w.c, a1b); a1b = fdot2f(p1.d, w.d, a1b);
            a2  = fdot2f(p2.a, w.a, a2);  a2  = fdot2f(p2.b, w.b, a2);
            a2b = fdot2f(p2.c, w.c, a2b); a2b = fdot2f(p2.d, w.d, a2b);
            a3  = fdot2f(p3.a, w.a, a3);  a3  = fdot2f(p3.b, w.b, a3);
            a3b = fdot2f(p3.c, w.c, a3b); a3b = fdot2f(p3.d, w.d, a3b);
        }
        pW1[(size_t)r[0] * HDIM + j] = 0.5f * (a0 + a0b);
        pW1[(size_t)r[1] * HDIM + j] = 0.5f * (a1 + a1b);
        pW1[(size_t)r[2] * HDIM + j] = 0.5f * (a2 + a2b);
        pW1[(size_t)r[3] * HDIM + j] = 0.5f * (a3 + a3b);
    }
}

// ============ k_nl: fp16-packed W_n2 sweep, 2 batches/block ================
__global__ __launch_bounds__(320) void k_nl(const float* __restrict__ n1,
                                            const v2h* __restrict__ Wn2p,
                                            const float* __restrict__ b_n2,
                                            float* __restrict__ out_nl,
                                            _Float16* __restrict__ nl_h) {
    const int NOUT = NDIM * DDIM;   // 1600
    int t = threadIdx.x;
    int j = blockIdx.y * 320 + t;
    int bg = blockIdx.x;            // 2 batches
    __shared__ v2h h2s[512];        // [2][256]
    for (int idx = t; idx < 512; idx += 320) {
        int bi = idx >> 8, k2 = idx & 255;
        v2h v;
        v.x = (_Float16)n1[(size_t)(bg * 2 + bi) * HDIM + 2 * k2];
        v.y = (_Float16)n1[(size_t)(bg * 2 + bi) * HDIM + 2 * k2 + 1];
        h2s[idx] = v;
    }
    __syncthreads();
    float a0 = 0.f, a0b = 0.f, a1 = 0.f, a1b = 0.f;
    for (int k8 = 0; k8 < 64; ++k8) {
        h8 ha = *reinterpret_cast<const h8*>(&h2s[k8 * 4]);
        h8 hb = *reinterpret_cast<const h8*>(&h2s[256 + k8 * 4]);
        h8 w  = *reinterpret_cast<const h8*>(&Wn2p[((size_t)k8 * 1600 + j) * 4]);
        a0  = fdot2f(ha.a, w.a, a0);  a0  = fdot2f(ha.b, w.b, a0);
        a0b = fdot2f(ha.c, w.c, a0b); a0b = fdot2f(ha.d, w.d, a0b);
        a1  = fdot2f(hb.a, w.a, a1);  a1  = fdot2f(hb.b, w.b, a1);
        a1b = fdot2f(hb.c, w.c, a1b); a1b = fdot2f(hb.d, w.d, a1b);
    }
    float bias = b_n2[j];
    float r0 = bias + a0 + a0b;
    float r1 = bias + a1 + a1b;
    out_nl[(size_t)(bg * 2 + 0) * NOUT + j] = r0;
    out_nl[(size_t)(bg * 2 + 1) * NOUT + j] = r1;
    nl_h[(size_t)(bg * 2 + 0) * NOUT + j] = (_Float16)r0;
    nl_h[(size_t)(bg * 2 + 1) * NOUT + j] = (_Float16)r1;
}

// ============ k_edge: LDS nl broadcast + packed produce weights ============
__global__ __launch_bounds__(256) void k_edge(
        const _Float16* __restrict__ nl_h,  // [256,50,32] fp16
        const float* __restrict__ u,        // [256,512]
        const float* __restrict__ pW1,      // [50,512]
        const v2h* __restrict__ Weeh,       // [2*512][16] packed produce W
        const float* __restrict__ b_e1,     // [512]
        const float* __restrict__ W_e2,     // [512,5]
        _Float16* __restrict__ P) {         // [4][256][1225][5] fp16
    int b  = blockIdx.x;
    int rh = blockIdx.y;
    int t  = threadIdx.x;
    int rbase = rh * ECH;
    constexpr int ech4 = ECH / 4;           // 32

    __shared__ __align__(16) _Float16 Ah[NDIM * ECH];  // 12.8 KB
    __shared__ __align__(16) _Float16 Bh[NDIM * ECH];  // 12.8 KB
    __shared__ v2h W2h[ECH / 2][EOUT];                 // 1.28 KB
    __shared__ __align__(16) v2h nls[NDIM * 16];       // 3.2 KB

    for (int i = t; i < (ECH / 2) * EOUT; i += 256) {
        int p = i / EOUT, o = i - p * EOUT;
        v2h w;
        w.x = (_Float16)W_e2[(size_t)(rbase + 2 * p) * EOUT + o];
        w.y = (_Float16)W_e2[(size_t)(rbase + 2 * p + 1) * EOUT + o];
        W2h[p][o] = w;
    }
    {
        const v2h* g = reinterpret_cast<const v2h*>(nl_h + (size_t)b * (NDIM * DDIM));
        for (int i = t; i < NDIM * 16; i += 256) nls[i] = g[i];
    }
    __syncthreads();

    bool has = (t < 225);
    int pp = 0, qq = 0;
    if (has) {
        int tt = t;
        for (pp = 0; pp < 25; ++pp) {
            int qmin = pp ? ((2 * pp - 2) / 3 + 1) : 0;
            int cnt = 17 - qmin;
            if (tt < cnt) { qq = qmin + tt; break; }
            tt -= cnt;
        }
    }
    int i0 = 2 * pp, i1 = i0 + 1;
    int j0 = 3 * qq, j1 = j0 + 1, j2r = (3 * qq + 2 < NDIM) ? 3 * qq + 2 : NDIM - 1;

    float acc[6][EOUT];
#pragma unroll
    for (int e = 0; e < 6; ++e)
#pragma unroll
        for (int o = 0; o < EOUT; ++o) acc[e][o] = 0.f;

    // ---- produce (packed W via Weeh, nl via LDS broadcast) ----
    {
        int arr = t >> 7, c = t & 127;
        int col = rbase + c;
        const h8* wp = reinterpret_cast<const h8*>(&Weeh[((size_t)arr * 512 + col) * 16]);
        h8 wA = wp[0], wB = wp[1], wC = wp[2], wD = wp[3];
        float cm = 0.5f * (u[(size_t)b * HDIM + col] + b_e1[col]);
        _Float16* dst = arr ? Bh : Ah;
        float pc = pW1[col];
        for (int n = 0; n < NDIM; ++n) {
            float pn = (n < NDIM - 1) ? pW1[(size_t)(n + 1) * HDIM + col] : 0.f;
            const h8* nrp = reinterpret_cast<const h8*>(&nls[n * 16]);
            h8 nA = nrp[0], nB = nrp[1], nC = nrp[2], nD = nrp[3];
            float s0 = 0.f, s1 = 0.f, s2 = 0.f, s3 = 0.f;
            s0 = fdot2f(nA.a, wA.a, s0); s0 = fdot2f(nA.b, wA.b, s0);
            s0 = fdot2f(nA.c, wA.c, s0); s0 = fdot2f(nA.d, wA.d, s0);
            s1 = fdot2f(nB.a, wB.a, s1); s1 = fdot2f(nB.b, wB.b, s1);
            s1 = fdot2f(nB.c, wB.c, s1); s1 = fdot2f(nB.d, wB.d, s1);
            s2 = fdot2f(nC.a, wC.a, s2); s2 = fdot2f(nC.b, wC.b, s2);
            s2 = fdot2f(nC.c, wC.c, s2); s2 = fdot2f(nC.d, wC.d, s2);
            s3 = fdot2f(nD.a, wD.a, s3); s3 = fdot2f(nD.b, wD.b, s3);
            s3 = fdot2f(nD.c, wD.c, s3); s3 = fdot2f(nD.d, wD.d, s3);
            float val = (cm + pc) + ((s0 + s1) + (s2 + s3));
            dst[n * ECH + ((((c >> 2) ^ (n & 7)) << 2) | (c & 3))] = (_Float16)val;
            pc = pn;
        }
    }
    __syncthreads();

    // ---- consume ----
    if (has) {
        int sA = i0 & 7, sB = i1 & 7, s0m = j0 & 7, s1m = j1 & 7, s2m = j2r & 7;
        for (int r4 = 0; r4 < ech4; ++r4) {
            h4 ra0 = *reinterpret_cast<const h4*>(&Ah[i0 * ECH + ((r4 ^ sA) << 2)]);
            h4 ra1 = *reinterpret_cast<const h4*>(&Ah[i1 * ECH + ((r4 ^ sB) << 2)]);
            h4 rb0 = *reinterpret_cast<const h4*>(&Bh[j0 * ECH + ((r4 ^ s0m) << 2)]);
            h4 rb1 = *reinterpret_cast<const h4*>(&Bh[j1 * ECH + ((r4 ^ s1m) << 2)]);
            h4 rb2 = *reinterpret_cast<const h4*>(&Bh[j2r * ECH + ((r4 ^ s2m) << 2)]);
            v2h v0l = relu2(ra0.lo, rb0.lo), v0h = relu2(ra0.hi, rb0.hi);
            v2h v1l = relu2(ra0.lo, rb1.lo), v1h = relu2(ra0.hi, rb1.hi);
            v2h v2l = relu2(ra0.lo, rb2.lo), v2hh = relu2(ra0.hi, rb2.hi);
            v2h v3l = relu2(ra1.lo, rb0.lo), v3h = relu2(ra1.hi, rb0.hi);
            v2h v4l = relu2(ra1.lo, rb1.lo), v4h = relu2(ra1.hi, rb1.hi);
            v2h v5l = relu2(ra1.lo, rb2.lo), v5h = relu2(ra1.hi, rb2.hi);
            int pb = r4 * 2;
#pragma unroll
            for (int o = 0; o < EOUT; ++o) {
                v2h wl = W2h[pb][o], wh = W2h[pb + 1][o];
                acc[0][o] = fdot2f(v0h, wh, fdot2f(v0l, wl, acc[0][o]));
                acc[1][o] = fdot2f(v1h, wh, fdot2f(v1l, wl, acc[1][o]));
                acc[2][o] = fdot2f(v2hh, wh, fdot2f(v2l, wl, acc[2][o]));
                acc[3][o] = fdot2f(v3h, wh, fdot2f(v3l, wl, acc[3][o]));
                acc[4][o] = fdot2f(v4h, wh, fdot2f(v4l, wl, acc[4][o]));
                acc[5][o] = fdot2f(v5h, wh, fdot2f(v5l, wl, acc[5][o]));
            }
        }
    }
    __syncthreads();

    if (has) {
        _Float16* Pb = P + ((size_t)rh * BSZ + b) * NEDGE * EOUT;
        int js[3] = {j0, j1, 3 * qq + 2};
#pragma unroll
        for (int r = 0; r < 2; ++r) {
            int i = i0 + r;
#pragma unroll
            for (int cc = 0; cc < 3; ++cc) {
                int j = js[cc];
                if (i < j && j < NDIM) {
                    int e = i * (NDIM - 1) - (i * (i - 1)) / 2 + (j - i - 1);
#pragma unroll
                    for (int o = 0; o < EOUT; ++o)
                        Pb[(size_t)e * EOUT + o] = (_Float16)acc[r * 3 + cc][o];
                }
            }
        }
    }
}

// ============ k_comb: out_el = sum of 4 fp16 partials + bias ===============
__global__ __launch_bounds__(256) void k_comb(const _Float16* __restrict__ P,
                                              const float* __restrict__ b_e2,
                                              float* __restrict__ out_el,
                                              float* __restrict__ out_idx) {
    int blk = blockIdx.x, t = threadIdx.x;
    const size_t PS = (size_t)BSZ * NEDGE * EOUT;   // 1568000 halves
    if (blk < 766) {
        int tid = blk * 256 + t;       // h8 unit index; 196000 total
        if (tid < 196000) {
            float s[8];
#pragma unroll
            for (int e = 0; e < 8; ++e) s[e] = 0.f;
#pragma unroll
            for (int p = 0; p < NRH; ++p) {
                h8 v = reinterpret_cast<const h8*>(P + (size_t)p * PS)[tid];
                s[0] += (float)v.a.x; s[1] += (float)v.a.y;
                s[2] += (float)v.b.x; s[3] += (float)v.b.y;
                s[4] += (float)v.c.x; s[5] += (float)v.c.y;
                s[6] += (float)v.d.x; s[7] += (float)v.d.y;
            }
            float b5[5];
#pragma unroll
            for (int cc = 0; cc < 5; ++cc) b5[cc] = b_e2[cc];
            size_t base = (size_t)tid * 8;
            int m = (int)(base % 5);
            float4 r0, r1;
#pragma unroll
            for (int e = 0; e < 8; ++e) {
                float val = s[e] + b5[m];
                if (e < 4) (&r0.x)[e] = val; else (&r1.x)[e - 4] = val;
                m = (m + 1 == 5) ? 0 : m + 1;
            }
            reinterpret_cast<float4*>(out_el + base)[0] = r0;
            reinterpret_cast<float4*>(out_el + base)[1] = r1;
        }
    } else {
        int e = (blk - 766) * 256 + t;
        if (e < NEDGE) {
            int i = 0, rem = e;
            while (rem >= (NDIM - 1 - i)) { rem -= (NDIM - 1 - i); ++i; }
            int j = i + 1 + rem;
            out_idx[e * 2] = (float)i;
            out_idx[e * 2 + 1] = (float)j;
        }
    }
}

extern "C" void kernel_launch(void* const* d_in, const int* in_sizes, int n_in,
                              void* d_out, int out_size, void* d_ws, size_t ws_size,
                              hipStream_t stream) {
    const float* z    = (const float*)d_in[0];
    const float* tp   = (const float*)d_in[1];
    const float* W_in = (const float*)d_in[2];
    const float* b_in = (const float*)d_in[3];
    const float* W_s1 = (const float*)d_in[4];
    const float* b_s1 = (const float*)d_in[5];
    const float* W_s2 = (const float*)d_in[6];
    const float* b_s2 = (const float*)d_in[7];
    const float* W_n1 = (const float*)d_in[8];
    const float* b_n1 = (const float*)d_in[9];
    const float* W_n2 = (const float*)d_in[10];
    const float* b_n2 = (const float*)d_in[11];
    const float* W_e1 = (const float*)d_in[12];
    const float* b_e1 = (const float*)d_in[13];
    const float* W_e2 = (const float*)d_in[14];
    const float* b_e2 = (const float*)d_in[15];
    const float* pe   = (const float*)d_in[16];

    float* out     = (float*)d_out;
    float* out_nl  = out;                 // node_logits
    float* out_el  = out + 409600;        // edge_logits
    float* out_sp  = out + 1977600;       // size_probs
    float* out_idx = out + 1990400;       // edge_indices (as float)

    float* ws   = (float*)d_ws;
    float* u    = ws;
    float* pW1  = ws + 131072;
    float* n1   = ws + 156672;
    _Float16* P_h = (_Float16*)(ws + 287744);    // [4][256][1225][5] fp16
    _Float16* nl_h = (_Float16*)(ws + 6559744);  // [256,50,32] fp16
    v2h* W1p  = (v2h*)(ws + 6764544);
    v2h* Wep  = (v2h*)(ws + 6895616);
    v2h* Wsp  = (v2h*)(ws + 7026688);
    v2h* Winp = (v2h*)(ws + 7092224);
    v2h* Wn2p = (v2h*)(ws + 7127040);
    v2h* Weeh = (v2h*)(ws + 7536640);

    k_prep<<<3080, 256, 0, stream>>>(W_n1, W_e1, W_s1, W_in, W_n2,
                                     W1p, Wep, Wsp, Winp, Wn2p, Weeh);
    k_pre<<<666, 256, 0, stream>>>(z, tp, b_in, b_s1, W_s2, b_s2, b_n1, pe,
                                   W1p, Wep, Wsp, Winp, n1, u, pW1, out_sp);
    k_nl<<<dim3(128, 5), 320, 0, stream>>>(n1, Wn2p, b_n2, out_nl, nl_h);
    k_edge<<<dim3(BSZ, NRH), 256, 0, stream>>>(nl_h, u, pW1, Weeh, b_e1, W_e2, P_h);
    k_comb<<<771, 256, 0, stream>>>(P_h, b_e2, out_el, out_idx);
}